// Round 10
// baseline (507.107 us; speedup 1.0000x reference)
//
#include <hip/hip_runtime.h>
#include <hip/hip_fp16.h>
#include <math.h>

#define NN 50000
#define NE 800000
#define ET (NE + NN)
#define NG 64
#define H 4
#define NB ((NN + 255) / 256)   // 196 blocks of 256 nodes
#define PAD 16                  // one atomic counter per 64B line

typedef _Float16 half8 __attribute__((ext_vector_type(8)));
typedef _Float16 hv2 __attribute__((ext_vector_type(2)));
typedef float floatx4 __attribute__((ext_vector_type(4)));

// ---------------- CSR build ----------------
// deg/cursor are line-padded (stride 16 ints): 272 atomics/line -> 17, kills L2 RMW serialization.

__global__ __launch_bounds__(256) void k_count(const int* __restrict__ ei, int* __restrict__ deg) {
    int e = blockIdx.x * 256 + threadIdx.x;
    if (e >= ET) return;
    int d = (e < NE) ? ei[NE + e] : (e - NE);
    atomicAdd(&deg[d * PAD], 1);
}

// batch is sorted: graph boundaries without atomics.
__global__ __launch_bounds__(256) void k_bounds(const int* __restrict__ batch, int* __restrict__ bpos) {
    int i = blockIdx.x * 256 + threadIdx.x;
    if (i >= NN) return;
    int cur = batch[i];
    int prev = (i == 0) ? -1 : batch[i - 1];
    for (int g = prev + 1; g <= cur; ++g) bpos[g] = i;
    if (i == NN - 1)
        for (int g = cur + 1; g <= NG; ++g) bpos[g] = NN;
}

// ---- decoupled 3-pass exclusive scan of padded deg[] -> rowptr/cursor

__global__ __launch_bounds__(256) void k_blksum(const int* __restrict__ deg, int* __restrict__ bsum) {
    int i = blockIdx.x * 256 + threadIdx.x;
    int v = (i < NN) ? deg[i * PAD] : 0;
    for (int off = 32; off; off >>= 1) v += __shfl_down(v, off, 64);
    __shared__ int lds[4];
    int lane = threadIdx.x & 63, wid = threadIdx.x >> 6;
    if (lane == 0) lds[wid] = v;
    __syncthreads();
    if (threadIdx.x == 0) bsum[blockIdx.x] = lds[0] + lds[1] + lds[2] + lds[3];
}

// scan of block sums; also derives per-graph counts from bpos (folded k_cnt)
__global__ __launch_bounds__(256) void k_scanb(const int* __restrict__ bsum, int* __restrict__ boff,
                                               const int* __restrict__ bpos, int* __restrict__ cnt) {
    __shared__ int lds[256];
    int t = threadIdx.x;
    int v = (t < NB) ? bsum[t] : 0;
    lds[t] = v;
    __syncthreads();
    for (int off = 1; off < 256; off <<= 1) {
        int y = (t >= off) ? lds[t - off] : 0;
        __syncthreads();
        lds[t] += y;
        __syncthreads();
    }
    if (t < NB) boff[t] = lds[t] - v;   // exclusive
    if (t < NG) cnt[t] = bpos[t + 1] - bpos[t];
}

__global__ __launch_bounds__(256) void k_scanc(const int* __restrict__ deg, const int* __restrict__ boff,
                                               int* __restrict__ rowptr, int* __restrict__ cursor) {
    int b = blockIdx.x, t = threadIdx.x;
    int i = b * 256 + t;
    int v = (i < NN) ? deg[i * PAD] : 0;
    int lane = t & 63, wid = t >> 6;
    int x = v;
    for (int off = 1; off < 64; off <<= 1) {
        int y = __shfl_up(x, off, 64);
        if (lane >= off) x += y;
    }
    __shared__ int wsum[4];
    if (lane == 63) wsum[wid] = x;
    __syncthreads();
    int base = boff[b];
    for (int w = 0; w < wid; ++w) base += wsum[w];
    int p = base + x - v;   // exclusive prefix for node i
    if (i < NN) { rowptr[i] = p; cursor[i * PAD] = p; }
    if (i == NN - 1) rowptr[NN] = p + v;
}

__global__ __launch_bounds__(256) void k_scatter(const int* __restrict__ ei, int* __restrict__ cursor,
                                                 unsigned short* __restrict__ colsrc) {
    int e = blockIdx.x * 256 + threadIdx.x;
    if (e >= ET) return;
    int s, d;
    if (e < NE) { s = ei[e]; d = ei[NE + e]; } else { s = e - NE; d = s; }
    int pos = atomicAdd(&cursor[d * PAD], 1);
    colsrc[pos] = (unsigned short)s;
}

// ---------------- fp32 -> fp16 cast (layer-1 GEMM input) ----------------

__global__ __launch_bounds__(256) void k_cast(const float* __restrict__ x, __half* __restrict__ xh) {
    int i = blockIdx.x * 256 + threadIdx.x;       // one thread = 8 elements; NN*128 % 8 == 0
    size_t base = (size_t)i * 8;
    if (base >= (size_t)NN * 128) return;
    const float4* p = (const float4*)(x + base);
    float4 a = p[0], b = p[1];
    half8 h;
    h[0] = (_Float16)a.x; h[1] = (_Float16)a.y; h[2] = (_Float16)a.z; h[3] = (_Float16)a.w;
    h[4] = (_Float16)b.x; h[5] = (_Float16)b.y; h[6] = (_Float16)b.z; h[7] = (_Float16)b.w;
    *(half8*)(xh + base) = h;
}

// ---------------- weight prep: fp32 [K][M2]x2 -> fp16 MFMA-fragment order (all 3 layers fused) ----------------

template <int K, int M2>
__device__ __forceinline__ void wprep_fn(int chunk, const float* __restrict__ Wl, const float* __restrict__ Wr,
                                         _Float16* __restrict__ Wfrag) {
    constexpr int MTOT = 2 * M2, NT = MTOT / 16;
    if (chunk >= MTOT * K / 8) return;
    int lane = chunk & 63, tt = chunk >> 6;
    int t = tt % NT, kt = tt / NT;
    int n = t * 16 + (lane & 15);
    int kb = kt * 32 + (lane >> 4) * 8;
    const float* src = (n < M2) ? (Wl + n) : (Wr + (n - M2));
    half8 h;
#pragma unroll
    for (int j = 0; j < 8; ++j) h[j] = (_Float16)src[(size_t)(kb + j) * M2];
    *(half8*)(Wfrag + (size_t)chunk * 8) = h;
}

__global__ __launch_bounds__(256) void k_wprep_all(const float* __restrict__ Wl1, const float* __restrict__ Wr1,
                                                   const float* __restrict__ Wl2, const float* __restrict__ Wr2,
                                                   const float* __restrict__ Wl3, const float* __restrict__ Wr3,
                                                   _Float16* __restrict__ Wf1, _Float16* __restrict__ Wf2,
                                                   _Float16* __restrict__ Wf3) {
    int b = blockIdx.x, t = threadIdx.x;
    if (b < 16)      wprep_fn<128, 128>(b * 256 + t, Wl1, Wr1, Wf1);
    else if (b < 24) wprep_fn<128, 64>((b - 16) * 256 + t, Wl2, Wr2, Wf2);
    else             wprep_fn<64, 32>((b - 24) * 256 + t, Wl3, Wr3, Wf3);
}

// ---------------- fused dual MFMA GEMM, LDS-free ----------------

template <int K, int M2>
__global__ __launch_bounds__(256) void k_dualgemm(const __half* __restrict__ Ain,
                                                  const _Float16* __restrict__ Wfrag,
                                                  __half* __restrict__ Ol, float* __restrict__ Or) {
    constexpr int MTOT = 2 * M2;
    constexpr int NT = MTOT / 16;
    constexpr int KT = K / 32;
    int tid = threadIdx.x;
    int wid = tid >> 6, lane = tid & 63;
    int q = lane >> 4, l15 = lane & 15;
    int r0 = blockIdx.x * 64 + wid * 16;
    int arow = min(r0 + l15, NN - 1);
    const _Float16* A = (const _Float16*)Ain;
    const _Float16* ap = A + (size_t)arow * K + q * 8;

    floatx4 acc[NT];
#pragma unroll
    for (int t = 0; t < NT; ++t) acc[t] = (floatx4){0.f, 0.f, 0.f, 0.f};

#pragma unroll
    for (int kt = 0; kt < KT; ++kt) {
        half8 a8 = *(const half8*)(ap + kt * 32);
        const _Float16* wp = Wfrag + ((size_t)(kt * NT) * 64 + lane) * 8;
#pragma unroll
        for (int t = 0; t < NT; ++t) {
            half8 b8 = *(const half8*)(wp + (size_t)t * 64 * 8);
            acc[t] = __builtin_amdgcn_mfma_f32_16x16x32_f16(a8, b8, acc[t], 0, 0, 0);
        }
    }

#pragma unroll
    for (int t = 0; t < NT; ++t) {
        int cn = t * 16 + l15;
#pragma unroll
        for (int reg = 0; reg < 4; ++reg) {
            int r = r0 + q * 4 + reg;
            if (r < NN) {
                if (cn < M2) Ol[(size_t)r * M2 + cn] = __float2half(acc[t][reg]);
                else         Or[(size_t)r * M2 + (cn - M2)] = acc[t][reg];
            }
        }
    }
}

// ---------------- GATv2 attention: channel-split + packed fp16 + no-max softmax ----------------

template <int CP> struct HVec { hv2 h2[CP / 2]; };

template <int CP>
__device__ __forceinline__ HVec<CP> load_hv(const __half* __restrict__ p) {
    HVec<CP> r;
    if constexpr (CP == 8) { float4 t = *(const float4*)p; r = *(HVec<CP>*)&t; }
    else if constexpr (CP == 4) { float2 t = *(const float2*)p; r = *(HVec<CP>*)&t; }
    else { r.h2[0] = *(const hv2*)p; }
    return r;
}

template <int C, int EP, bool CONCAT>
__global__ __launch_bounds__(256, 4) void k_attn(const __half* __restrict__ xl, const float* __restrict__ xr,
                                                 const int* __restrict__ rowptr,
                                                 const unsigned short* __restrict__ colsrc,
                                                 const float* __restrict__ att, const float* __restrict__ bias,
                                                 float* __restrict__ out) {
    constexpr int CP = C / EP;
    int t = blockIdx.x * 256 + threadIdx.x;
    int part = t & (EP - 1);
    int nh = t >> 2;                          // EP == 4
    if (nh >= NN * H) return;
    int node = nh >> 2, h = nh & 3;           // H == 4
    int cbase = h * C + part * CP;
    hv2 xrr2[CP / 2], attv2[CP / 2];
    float acc[CP];
    {
        const float* p = xr + (size_t)node * (H * C) + cbase;
        const float* q = att + cbase;
#pragma unroll
        for (int j = 0; j < CP / 2; ++j) {
            xrr2[j] = (hv2){(_Float16)p[2 * j], (_Float16)p[2 * j + 1]};
            attv2[j] = (hv2){(_Float16)q[2 * j], (_Float16)q[2 * j + 1]};
        }
#pragma unroll
        for (int c = 0; c < CP; ++c) acc[c] = 0.f;
    }
    float denom = 0.f;
    int beg = rowptr[node], end = rowptr[node + 1];

    auto process = [&](const HVec<CP>& xv) {
        float part_s = 0.f;
#pragma unroll
        for (int j = 0; j < CP / 2; ++j) {
            hv2 z = xv.h2[j] + xrr2[j];
            hv2 l = __builtin_elementwise_max(z, z * (_Float16)0.2f);   // leaky_relu
            part_s = __builtin_amdgcn_fdot2(l, attv2[j], part_s, false);
        }
        float score = part_s;
#pragma unroll
        for (int mask = 1; mask < EP; mask <<= 1) score += __shfl_xor(score, mask, 64);
        float w = __expf(score);
        denom += w;
        const _Float16* xh = (const _Float16*)&xv;
#pragma unroll
        for (int c = 0; c < CP; ++c) acc[c] = fmaf(w, (float)xh[c], acc[c]);
    };

    int idx = beg;
    for (; idx + 2 <= end; idx += 2) {
        int s0 = colsrc[idx], s1 = colsrc[idx + 1];
        HVec<CP> xv0 = load_hv<CP>(xl + (size_t)s0 * (H * C) + cbase);
        HVec<CP> xv1 = load_hv<CP>(xl + (size_t)s1 * (H * C) + cbase);
        process(xv0);
        process(xv1);
    }
    if (idx < end) {
        int s = colsrc[idx];
        HVec<CP> xv = load_hv<CP>(xl + (size_t)s * (H * C) + cbase);
        process(xv);
    }

    float inv = 1.f / denom;
    float* op = out + (size_t)node * (H * C) + cbase;
    float v[CP];
#pragma unroll
    for (int c = 0; c < CP; ++c) {
        v[c] = acc[c] * inv;
        if (CONCAT) v[c] += bias[cbase + c];
    }
    if constexpr (CP == 8) {
        *(float4*)(op) = make_float4(v[0], v[1], v[2], v[3]);
        *(float4*)(op + 4) = make_float4(v[4], v[5], v[6], v[7]);
    } else if constexpr (CP == 4) {
        *(float4*)(op) = make_float4(v[0], v[1], v[2], v[3]);
    } else {
        *(float2*)(op) = make_float2(v[0], v[1]);
    }
}

// ---------------- GraphNorm ----------------

template <int LOGC>
__global__ __launch_bounds__(256) void k_gnred(const float* __restrict__ h, const int* __restrict__ batch,
                                               float* __restrict__ sum, float* __restrict__ sumsq) {
    constexpr int C = 1 << LOGC;
    constexpr int ROWS = 256 >> LOGC;
    constexpr int NPB = 64;
    int c = threadIdx.x & (C - 1);
    int row = threadIdx.x >> LOGC;
    int base = blockIdx.x * NPB;
    int curg = -1;
    float s = 0.f, ss = 0.f;
#pragma unroll
    for (int r = row; r < NPB; r += ROWS) {
        int nd = base + r;
        if (nd >= NN) break;
        int g = batch[nd];
        if (g != curg) {
            if (curg >= 0) { atomicAdd(&sum[curg * C + c], s); atomicAdd(&sumsq[curg * C + c], ss); }
            curg = g; s = 0.f; ss = 0.f;
        }
        float x = h[(size_t)nd * C + c];
        s += x; ss += x * x;
    }
    if (curg >= 0) { atomicAdd(&sum[curg * C + c], s); atomicAdd(&sumsq[curg * C + c], ss); }
}

// var(out) = E[x^2] - (2s - s^2) mu^2  where out = x - mu*s; optional fp16 copy for next GEMM
__global__ __launch_bounds__(256) void k_gnnorm(float* __restrict__ h, const int* __restrict__ batch,
                                                const float* __restrict__ sum, const float* __restrict__ sumsq,
                                                const int* __restrict__ cnt, const float* __restrict__ w,
                                                const float* __restrict__ b, const float* __restrict__ ms,
                                                int logC, __half* __restrict__ h16) {
    int C = 1 << logC;
    int i = blockIdx.x * 256 + threadIdx.x;
    if (i >= NN * C) return;
    int nd = i >> logC, c = i & (C - 1);
    int g = batch[nd];
    float cg = fmaxf((float)cnt[g], 1.f);
    float mu = sum[g * C + c] / cg;
    float ex2 = sumsq[g * C + c] / cg;
    float s_ = ms[c];
    float var = ex2 - (2.f * s_ - s_ * s_) * mu * mu;
    float y = (h[i] - mu * s_) * rsqrtf(var + 1e-5f) * w[c] + b[c];
    y = fmaxf(y, 0.f);   // fused ReLU
    h[i] = y;
    if (h16) h16[i] = __float2half(y);
}

// ---------------- layer-3 head mean + bias ----------------

__global__ __launch_bounds__(256) void k_headmean(const float* __restrict__ tmp, const float* __restrict__ b3,
                                                  float* __restrict__ out) {
    int i = blockIdx.x * 256 + threadIdx.x;
    if (i >= NN * 8) return;
    int nd = i >> 3, c = i & 7;
    const float* p = tmp + (size_t)nd * 32 + c;
    out[i] = 0.25f * (p[0] + p[8] + p[16] + p[24]) + b3[c];
}

// ---------------- pool mean + linear head ----------------

__global__ __launch_bounds__(512) void k_final(const float* __restrict__ pool, const int* __restrict__ cnt,
                                               const float* __restrict__ lw, const float* __restrict__ lb,
                                               float* __restrict__ outp) {
    __shared__ float feat[512];
    int t = threadIdx.x;
    int g = t >> 3;
    float f = pool[t] / fmaxf((float)cnt[g], 1.f);
    feat[t] = f;
    outp[256 + t] = f;          // features: d_out[256 .. 768)
    __syncthreads();
    if (t < 256) {
        int g2 = t >> 2, o = t & 3;
        float a = lb[o];
#pragma unroll
        for (int cc = 0; cc < 8; ++cc) a += feat[g2 * 8 + cc] * lw[cc * 4 + o];
        outp[t] = a;            // logits: d_out[0 .. 256)
    }
}

// ---------------- host ----------------

extern "C" void kernel_launch(void* const* d_in, const int* in_sizes, int n_in,
                              void* d_out, int out_size, void* d_ws, size_t ws_size,
                              hipStream_t stream) {
    const float* x    = (const float*)d_in[0];
    const int*   ei   = (const int*)d_in[1];
    const int*   batch= (const int*)d_in[2];
    const float *w_l1 = (const float*)d_in[3],  *w_r1 = (const float*)d_in[4];
    const float *att1 = (const float*)d_in[5],  *b1   = (const float*)d_in[6];
    const float *gn1w = (const float*)d_in[7],  *gn1b = (const float*)d_in[8],  *gn1s = (const float*)d_in[9];
    const float *w_l2 = (const float*)d_in[10], *w_r2 = (const float*)d_in[11];
    const float *att2 = (const float*)d_in[12], *b2   = (const float*)d_in[13];
    const float *gn2w = (const float*)d_in[14], *gn2b = (const float*)d_in[15], *gn2s = (const float*)d_in[16];
    const float *w_l3 = (const float*)d_in[17], *w_r3 = (const float*)d_in[18];
    const float *att3 = (const float*)d_in[19], *b3   = (const float*)d_in[20];
    const float *gn3w = (const float*)d_in[21], *gn3b = (const float*)d_in[22], *gn3s = (const float*)d_in[23];
    const float *lw   = (const float*)d_in[24], *lb   = (const float*)d_in[25];

    char* ws = (char*)d_ws;
    size_t off = 0;
    auto alloc = [&](size_t bytes) -> void* {
        void* p = ws + off;
        off += (bytes + 255) & ~(size_t)255;
        return p;
    };
    __half* Ah  = (__half*)alloc((size_t)NN * 128 * 2);  // x_l fp16 (GEMM out, attn gather operand)
    __half* Xh  = (__half*)alloc((size_t)NN * 128 * 2);  // GEMM fp16 input (cast of x / gnnorm out)
    float*  B   = (float*)alloc((size_t)NN * 128 * 4);   // x_r / layer-out scratch
    float*  Cb  = (float*)alloc((size_t)NN * 64 * 4);    // h2 scratch
    float*  Af  = (float*)alloc((size_t)NN * 8 * 4);     // layer-3 final node features
    _Float16* Wf1 = (_Float16*)alloc((size_t)256 * 128 * 2);  // frag-ordered weights l1
    _Float16* Wf2 = (_Float16*)alloc((size_t)128 * 128 * 2);  // l2
    _Float16* Wf3 = (_Float16*)alloc((size_t)64 * 64 * 2);    // l3
    int* rowptr = (int*)alloc((size_t)(NN + 1) * 4);
    int* cursor = (int*)alloc((size_t)NN * PAD * 4);     // line-padded
    unsigned short* colsrc = (unsigned short*)alloc((size_t)ET * 2);
    int* bpos   = (int*)alloc((size_t)(NG + 1) * 4);
    int* cnt    = (int*)alloc((size_t)NG * 4);
    int* bsum   = (int*)alloc((size_t)NB * 4);
    int* boff   = (int*)alloc((size_t)NB * 4);
    char* zbase = ws + off;                              // everything below gets one memset
    int*   deg  = (int*)alloc((size_t)NN * PAD * 4);     // line-padded
    float* sum1 = (float*)alloc((size_t)NG * 128 * 4);
    float* sq1  = (float*)alloc((size_t)NG * 128 * 4);
    float* sum2 = (float*)alloc((size_t)NG * 64 * 4);
    float* sq2  = (float*)alloc((size_t)NG * 64 * 4);
    float* sum3 = (float*)alloc((size_t)NG * 8 * 4);
    float* sq3  = (float*)alloc((size_t)NG * 8 * 4);
    float* pool = (float*)alloc((size_t)NG * 8 * 4);
    size_t zbytes = (size_t)((ws + off) - zbase);
    (void)hipMemsetAsync(zbase, 0, zbytes, stream);

    int gE = (ET + 255) / 256;
    k_cast<<<(NN * 128 / 8 + 255) / 256, 256, 0, stream>>>(x, Xh);
    k_wprep_all<<<26, 256, 0, stream>>>(w_l1, w_r1, w_l2, w_r2, w_l3, w_r3, Wf1, Wf2, Wf3);
    k_count<<<gE, 256, 0, stream>>>(ei, deg);
    k_bounds<<<(NN + 255) / 256, 256, 0, stream>>>(batch, bpos);
    k_blksum<<<NB, 256, 0, stream>>>(deg, bsum);
    k_scanb<<<1, 256, 0, stream>>>(bsum, boff, bpos, cnt);
    k_scanc<<<NB, 256, 0, stream>>>(deg, boff, rowptr, cursor);
    k_scatter<<<gE, 256, 0, stream>>>(ei, cursor, colsrc);

    int gA4 = (NN * H * 4) / 256;            // attention grid, EP=4 -> 3125 blocks exact
    int gG  = (NN + 63) / 64;                // gn-reduce grid, 64 nodes/block
    int gD  = (NN + 63) / 64;                // dualgemm grid, 64 rows/block

    // ---- layer 1: 128 -> 4x32 concat -> 128
    k_dualgemm<128, 128><<<gD, 256, 0, stream>>>(Xh, Wf1, Ah, B);
    k_attn<32, 4, true><<<gA4, 256, 0, stream>>>(Ah, B, rowptr, colsrc, att1, b1, B);
    k_gnred<7><<<gG, 256, 0, stream>>>(B, batch, sum1, sq1);
    k_gnnorm<<<(NN * 128 + 255) / 256, 256, 0, stream>>>(B, batch, sum1, sq1, cnt, gn1w, gn1b, gn1s, 7, Xh);

    // ---- layer 2: 128 -> 4x16 concat -> 64
    k_dualgemm<128, 64><<<gD, 256, 0, stream>>>(Xh, Wf2, Ah, Cb);
    k_attn<16, 4, true><<<gA4, 256, 0, stream>>>(Ah, Cb, rowptr, colsrc, att2, b2, Cb);
    k_gnred<6><<<gG, 256, 0, stream>>>(Cb, batch, sum2, sq2);
    k_gnnorm<<<(NN * 64 + 255) / 256, 256, 0, stream>>>(Cb, batch, sum2, sq2, cnt, gn2w, gn2b, gn2s, 6, Xh);

    // ---- layer 3: 64 -> 4x8 mean -> 8
    k_dualgemm<64, 32><<<gD, 256, 0, stream>>>(Xh, Wf3, Ah, B);
    k_attn<8, 4, false><<<gA4, 256, 0, stream>>>(Ah, B, rowptr, colsrc, att3, nullptr, B);
    k_headmean<<<(NN * 8 + 255) / 256, 256, 0, stream>>>(B, b3, Af);
    k_gnred<3><<<gG, 256, 0, stream>>>(Af, batch, sum3, sq3);
    k_gnnorm<<<(NN * 8 + 255) / 256, 256, 0, stream>>>(Af, batch, sum3, sq3, cnt, gn3w, gn3b, gn3s, 3, nullptr);

    // ---- global mean pool + linear
    k_gnred<3><<<gG, 256, 0, stream>>>(Af, batch, pool, sq3);  // sq3 as throwaway sumsq
    k_final<<<1, 512, 0, stream>>>(pool, cnt, lw, lb, (float*)d_out);
}

// Round 11
// 442.981 us; speedup vs baseline: 1.1448x; 1.1448x over previous
//
#include <hip/hip_runtime.h>
#include <hip/hip_fp16.h>
#include <math.h>

#define NN 50000
#define NE 800000
#define ET (NE + NN)
#define NG 64
#define H 4
#define NB ((NN + 255) / 256)     // 196 blocks of 256 nodes
#define NBK 196                   // dst buckets (dst >> 8)
#define CH 4096                   // edges per chunk
#define SB ((ET + CH - 1) / CH)   // 208 edge chunks

typedef _Float16 half8 __attribute__((ext_vector_type(8)));
typedef _Float16 hv2 __attribute__((ext_vector_type(2)));
typedef float floatx4 __attribute__((ext_vector_type(4)));

// ---------------- CSR build: two-level bucketed counting sort, LDS atomics only ----------------

__device__ __forceinline__ void edge_sd(int e, const int* __restrict__ ei, int& s, int& d) {
    if (e < NE) { s = ei[e]; d = ei[NE + e]; } else { s = e - NE; d = s; }
}

// Phase 1: per-(chunk, bucket) histogram.  bcnt layout: [bucket * SB + chunk]
__global__ __launch_bounds__(256) void k_bhist(const int* __restrict__ ei, int* __restrict__ bcnt) {
    __shared__ int hist[NBK];
    int b0 = blockIdx.x, tid = threadIdx.x;
    for (int i = tid; i < NBK; i += 256) hist[i] = 0;
    __syncthreads();
#pragma unroll
    for (int pass = 0; pass < CH / 256; ++pass) {
        int e = b0 * CH + pass * 256 + tid;
        if (e < ET) {
            int d = (e < NE) ? ei[NE + e] : (e - NE);
            atomicAdd(&hist[d >> 8], 1);
        }
    }
    __syncthreads();
    if (tid < NBK) bcnt[tid * SB + b0] = hist[tid];
}

// Phase 2a: per-bucket exclusive scan over its SB chunk-counts (coalesced). tot[b] = bucket total.
__global__ __launch_bounds__(256) void k_bscanA(const int* __restrict__ bcnt, int* __restrict__ boff,
                                                int* __restrict__ tot) {
    __shared__ int lds[256];
    int b = blockIdx.x, t = threadIdx.x;
    int v = (t < SB) ? bcnt[b * SB + t] : 0;
    lds[t] = v;
    __syncthreads();
    for (int off = 1; off < 256; off <<= 1) {
        int y = (t >= off) ? lds[t - off] : 0;
        __syncthreads();
        lds[t] += y;
        __syncthreads();
    }
    if (t < SB) boff[b * SB + t] = lds[t] - v;   // exclusive within bucket
    if (t == 255) tot[b] = lds[255];
}

// Phase 2b: scan bucket totals -> ebase; fold per-graph counts from bpos.
__global__ __launch_bounds__(256) void k_bscanB(const int* __restrict__ tot, int* __restrict__ ebase,
                                                const int* __restrict__ bpos, int* __restrict__ cnt) {
    __shared__ int lds[256];
    int t = threadIdx.x;
    int v = (t < NBK) ? tot[t] : 0;
    lds[t] = v;
    __syncthreads();
    for (int off = 1; off < 256; off <<= 1) {
        int y = (t >= off) ? lds[t - off] : 0;
        __syncthreads();
        lds[t] += y;
        __syncthreads();
    }
    if (t < NBK) ebase[t] = lds[t] - v;
    if (t == 0) ebase[NBK] = ET;
    if (t < NG) cnt[t] = bpos[t + 1] - bpos[t];
}

// batch is sorted: graph boundaries without atomics.
__global__ __launch_bounds__(256) void k_bounds(const int* __restrict__ batch, int* __restrict__ bpos) {
    int i = blockIdx.x * 256 + threadIdx.x;
    if (i >= NN) return;
    int cur = batch[i];
    int prev = (i == 0) ? -1 : batch[i - 1];
    for (int g = prev + 1; g <= cur; ++g) bpos[g] = i;
    if (i == NN - 1)
        for (int g = cur + 1; g <= NG; ++g) bpos[g] = NN;
}

// Phase 3: scatter edges into bucket-major ebuf. Each block's target sub-regions are private
// (pre-assigned offsets) -> no cross-block line ping-pong, no global atomics.
// ebuf entry: (src << 16) | (dst & 255)
__global__ __launch_bounds__(256) void k_bscatter(const int* __restrict__ ei, const int* __restrict__ ebase,
                                                  const int* __restrict__ boff, unsigned int* __restrict__ ebuf) {
    __shared__ int cur[NBK];
    int b0 = blockIdx.x, tid = threadIdx.x;
    for (int i = tid; i < NBK; i += 256) cur[i] = ebase[i] + boff[i * SB + b0];
    __syncthreads();
#pragma unroll
    for (int pass = 0; pass < CH / 256; ++pass) {
        int e = b0 * CH + pass * 256 + tid;
        if (e < ET) {
            int s, d;
            edge_sd(e, ei, s, d);
            int pos = atomicAdd(&cur[d >> 8], 1);
            ebuf[pos] = ((unsigned)s << 16) | (unsigned)(d & 255);
        }
    }
}

// Phase 4: one block per bucket. Exact-dst LDS counting sort -> rowptr + colsrc (contiguous,
// block-private output region).
__global__ __launch_bounds__(256) void k_bsort(const unsigned int* __restrict__ ebuf,
                                               const int* __restrict__ ebase,
                                               int* __restrict__ rowptr, unsigned short* __restrict__ colsrc) {
    __shared__ int cnt2[256];
    __shared__ int sc[256];
    __shared__ int cur2[256];
    int b = blockIdx.x, t = threadIdx.x;
    int base = ebase[b], n = ebase[b + 1] - base;
    cnt2[t] = 0;
    __syncthreads();
    for (int i = t; i < n; i += 256) atomicAdd(&cnt2[ebuf[base + i] & 255], 1);
    __syncthreads();
    int v = cnt2[t];
    sc[t] = v;
    __syncthreads();
    for (int off = 1; off < 256; off <<= 1) {
        int y = (t >= off) ? sc[t - off] : 0;
        __syncthreads();
        sc[t] += y;
        __syncthreads();
    }
    int excl = sc[t] - v;
    int d = b * 256 + t;
    if (d < NN) rowptr[d] = base + excl;
    if (b == 0 && t == 0) rowptr[NN] = ET;
    cur2[t] = excl;
    __syncthreads();
    for (int i = t; i < n; i += 256) {
        unsigned u = ebuf[base + i];
        int pos = atomicAdd(&cur2[u & 255], 1);
        colsrc[base + pos] = (unsigned short)(u >> 16);
    }
}

// ---------------- fp32 -> fp16 cast (layer-1 GEMM input) ----------------

__global__ __launch_bounds__(256) void k_cast(const float* __restrict__ x, __half* __restrict__ xh) {
    int i = blockIdx.x * 256 + threadIdx.x;       // one thread = 8 elements; NN*128 % 8 == 0
    size_t base = (size_t)i * 8;
    if (base >= (size_t)NN * 128) return;
    const float4* p = (const float4*)(x + base);
    float4 a = p[0], b = p[1];
    half8 h;
    h[0] = (_Float16)a.x; h[1] = (_Float16)a.y; h[2] = (_Float16)a.z; h[3] = (_Float16)a.w;
    h[4] = (_Float16)b.x; h[5] = (_Float16)b.y; h[6] = (_Float16)b.z; h[7] = (_Float16)b.w;
    *(half8*)(xh + base) = h;
}

// ---------------- weight prep: fp32 [K][M2]x2 -> fp16 MFMA-fragment order (all 3 layers fused) ----------------

template <int K, int M2>
__device__ __forceinline__ void wprep_fn(int chunk, const float* __restrict__ Wl, const float* __restrict__ Wr,
                                         _Float16* __restrict__ Wfrag) {
    constexpr int MTOT = 2 * M2, NT = MTOT / 16;
    if (chunk >= MTOT * K / 8) return;
    int lane = chunk & 63, tt = chunk >> 6;
    int t = tt % NT, kt = tt / NT;
    int n = t * 16 + (lane & 15);
    int kb = kt * 32 + (lane >> 4) * 8;
    const float* src = (n < M2) ? (Wl + n) : (Wr + (n - M2));
    half8 h;
#pragma unroll
    for (int j = 0; j < 8; ++j) h[j] = (_Float16)src[(size_t)(kb + j) * M2];
    *(half8*)(Wfrag + (size_t)chunk * 8) = h;
}

__global__ __launch_bounds__(256) void k_wprep_all(const float* __restrict__ Wl1, const float* __restrict__ Wr1,
                                                   const float* __restrict__ Wl2, const float* __restrict__ Wr2,
                                                   const float* __restrict__ Wl3, const float* __restrict__ Wr3,
                                                   _Float16* __restrict__ Wf1, _Float16* __restrict__ Wf2,
                                                   _Float16* __restrict__ Wf3) {
    int b = blockIdx.x, t = threadIdx.x;
    if (b < 16)      wprep_fn<128, 128>(b * 256 + t, Wl1, Wr1, Wf1);
    else if (b < 24) wprep_fn<128, 64>((b - 16) * 256 + t, Wl2, Wr2, Wf2);
    else             wprep_fn<64, 32>((b - 24) * 256 + t, Wl3, Wr3, Wf3);
}

// ---------------- fused dual MFMA GEMM, LDS-free ----------------

template <int K, int M2>
__global__ __launch_bounds__(256) void k_dualgemm(const __half* __restrict__ Ain,
                                                  const _Float16* __restrict__ Wfrag,
                                                  __half* __restrict__ Ol, float* __restrict__ Or) {
    constexpr int MTOT = 2 * M2;
    constexpr int NT = MTOT / 16;
    constexpr int KT = K / 32;
    int tid = threadIdx.x;
    int wid = tid >> 6, lane = tid & 63;
    int q = lane >> 4, l15 = lane & 15;
    int r0 = blockIdx.x * 64 + wid * 16;
    int arow = min(r0 + l15, NN - 1);
    const _Float16* A = (const _Float16*)Ain;
    const _Float16* ap = A + (size_t)arow * K + q * 8;

    floatx4 acc[NT];
#pragma unroll
    for (int t = 0; t < NT; ++t) acc[t] = (floatx4){0.f, 0.f, 0.f, 0.f};

#pragma unroll
    for (int kt = 0; kt < KT; ++kt) {
        half8 a8 = *(const half8*)(ap + kt * 32);
        const _Float16* wp = Wfrag + ((size_t)(kt * NT) * 64 + lane) * 8;
#pragma unroll
        for (int t = 0; t < NT; ++t) {
            half8 b8 = *(const half8*)(wp + (size_t)t * 64 * 8);
            acc[t] = __builtin_amdgcn_mfma_f32_16x16x32_f16(a8, b8, acc[t], 0, 0, 0);
        }
    }

#pragma unroll
    for (int t = 0; t < NT; ++t) {
        int cn = t * 16 + l15;
#pragma unroll
        for (int reg = 0; reg < 4; ++reg) {
            int r = r0 + q * 4 + reg;
            if (r < NN) {
                if (cn < M2) Ol[(size_t)r * M2 + cn] = __float2half(acc[t][reg]);
                else         Or[(size_t)r * M2 + (cn - M2)] = acc[t][reg];
            }
        }
    }
}

// ---------------- GATv2 attention: channel-split + packed fp16 + no-max softmax ----------------

template <int CP> struct HVec { hv2 h2[CP / 2]; };

template <int CP>
__device__ __forceinline__ HVec<CP> load_hv(const __half* __restrict__ p) {
    HVec<CP> r;
    if constexpr (CP == 8) { float4 t = *(const float4*)p; r = *(HVec<CP>*)&t; }
    else if constexpr (CP == 4) { float2 t = *(const float2*)p; r = *(HVec<CP>*)&t; }
    else { r.h2[0] = *(const hv2*)p; }
    return r;
}

template <int C, int EP, bool CONCAT>
__global__ __launch_bounds__(256, 4) void k_attn(const __half* __restrict__ xl, const float* __restrict__ xr,
                                                 const int* __restrict__ rowptr,
                                                 const unsigned short* __restrict__ colsrc,
                                                 const float* __restrict__ att, const float* __restrict__ bias,
                                                 float* __restrict__ out) {
    constexpr int CP = C / EP;
    int t = blockIdx.x * 256 + threadIdx.x;
    int part = t & (EP - 1);
    int nh = t >> 2;                          // EP == 4
    if (nh >= NN * H) return;
    int node = nh >> 2, h = nh & 3;           // H == 4
    int cbase = h * C + part * CP;
    hv2 xrr2[CP / 2], attv2[CP / 2];
    float acc[CP];
    {
        const float* p = xr + (size_t)node * (H * C) + cbase;
        const float* q = att + cbase;
#pragma unroll
        for (int j = 0; j < CP / 2; ++j) {
            xrr2[j] = (hv2){(_Float16)p[2 * j], (_Float16)p[2 * j + 1]};
            attv2[j] = (hv2){(_Float16)q[2 * j], (_Float16)q[2 * j + 1]};
        }
#pragma unroll
        for (int c = 0; c < CP; ++c) acc[c] = 0.f;
    }
    float denom = 0.f;
    int beg = rowptr[node], end = rowptr[node + 1];

    auto process = [&](const HVec<CP>& xv) {
        float part_s = 0.f;
#pragma unroll
        for (int j = 0; j < CP / 2; ++j) {
            hv2 z = xv.h2[j] + xrr2[j];
            hv2 l = __builtin_elementwise_max(z, z * (_Float16)0.2f);   // leaky_relu
            part_s = __builtin_amdgcn_fdot2(l, attv2[j], part_s, false);
        }
        float score = part_s;
#pragma unroll
        for (int mask = 1; mask < EP; mask <<= 1) score += __shfl_xor(score, mask, 64);
        float w = __expf(score);
        denom += w;
        const _Float16* xh = (const _Float16*)&xv;
#pragma unroll
        for (int c = 0; c < CP; ++c) acc[c] = fmaf(w, (float)xh[c], acc[c]);
    };

    int idx = beg;
    for (; idx + 2 <= end; idx += 2) {
        int s0 = colsrc[idx], s1 = colsrc[idx + 1];
        HVec<CP> xv0 = load_hv<CP>(xl + (size_t)s0 * (H * C) + cbase);
        HVec<CP> xv1 = load_hv<CP>(xl + (size_t)s1 * (H * C) + cbase);
        process(xv0);
        process(xv1);
    }
    if (idx < end) {
        int s = colsrc[idx];
        HVec<CP> xv = load_hv<CP>(xl + (size_t)s * (H * C) + cbase);
        process(xv);
    }

    float inv = 1.f / denom;
    float* op = out + (size_t)node * (H * C) + cbase;
    float v[CP];
#pragma unroll
    for (int c = 0; c < CP; ++c) {
        v[c] = acc[c] * inv;
        if (CONCAT) v[c] += bias[cbase + c];
    }
    if constexpr (CP == 8) {
        *(float4*)(op) = make_float4(v[0], v[1], v[2], v[3]);
        *(float4*)(op + 4) = make_float4(v[4], v[5], v[6], v[7]);
    } else if constexpr (CP == 4) {
        *(float4*)(op) = make_float4(v[0], v[1], v[2], v[3]);
    } else {
        *(float2*)(op) = make_float2(v[0], v[1]);
    }
}

// ---------------- GraphNorm ----------------

template <int LOGC>
__global__ __launch_bounds__(256) void k_gnred(const float* __restrict__ h, const int* __restrict__ batch,
                                               float* __restrict__ sum, float* __restrict__ sumsq) {
    constexpr int C = 1 << LOGC;
    constexpr int ROWS = 256 >> LOGC;
    constexpr int NPB = 64;
    int c = threadIdx.x & (C - 1);
    int row = threadIdx.x >> LOGC;
    int base = blockIdx.x * NPB;
    int curg = -1;
    float s = 0.f, ss = 0.f;
#pragma unroll
    for (int r = row; r < NPB; r += ROWS) {
        int nd = base + r;
        if (nd >= NN) break;
        int g = batch[nd];
        if (g != curg) {
            if (curg >= 0) { atomicAdd(&sum[curg * C + c], s); atomicAdd(&sumsq[curg * C + c], ss); }
            curg = g; s = 0.f; ss = 0.f;
        }
        float x = h[(size_t)nd * C + c];
        s += x; ss += x * x;
    }
    if (curg >= 0) { atomicAdd(&sum[curg * C + c], s); atomicAdd(&sumsq[curg * C + c], ss); }
}

// var(out) = E[x^2] - (2s - s^2) mu^2  where out = x - mu*s; optional fp16 copy for next GEMM
__global__ __launch_bounds__(256) void k_gnnorm(float* __restrict__ h, const int* __restrict__ batch,
                                                const float* __restrict__ sum, const float* __restrict__ sumsq,
                                                const int* __restrict__ cnt, const float* __restrict__ w,
                                                const float* __restrict__ b, const float* __restrict__ ms,
                                                int logC, __half* __restrict__ h16) {
    int C = 1 << logC;
    int i = blockIdx.x * 256 + threadIdx.x;
    if (i >= NN * C) return;
    int nd = i >> logC, c = i & (C - 1);
    int g = batch[nd];
    float cg = fmaxf((float)cnt[g], 1.f);
    float mu = sum[g * C + c] / cg;
    float ex2 = sumsq[g * C + c] / cg;
    float s_ = ms[c];
    float var = ex2 - (2.f * s_ - s_ * s_) * mu * mu;
    float y = (h[i] - mu * s_) * rsqrtf(var + 1e-5f) * w[c] + b[c];
    y = fmaxf(y, 0.f);   // fused ReLU
    h[i] = y;
    if (h16) h16[i] = __float2half(y);
}

// ---------------- layer-3 head mean + bias ----------------

__global__ __launch_bounds__(256) void k_headmean(const float* __restrict__ tmp, const float* __restrict__ b3,
                                                  float* __restrict__ out) {
    int i = blockIdx.x * 256 + threadIdx.x;
    if (i >= NN * 8) return;
    int nd = i >> 3, c = i & 7;
    const float* p = tmp + (size_t)nd * 32 + c;
    out[i] = 0.25f * (p[0] + p[8] + p[16] + p[24]) + b3[c];
}

// ---------------- pool mean + linear head ----------------

__global__ __launch_bounds__(512) void k_final(const float* __restrict__ pool, const int* __restrict__ cnt,
                                               const float* __restrict__ lw, const float* __restrict__ lb,
                                               float* __restrict__ outp) {
    __shared__ float feat[512];
    int t = threadIdx.x;
    int g = t >> 3;
    float f = pool[t] / fmaxf((float)cnt[g], 1.f);
    feat[t] = f;
    outp[256 + t] = f;          // features: d_out[256 .. 768)
    __syncthreads();
    if (t < 256) {
        int g2 = t >> 2, o = t & 3;
        float a = lb[o];
#pragma unroll
        for (int cc = 0; cc < 8; ++cc) a += feat[g2 * 8 + cc] * lw[cc * 4 + o];
        outp[t] = a;            // logits: d_out[0 .. 256)
    }
}

// ---------------- host ----------------

extern "C" void kernel_launch(void* const* d_in, const int* in_sizes, int n_in,
                              void* d_out, int out_size, void* d_ws, size_t ws_size,
                              hipStream_t stream) {
    const float* x    = (const float*)d_in[0];
    const int*   ei   = (const int*)d_in[1];
    const int*   batch= (const int*)d_in[2];
    const float *w_l1 = (const float*)d_in[3],  *w_r1 = (const float*)d_in[4];
    const float *att1 = (const float*)d_in[5],  *b1   = (const float*)d_in[6];
    const float *gn1w = (const float*)d_in[7],  *gn1b = (const float*)d_in[8],  *gn1s = (const float*)d_in[9];
    const float *w_l2 = (const float*)d_in[10], *w_r2 = (const float*)d_in[11];
    const float *att2 = (const float*)d_in[12], *b2   = (const float*)d_in[13];
    const float *gn2w = (const float*)d_in[14], *gn2b = (const float*)d_in[15], *gn2s = (const float*)d_in[16];
    const float *w_l3 = (const float*)d_in[17], *w_r3 = (const float*)d_in[18];
    const float *att3 = (const float*)d_in[19], *b3   = (const float*)d_in[20];
    const float *gn3w = (const float*)d_in[21], *gn3b = (const float*)d_in[22], *gn3s = (const float*)d_in[23];
    const float *lw   = (const float*)d_in[24], *lb   = (const float*)d_in[25];

    char* ws = (char*)d_ws;
    size_t off = 0;
    auto alloc = [&](size_t bytes) -> void* {
        void* p = ws + off;
        off += (bytes + 255) & ~(size_t)255;
        return p;
    };
    __half* Ah  = (__half*)alloc((size_t)NN * 128 * 2);  // x_l fp16 (GEMM out, attn gather operand)
    __half* Xh  = (__half*)alloc((size_t)NN * 128 * 2);  // GEMM fp16 input (cast of x / gnnorm out)
    float*  B   = (float*)alloc((size_t)NN * 128 * 4);   // x_r / layer-out scratch
    float*  Cb  = (float*)alloc((size_t)NN * 64 * 4);    // h2 scratch
    float*  Af  = (float*)alloc((size_t)NN * 8 * 4);     // layer-3 final node features
    _Float16* Wf1 = (_Float16*)alloc((size_t)256 * 128 * 2);  // frag-ordered weights l1
    _Float16* Wf2 = (_Float16*)alloc((size_t)128 * 128 * 2);  // l2
    _Float16* Wf3 = (_Float16*)alloc((size_t)64 * 64 * 2);    // l3
    int* rowptr = (int*)alloc((size_t)(NN + 1) * 4);
    unsigned short* colsrc = (unsigned short*)alloc((size_t)ET * 2);
    unsigned int* ebuf = (unsigned int*)alloc((size_t)ET * 4);
    int* bcnt   = (int*)alloc((size_t)NBK * SB * 4);
    int* boff   = (int*)alloc((size_t)NBK * SB * 4);
    int* tot    = (int*)alloc((size_t)NBK * 4);
    int* ebase  = (int*)alloc((size_t)(NBK + 1) * 4);
    int* bpos   = (int*)alloc((size_t)(NG + 1) * 4);
    int* cnt    = (int*)alloc((size_t)NG * 4);
    char* zbase = ws + off;                              // everything below gets one memset
    float* sum1 = (float*)alloc((size_t)NG * 128 * 4);
    float* sq1  = (float*)alloc((size_t)NG * 128 * 4);
    float* sum2 = (float*)alloc((size_t)NG * 64 * 4);
    float* sq2  = (float*)alloc((size_t)NG * 64 * 4);
    float* sum3 = (float*)alloc((size_t)NG * 8 * 4);
    float* sq3  = (float*)alloc((size_t)NG * 8 * 4);
    float* pool = (float*)alloc((size_t)NG * 8 * 4);
    size_t zbytes = (size_t)((ws + off) - zbase);
    (void)hipMemsetAsync(zbase, 0, zbytes, stream);

    k_cast<<<(NN * 128 / 8 + 255) / 256, 256, 0, stream>>>(x, Xh);
    k_wprep_all<<<26, 256, 0, stream>>>(w_l1, w_r1, w_l2, w_r2, w_l3, w_r3, Wf1, Wf2, Wf3);
    k_bounds<<<(NN + 255) / 256, 256, 0, stream>>>(batch, bpos);
    k_bhist<<<SB, 256, 0, stream>>>(ei, bcnt);
    k_bscanA<<<NBK, 256, 0, stream>>>(bcnt, boff, tot);
    k_bscanB<<<1, 256, 0, stream>>>(tot, ebase, bpos, cnt);
    k_bscatter<<<SB, 256, 0, stream>>>(ei, ebase, boff, ebuf);
    k_bsort<<<NBK, 256, 0, stream>>>(ebuf, ebase, rowptr, colsrc);

    int gA4 = (NN * H * 4) / 256;            // attention grid, EP=4 -> 3125 blocks exact
    int gG  = (NN + 63) / 64;                // gn-reduce grid, 64 nodes/block
    int gD  = (NN + 63) / 64;                // dualgemm grid, 64 rows/block

    // ---- layer 1: 128 -> 4x32 concat -> 128
    k_dualgemm<128, 128><<<gD, 256, 0, stream>>>(Xh, Wf1, Ah, B);
    k_attn<32, 4, true><<<gA4, 256, 0, stream>>>(Ah, B, rowptr, colsrc, att1, b1, B);
    k_gnred<7><<<gG, 256, 0, stream>>>(B, batch, sum1, sq1);
    k_gnnorm<<<(NN * 128 + 255) / 256, 256, 0, stream>>>(B, batch, sum1, sq1, cnt, gn1w, gn1b, gn1s, 7, Xh);

    // ---- layer 2: 128 -> 4x16 concat -> 64
    k_dualgemm<128, 64><<<gD, 256, 0, stream>>>(Xh, Wf2, Ah, Cb);
    k_attn<16, 4, true><<<gA4, 256, 0, stream>>>(Ah, Cb, rowptr, colsrc, att2, b2, Cb);
    k_gnred<6><<<gG, 256, 0, stream>>>(Cb, batch, sum2, sq2);
    k_gnnorm<<<(NN * 64 + 255) / 256, 256, 0, stream>>>(Cb, batch, sum2, sq2, cnt, gn2w, gn2b, gn2s, 6, Xh);

    // ---- layer 3: 64 -> 4x8 mean -> 8
    k_dualgemm<64, 32><<<gD, 256, 0, stream>>>(Xh, Wf3, Ah, B);
    k_attn<8, 4, false><<<gA4, 256, 0, stream>>>(Ah, B, rowptr, colsrc, att3, nullptr, B);
    k_headmean<<<(NN * 8 + 255) / 256, 256, 0, stream>>>(B, b3, Af);
    k_gnred<3><<<gG, 256, 0, stream>>>(Af, batch, sum3, sq3);
    k_gnnorm<<<(NN * 8 + 255) / 256, 256, 0, stream>>>(Af, batch, sum3, sq3, cnt, gn3w, gn3b, gn3s, 3, nullptr);

    // ---- global mean pool + linear
    k_gnred<3><<<gG, 256, 0, stream>>>(Af, batch, pool, sq3);  // sq3 as throwaway sumsq
    k_final<<<1, 512, 0, stream>>>(pool, cnt, lw, lb, (float*)d_out);
}

// Round 12
// 360.907 us; speedup vs baseline: 1.4051x; 1.2274x over previous
//
#include <hip/hip_runtime.h>
#include <hip/hip_fp16.h>
#include <math.h>

#define NN 50000
#define NE 800000
#define ET (NE + NN)
#define NG 64
#define H 4
#define NBK 196                   // dst buckets (dst >> 8)
#define CH 4096                   // edges per chunk
#define SB ((ET + CH - 1) / CH)   // 208 edge chunks

typedef _Float16 half8 __attribute__((ext_vector_type(8)));
typedef _Float16 hv2 __attribute__((ext_vector_type(2)));
typedef float floatx4 __attribute__((ext_vector_type(4)));

// ---------------- CSR build: two-level bucketed counting sort, LDS atomics only ----------------

__device__ __forceinline__ void edge_sd(int e, const int* __restrict__ ei, int& s, int& d) {
    if (e < NE) { s = ei[e]; d = ei[NE + e]; } else { s = e - NE; d = s; }
}

// Phase 1: per-(chunk, bucket) histogram.  bcnt layout: [bucket * SB + chunk]
__global__ __launch_bounds__(256) void k_bhist(const int* __restrict__ ei, int* __restrict__ bcnt) {
    __shared__ int hist[NBK];
    int b0 = blockIdx.x, tid = threadIdx.x;
    for (int i = tid; i < NBK; i += 256) hist[i] = 0;
    __syncthreads();
#pragma unroll
    for (int pass = 0; pass < CH / 256; ++pass) {
        int e = b0 * CH + pass * 256 + tid;
        if (e < ET) {
            int d = (e < NE) ? ei[NE + e] : (e - NE);
            atomicAdd(&hist[d >> 8], 1);
        }
    }
    __syncthreads();
    if (tid < NBK) bcnt[tid * SB + b0] = hist[tid];
}

// Phase 2a: per-bucket exclusive scan over its SB chunk-counts (coalesced). tot[b] = bucket total.
__global__ __launch_bounds__(256) void k_bscanA(const int* __restrict__ bcnt, int* __restrict__ boff,
                                                int* __restrict__ tot) {
    __shared__ int lds[256];
    int b = blockIdx.x, t = threadIdx.x;
    int v = (t < SB) ? bcnt[b * SB + t] : 0;
    lds[t] = v;
    __syncthreads();
    for (int off = 1; off < 256; off <<= 1) {
        int y = (t >= off) ? lds[t - off] : 0;
        __syncthreads();
        lds[t] += y;
        __syncthreads();
    }
    if (t < SB) boff[b * SB + t] = lds[t] - v;   // exclusive within bucket
    if (t == 255) tot[b] = lds[255];
}

// Phase 2b: scan bucket totals -> ebase; fold per-graph counts from bpos.
__global__ __launch_bounds__(256) void k_bscanB(const int* __restrict__ tot, int* __restrict__ ebase,
                                                const int* __restrict__ bpos, int* __restrict__ cnt) {
    __shared__ int lds[256];
    int t = threadIdx.x;
    int v = (t < NBK) ? tot[t] : 0;
    lds[t] = v;
    __syncthreads();
    for (int off = 1; off < 256; off <<= 1) {
        int y = (t >= off) ? lds[t - off] : 0;
        __syncthreads();
        lds[t] += y;
        __syncthreads();
    }
    if (t < NBK) ebase[t] = lds[t] - v;
    if (t == 0) ebase[NBK] = ET;
    if (t < NG) cnt[t] = bpos[t + 1] - bpos[t];
}

// batch is sorted: graph boundaries without atomics.
__global__ __launch_bounds__(256) void k_bounds(const int* __restrict__ batch, int* __restrict__ bpos) {
    int i = blockIdx.x * 256 + threadIdx.x;
    if (i >= NN) return;
    int cur = batch[i];
    int prev = (i == 0) ? -1 : batch[i - 1];
    for (int g = prev + 1; g <= cur; ++g) bpos[g] = i;
    if (i == NN - 1)
        for (int g = cur + 1; g <= NG; ++g) bpos[g] = NN;
}

// Phase 3: scatter edges into bucket-major ebuf. Block-private offsets -> no global atomics.
// ebuf entry: (src << 16) | (dst & 255)
__global__ __launch_bounds__(256) void k_bscatter(const int* __restrict__ ei, const int* __restrict__ ebase,
                                                  const int* __restrict__ boff, unsigned int* __restrict__ ebuf) {
    __shared__ int cur[NBK];
    int b0 = blockIdx.x, tid = threadIdx.x;
    for (int i = tid; i < NBK; i += 256) cur[i] = ebase[i] + boff[i * SB + b0];
    __syncthreads();
#pragma unroll
    for (int pass = 0; pass < CH / 256; ++pass) {
        int e = b0 * CH + pass * 256 + tid;
        if (e < ET) {
            int s, d;
            edge_sd(e, ei, s, d);
            int pos = atomicAdd(&cur[d >> 8], 1);
            ebuf[pos] = ((unsigned)s << 16) | (unsigned)(d & 255);
        }
    }
}

// Phase 4: one block per bucket. Exact-dst LDS counting sort -> rowptr + colsrc.
__global__ __launch_bounds__(256) void k_bsort(const unsigned int* __restrict__ ebuf,
                                               const int* __restrict__ ebase,
                                               int* __restrict__ rowptr, unsigned short* __restrict__ colsrc) {
    __shared__ int cnt2[256];
    __shared__ int sc[256];
    __shared__ int cur2[256];
    int b = blockIdx.x, t = threadIdx.x;
    int base = ebase[b], n = ebase[b + 1] - base;
    cnt2[t] = 0;
    __syncthreads();
    for (int i = t; i < n; i += 256) atomicAdd(&cnt2[ebuf[base + i] & 255], 1);
    __syncthreads();
    int v = cnt2[t];
    sc[t] = v;
    __syncthreads();
    for (int off = 1; off < 256; off <<= 1) {
        int y = (t >= off) ? sc[t - off] : 0;
        __syncthreads();
        sc[t] += y;
        __syncthreads();
    }
    int excl = sc[t] - v;
    int d = b * 256 + t;
    if (d < NN) rowptr[d] = base + excl;
    if (b == 0 && t == 0) rowptr[NN] = ET;
    cur2[t] = excl;
    __syncthreads();
    for (int i = t; i < n; i += 256) {
        unsigned u = ebuf[base + i];
        int pos = atomicAdd(&cur2[u & 255], 1);
        colsrc[base + pos] = (unsigned short)(u >> 16);
    }
}

// ---------------- fp32 -> fp16 cast (layer-1 GEMM input) ----------------

__global__ __launch_bounds__(256) void k_cast(const float* __restrict__ x, __half* __restrict__ xh) {
    int i = blockIdx.x * 256 + threadIdx.x;       // one thread = 8 elements; NN*128 % 8 == 0
    size_t base = (size_t)i * 8;
    if (base >= (size_t)NN * 128) return;
    const float4* p = (const float4*)(x + base);
    float4 a = p[0], b = p[1];
    half8 h;
    h[0] = (_Float16)a.x; h[1] = (_Float16)a.y; h[2] = (_Float16)a.z; h[3] = (_Float16)a.w;
    h[4] = (_Float16)b.x; h[5] = (_Float16)b.y; h[6] = (_Float16)b.z; h[7] = (_Float16)b.w;
    *(half8*)(xh + base) = h;
}

// ---------------- weight prep: fp32 [K][M2]x2 -> fp16 MFMA-fragment order (all 3 layers fused) ----------------

template <int K, int M2>
__device__ __forceinline__ void wprep_fn(int chunk, const float* __restrict__ Wl, const float* __restrict__ Wr,
                                         _Float16* __restrict__ Wfrag) {
    constexpr int MTOT = 2 * M2, NT = MTOT / 16;
    if (chunk >= MTOT * K / 8) return;
    int lane = chunk & 63, tt = chunk >> 6;
    int t = tt % NT, kt = tt / NT;
    int n = t * 16 + (lane & 15);
    int kb = kt * 32 + (lane >> 4) * 8;
    const float* src = (n < M2) ? (Wl + n) : (Wr + (n - M2));
    half8 h;
#pragma unroll
    for (int j = 0; j < 8; ++j) h[j] = (_Float16)src[(size_t)(kb + j) * M2];
    *(half8*)(Wfrag + (size_t)chunk * 8) = h;
}

__global__ __launch_bounds__(256) void k_wprep_all(const float* __restrict__ Wl1, const float* __restrict__ Wr1,
                                                   const float* __restrict__ Wl2, const float* __restrict__ Wr2,
                                                   const float* __restrict__ Wl3, const float* __restrict__ Wr3,
                                                   _Float16* __restrict__ Wf1, _Float16* __restrict__ Wf2,
                                                   _Float16* __restrict__ Wf3) {
    int b = blockIdx.x, t = threadIdx.x;
    if (b < 16)      wprep_fn<128, 128>(b * 256 + t, Wl1, Wr1, Wf1);
    else if (b < 24) wprep_fn<128, 64>((b - 16) * 256 + t, Wl2, Wr2, Wf2);
    else             wprep_fn<64, 32>((b - 24) * 256 + t, Wl3, Wr3, Wf3);
}

// ---------------- fused dual MFMA GEMM, LDS-free ----------------

template <int K, int M2>
__global__ __launch_bounds__(256) void k_dualgemm(const __half* __restrict__ Ain,
                                                  const _Float16* __restrict__ Wfrag,
                                                  __half* __restrict__ Ol, float* __restrict__ Or) {
    constexpr int MTOT = 2 * M2;
    constexpr int NT = MTOT / 16;
    constexpr int KT = K / 32;
    int tid = threadIdx.x;
    int wid = tid >> 6, lane = tid & 63;
    int q = lane >> 4, l15 = lane & 15;
    int r0 = blockIdx.x * 64 + wid * 16;
    int arow = min(r0 + l15, NN - 1);
    const _Float16* A = (const _Float16*)Ain;
    const _Float16* ap = A + (size_t)arow * K + q * 8;

    floatx4 acc[NT];
#pragma unroll
    for (int t = 0; t < NT; ++t) acc[t] = (floatx4){0.f, 0.f, 0.f, 0.f};

#pragma unroll
    for (int kt = 0; kt < KT; ++kt) {
        half8 a8 = *(const half8*)(ap + kt * 32);
        const _Float16* wp = Wfrag + ((size_t)(kt * NT) * 64 + lane) * 8;
#pragma unroll
        for (int t = 0; t < NT; ++t) {
            half8 b8 = *(const half8*)(wp + (size_t)t * 64 * 8);
            acc[t] = __builtin_amdgcn_mfma_f32_16x16x32_f16(a8, b8, acc[t], 0, 0, 0);
        }
    }

#pragma unroll
    for (int t = 0; t < NT; ++t) {
        int cn = t * 16 + l15;
#pragma unroll
        for (int reg = 0; reg < 4; ++reg) {
            int r = r0 + q * 4 + reg;
            if (r < NN) {
                if (cn < M2) Ol[(size_t)r * M2 + cn] = __float2half(acc[t][reg]);
                else         Or[(size_t)r * M2 + (cn - M2)] = acc[t][reg];
            }
        }
    }
}

// ---------------- GATv2 attention: channel-split + packed fp16 + no-max softmax ----------------

template <int CP> struct HVec { hv2 h2[CP / 2]; };

template <int CP>
__device__ __forceinline__ HVec<CP> load_hv(const __half* __restrict__ p) {
    HVec<CP> r;
    if constexpr (CP == 8) { float4 t = *(const float4*)p; r = *(HVec<CP>*)&t; }
    else if constexpr (CP == 4) { float2 t = *(const float2*)p; r = *(HVec<CP>*)&t; }
    else { r.h2[0] = *(const hv2*)p; }
    return r;
}

template <int C, int EP, bool CONCAT>
__global__ __launch_bounds__(256, 4) void k_attn(const __half* __restrict__ xl, const float* __restrict__ xr,
                                                 const int* __restrict__ rowptr,
                                                 const unsigned short* __restrict__ colsrc,
                                                 const float* __restrict__ att, const float* __restrict__ bias,
                                                 float* __restrict__ out) {
    constexpr int CP = C / EP;
    int t = blockIdx.x * 256 + threadIdx.x;
    int part = t & (EP - 1);
    int nh = t >> 2;                          // EP == 4
    if (nh >= NN * H) return;
    int node = nh >> 2, h = nh & 3;           // H == 4
    int cbase = h * C + part * CP;
    hv2 xrr2[CP / 2], attv2[CP / 2];
    float acc[CP];
    {
        const float* p = xr + (size_t)node * (H * C) + cbase;
        const float* q = att + cbase;
#pragma unroll
        for (int j = 0; j < CP / 2; ++j) {
            xrr2[j] = (hv2){(_Float16)p[2 * j], (_Float16)p[2 * j + 1]};
            attv2[j] = (hv2){(_Float16)q[2 * j], (_Float16)q[2 * j + 1]};
        }
#pragma unroll
        for (int c = 0; c < CP; ++c) acc[c] = 0.f;
    }
    float denom = 0.f;
    int beg = rowptr[node], end = rowptr[node + 1];

    auto process = [&](const HVec<CP>& xv) {
        float part_s = 0.f;
#pragma unroll
        for (int j = 0; j < CP / 2; ++j) {
            hv2 z = xv.h2[j] + xrr2[j];
            hv2 l = __builtin_elementwise_max(z, z * (_Float16)0.2f);   // leaky_relu
            part_s = __builtin_amdgcn_fdot2(l, attv2[j], part_s, false);
        }
        float score = part_s;
#pragma unroll
        for (int mask = 1; mask < EP; mask <<= 1) score += __shfl_xor(score, mask, 64);
        float w = __expf(score);
        denom += w;
        const _Float16* xh = (const _Float16*)&xv;
#pragma unroll
        for (int c = 0; c < CP; ++c) acc[c] = fmaf(w, (float)xh[c], acc[c]);
    };

    int idx = beg;
    for (; idx + 2 <= end; idx += 2) {
        int s0 = colsrc[idx], s1 = colsrc[idx + 1];
        HVec<CP> xv0 = load_hv<CP>(xl + (size_t)s0 * (H * C) + cbase);
        HVec<CP> xv1 = load_hv<CP>(xl + (size_t)s1 * (H * C) + cbase);
        process(xv0);
        process(xv1);
    }
    if (idx < end) {
        int s = colsrc[idx];
        HVec<CP> xv = load_hv<CP>(xl + (size_t)s * (H * C) + cbase);
        process(xv);
    }

    float inv = 1.f / denom;
    float* op = out + (size_t)node * (H * C) + cbase;
    float v[CP];
#pragma unroll
    for (int c = 0; c < CP; ++c) {
        v[c] = acc[c] * inv;
        if (CONCAT) v[c] += bias[cbase + c];
    }
    if constexpr (CP == 8) {
        *(float4*)(op) = make_float4(v[0], v[1], v[2], v[3]);
        *(float4*)(op + 4) = make_float4(v[4], v[5], v[6], v[7]);
    } else if constexpr (CP == 4) {
        *(float4*)(op) = make_float4(v[0], v[1], v[2], v[3]);
    } else {
        *(float2*)(op) = make_float2(v[0], v[1]);
    }
}

// ---------------- GraphNorm reduce: one block per (graph, segment), LDS tree, C*2 atomics/block ----------------

template <int LOGC, int SPLIT>
__global__ __launch_bounds__(256) void k_gnred2(const float* __restrict__ h, const int* __restrict__ bpos,
                                                float* __restrict__ sum, float* __restrict__ sumsq) {
    constexpr int C = 1 << LOGC;
    constexpr int RG = 256 >> LOGC;      // row-groups per block
    int g = blockIdx.x / SPLIT, s = blockIdx.x % SPLIT;
    int c = threadIdx.x & (C - 1);
    int rg = threadIdx.x >> LOGC;
    int b0 = bpos[g], b1 = bpos[g + 1];
    int n = b1 - b0;
    int seg = (n + SPLIT - 1) / SPLIT;
    int r0 = b0 + s * seg;
    int r1 = min(r0 + seg, b1);
    float sv = 0.f, ssv = 0.f;
    for (int r = r0 + rg; r < r1; r += RG) {
        float x = h[(size_t)r * C + c];
        sv += x; ssv += x * x;
    }
    __shared__ float ls[256], lss[256];
    ls[threadIdx.x] = sv; lss[threadIdx.x] = ssv;
    __syncthreads();
    for (int off = 128; off >= C; off >>= 1) {
        if (threadIdx.x < off) {
            ls[threadIdx.x] += ls[threadIdx.x + off];
            lss[threadIdx.x] += lss[threadIdx.x + off];
        }
        __syncthreads();
    }
    if (threadIdx.x < C) {
        atomicAdd(&sum[g * C + threadIdx.x], ls[threadIdx.x]);
        atomicAdd(&sumsq[g * C + threadIdx.x], lss[threadIdx.x]);
    }
}

// var(out) = E[x^2] - (2s - s^2) mu^2  where out = x - mu*s; optional fp16 copy for next GEMM
__global__ __launch_bounds__(256) void k_gnnorm(float* __restrict__ h, const int* __restrict__ batch,
                                                const float* __restrict__ sum, const float* __restrict__ sumsq,
                                                const int* __restrict__ cnt, const float* __restrict__ w,
                                                const float* __restrict__ b, const float* __restrict__ ms,
                                                int logC, __half* __restrict__ h16) {
    int C = 1 << logC;
    int i = blockIdx.x * 256 + threadIdx.x;
    if (i >= NN * C) return;
    int nd = i >> logC, c = i & (C - 1);
    int g = batch[nd];
    float cg = fmaxf((float)cnt[g], 1.f);
    float mu = sum[g * C + c] / cg;
    float ex2 = sumsq[g * C + c] / cg;
    float s_ = ms[c];
    float var = ex2 - (2.f * s_ - s_ * s_) * mu * mu;
    float y = (h[i] - mu * s_) * rsqrtf(var + 1e-5f) * w[c] + b[c];
    y = fmaxf(y, 0.f);   // fused ReLU
    h[i] = y;
    if (h16) h16[i] = __float2half(y);
}

// ---------------- layer-3 head mean + bias ----------------

__global__ __launch_bounds__(256) void k_headmean(const float* __restrict__ tmp, const float* __restrict__ b3,
                                                  float* __restrict__ out) {
    int i = blockIdx.x * 256 + threadIdx.x;
    if (i >= NN * 8) return;
    int nd = i >> 3, c = i & 7;
    const float* p = tmp + (size_t)nd * 32 + c;
    out[i] = 0.25f * (p[0] + p[8] + p[16] + p[24]) + b3[c];
}

// ---------------- pool mean + linear head ----------------

__global__ __launch_bounds__(512) void k_final(const float* __restrict__ pool, const int* __restrict__ cnt,
                                               const float* __restrict__ lw, const float* __restrict__ lb,
                                               float* __restrict__ outp) {
    __shared__ float feat[512];
    int t = threadIdx.x;
    int g = t >> 3;
    float f = pool[t] / fmaxf((float)cnt[g], 1.f);
    feat[t] = f;
    outp[256 + t] = f;          // features: d_out[256 .. 768)
    __syncthreads();
    if (t < 256) {
        int g2 = t >> 2, o = t & 3;
        float a = lb[o];
#pragma unroll
        for (int cc = 0; cc < 8; ++cc) a += feat[g2 * 8 + cc] * lw[cc * 4 + o];
        outp[t] = a;            // logits: d_out[0 .. 256)
    }
}

// ---------------- host ----------------

extern "C" void kernel_launch(void* const* d_in, const int* in_sizes, int n_in,
                              void* d_out, int out_size, void* d_ws, size_t ws_size,
                              hipStream_t stream) {
    const float* x    = (const float*)d_in[0];
    const int*   ei   = (const int*)d_in[1];
    const int*   batch= (const int*)d_in[2];
    const float *w_l1 = (const float*)d_in[3],  *w_r1 = (const float*)d_in[4];
    const float *att1 = (const float*)d_in[5],  *b1   = (const float*)d_in[6];
    const float *gn1w = (const float*)d_in[7],  *gn1b = (const float*)d_in[8],  *gn1s = (const float*)d_in[9];
    const float *w_l2 = (const float*)d_in[10], *w_r2 = (const float*)d_in[11];
    const float *att2 = (const float*)d_in[12], *b2   = (const float*)d_in[13];
    const float *gn2w = (const float*)d_in[14], *gn2b = (const float*)d_in[15], *gn2s = (const float*)d_in[16];
    const float *w_l3 = (const float*)d_in[17], *w_r3 = (const float*)d_in[18];
    const float *att3 = (const float*)d_in[19], *b3   = (const float*)d_in[20];
    const float *gn3w = (const float*)d_in[21], *gn3b = (const float*)d_in[22], *gn3s = (const float*)d_in[23];
    const float *lw   = (const float*)d_in[24], *lb   = (const float*)d_in[25];

    char* ws = (char*)d_ws;
    size_t off = 0;
    auto alloc = [&](size_t bytes) -> void* {
        void* p = ws + off;
        off += (bytes + 255) & ~(size_t)255;
        return p;
    };
    __half* Ah  = (__half*)alloc((size_t)NN * 128 * 2);  // x_l fp16 (GEMM out, attn gather operand)
    __half* Xh  = (__half*)alloc((size_t)NN * 128 * 2);  // GEMM fp16 input (cast of x / gnnorm out)
    float*  B   = (float*)alloc((size_t)NN * 128 * 4);   // x_r / layer-out scratch
    float*  Cb  = (float*)alloc((size_t)NN * 64 * 4);    // h2 scratch
    float*  Af  = (float*)alloc((size_t)NN * 8 * 4);     // layer-3 final node features
    _Float16* Wf1 = (_Float16*)alloc((size_t)256 * 128 * 2);  // frag-ordered weights l1
    _Float16* Wf2 = (_Float16*)alloc((size_t)128 * 128 * 2);  // l2
    _Float16* Wf3 = (_Float16*)alloc((size_t)64 * 64 * 2);    // l3
    int* rowptr = (int*)alloc((size_t)(NN + 1) * 4);
    unsigned short* colsrc = (unsigned short*)alloc((size_t)ET * 2);
    unsigned int* ebuf = (unsigned int*)alloc((size_t)ET * 4);
    int* bcnt   = (int*)alloc((size_t)NBK * SB * 4);
    int* boff   = (int*)alloc((size_t)NBK * SB * 4);
    int* tot    = (int*)alloc((size_t)NBK * 4);
    int* ebase  = (int*)alloc((size_t)(NBK + 1) * 4);
    int* bpos   = (int*)alloc((size_t)(NG + 1) * 4);
    int* cnt    = (int*)alloc((size_t)NG * 4);
    char* zbase = ws + off;                              // everything below gets one memset
    float* sum1 = (float*)alloc((size_t)NG * 128 * 4);
    float* sq1  = (float*)alloc((size_t)NG * 128 * 4);
    float* sum2 = (float*)alloc((size_t)NG * 64 * 4);
    float* sq2  = (float*)alloc((size_t)NG * 64 * 4);
    float* sum3 = (float*)alloc((size_t)NG * 8 * 4);
    float* sq3  = (float*)alloc((size_t)NG * 8 * 4);
    float* pool = (float*)alloc((size_t)NG * 8 * 4);
    size_t zbytes = (size_t)((ws + off) - zbase);
    (void)hipMemsetAsync(zbase, 0, zbytes, stream);

    k_cast<<<(NN * 128 / 8 + 255) / 256, 256, 0, stream>>>(x, Xh);
    k_wprep_all<<<26, 256, 0, stream>>>(w_l1, w_r1, w_l2, w_r2, w_l3, w_r3, Wf1, Wf2, Wf3);
    k_bounds<<<(NN + 255) / 256, 256, 0, stream>>>(batch, bpos);
    k_bhist<<<SB, 256, 0, stream>>>(ei, bcnt);
    k_bscanA<<<NBK, 256, 0, stream>>>(bcnt, boff, tot);
    k_bscanB<<<1, 256, 0, stream>>>(tot, ebase, bpos, cnt);
    k_bscatter<<<SB, 256, 0, stream>>>(ei, ebase, boff, ebuf);
    k_bsort<<<NBK, 256, 0, stream>>>(ebuf, ebase, rowptr, colsrc);

    int gA4 = (NN * H * 4) / 256;            // attention grid, EP=4 -> 3125 blocks exact
    int gD  = (NN + 63) / 64;                // dualgemm grid, 64 rows/block

    // ---- layer 1: 128 -> 4x32 concat -> 128
    k_dualgemm<128, 128><<<gD, 256, 0, stream>>>(Xh, Wf1, Ah, B);
    k_attn<32, 4, true><<<gA4, 256, 0, stream>>>(Ah, B, rowptr, colsrc, att1, b1, B);
    k_gnred2<7, 8><<<NG * 8, 256, 0, stream>>>(B, bpos, sum1, sq1);
    k_gnnorm<<<(NN * 128 + 255) / 256, 256, 0, stream>>>(B, batch, sum1, sq1, cnt, gn1w, gn1b, gn1s, 7, Xh);

    // ---- layer 2: 128 -> 4x16 concat -> 64
    k_dualgemm<128, 64><<<gD, 256, 0, stream>>>(Xh, Wf2, Ah, Cb);
    k_attn<16, 4, true><<<gA4, 256, 0, stream>>>(Ah, Cb, rowptr, colsrc, att2, b2, Cb);
    k_gnred2<6, 8><<<NG * 8, 256, 0, stream>>>(Cb, bpos, sum2, sq2);
    k_gnnorm<<<(NN * 64 + 255) / 256, 256, 0, stream>>>(Cb, batch, sum2, sq2, cnt, gn2w, gn2b, gn2s, 6, Xh);

    // ---- layer 3: 64 -> 4x8 mean -> 8
    k_dualgemm<64, 32><<<gD, 256, 0, stream>>>(Xh, Wf3, Ah, B);
    k_attn<8, 4, false><<<gA4, 256, 0, stream>>>(Ah, B, rowptr, colsrc, att3, nullptr, B);
    k_headmean<<<(NN * 8 + 255) / 256, 256, 0, stream>>>(B, b3, Af);
    k_gnred2<3, 8><<<NG * 8, 256, 0, stream>>>(Af, bpos, sum3, sq3);
    k_gnnorm<<<(NN * 8 + 255) / 256, 256, 0, stream>>>(Af, batch, sum3, sq3, cnt, gn3w, gn3b, gn3s, 3, nullptr);

    // ---- global mean pool + linear
    k_gnred2<3, 8><<<NG * 8, 256, 0, stream>>>(Af, bpos, pool, sq3);  // sq3 as throwaway sumsq
    k_final<<<1, 512, 0, stream>>>(pool, cnt, lw, lb, (float*)d_out);
}

// Round 13
// 355.201 us; speedup vs baseline: 1.4277x; 1.0161x over previous
//
#include <hip/hip_runtime.h>
#include <hip/hip_fp16.h>
#include <math.h>

#define NN 50000
#define NE 800000
#define ET (NE + NN)
#define NG 64
#define H 4
#define NBK 196                   // dst buckets (dst >> 8)
#define CH 4096                   // edges per chunk
#define SB ((ET + CH - 1) / CH)   // 208 edge chunks

typedef _Float16 half8 __attribute__((ext_vector_type(8)));
typedef _Float16 hv2 __attribute__((ext_vector_type(2)));
typedef float floatx4 __attribute__((ext_vector_type(4)));

// ---------------- CSR build: two-level bucketed counting sort, LDS atomics only ----------------

__device__ __forceinline__ void edge_sd(int e, const int* __restrict__ ei, int& s, int& d) {
    if (e < NE) { s = ei[e]; d = ei[NE + e]; } else { s = e - NE; d = s; }
}

// Phase 1: per-(chunk, bucket) histogram.  bcnt layout: [bucket * SB + chunk]
__global__ __launch_bounds__(256) void k_bhist(const int* __restrict__ ei, int* __restrict__ bcnt) {
    __shared__ int hist[NBK];
    int b0 = blockIdx.x, tid = threadIdx.x;
    for (int i = tid; i < NBK; i += 256) hist[i] = 0;
    __syncthreads();
#pragma unroll
    for (int pass = 0; pass < CH / 256; ++pass) {
        int e = b0 * CH + pass * 256 + tid;
        if (e < ET) {
            int d = (e < NE) ? ei[NE + e] : (e - NE);
            atomicAdd(&hist[d >> 8], 1);
        }
    }
    __syncthreads();
    if (tid < NBK) bcnt[tid * SB + b0] = hist[tid];
}

// Phase 2a: per-bucket exclusive scan over its SB chunk-counts (coalesced). tot[b] = bucket total.
__global__ __launch_bounds__(256) void k_bscanA(const int* __restrict__ bcnt, int* __restrict__ boff,
                                                int* __restrict__ tot) {
    __shared__ int lds[256];
    int b = blockIdx.x, t = threadIdx.x;
    int v = (t < SB) ? bcnt[b * SB + t] : 0;
    lds[t] = v;
    __syncthreads();
    for (int off = 1; off < 256; off <<= 1) {
        int y = (t >= off) ? lds[t - off] : 0;
        __syncthreads();
        lds[t] += y;
        __syncthreads();
    }
    if (t < SB) boff[b * SB + t] = lds[t] - v;   // exclusive within bucket
    if (t == 255) tot[b] = lds[255];
}

// Phase 2b: scan bucket totals -> ebase; fold per-graph counts from bpos.
__global__ __launch_bounds__(256) void k_bscanB(const int* __restrict__ tot, int* __restrict__ ebase,
                                                const int* __restrict__ bpos, int* __restrict__ cnt) {
    __shared__ int lds[256];
    int t = threadIdx.x;
    int v = (t < NBK) ? tot[t] : 0;
    lds[t] = v;
    __syncthreads();
    for (int off = 1; off < 256; off <<= 1) {
        int y = (t >= off) ? lds[t - off] : 0;
        __syncthreads();
        lds[t] += y;
        __syncthreads();
    }
    if (t < NBK) ebase[t] = lds[t] - v;
    if (t == 0) ebase[NBK] = ET;
    if (t < NG) cnt[t] = bpos[t + 1] - bpos[t];
}

// batch is sorted: graph boundaries without atomics.
__global__ __launch_bounds__(256) void k_bounds(const int* __restrict__ batch, int* __restrict__ bpos) {
    int i = blockIdx.x * 256 + threadIdx.x;
    if (i >= NN) return;
    int cur = batch[i];
    int prev = (i == 0) ? -1 : batch[i - 1];
    for (int g = prev + 1; g <= cur; ++g) bpos[g] = i;
    if (i == NN - 1)
        for (int g = cur + 1; g <= NG; ++g) bpos[g] = NN;
}

// Phase 3: scatter edges into bucket-major ebuf. Block-private offsets -> no global atomics.
// ebuf entry: (src << 16) | (dst & 255)
__global__ __launch_bounds__(256) void k_bscatter(const int* __restrict__ ei, const int* __restrict__ ebase,
                                                  const int* __restrict__ boff, unsigned int* __restrict__ ebuf) {
    __shared__ int cur[NBK];
    int b0 = blockIdx.x, tid = threadIdx.x;
    for (int i = tid; i < NBK; i += 256) cur[i] = ebase[i] + boff[i * SB + b0];
    __syncthreads();
#pragma unroll
    for (int pass = 0; pass < CH / 256; ++pass) {
        int e = b0 * CH + pass * 256 + tid;
        if (e < ET) {
            int s, d;
            edge_sd(e, ei, s, d);
            int pos = atomicAdd(&cur[d >> 8], 1);
            ebuf[pos] = ((unsigned)s << 16) | (unsigned)(d & 255);
        }
    }
}

// Phase 4: one block per bucket. Exact-dst LDS counting sort -> rowptr + colsrc.
__global__ __launch_bounds__(256) void k_bsort(const unsigned int* __restrict__ ebuf,
                                               const int* __restrict__ ebase,
                                               int* __restrict__ rowptr, unsigned short* __restrict__ colsrc) {
    __shared__ int cnt2[256];
    __shared__ int sc[256];
    __shared__ int cur2[256];
    int b = blockIdx.x, t = threadIdx.x;
    int base = ebase[b], n = ebase[b + 1] - base;
    cnt2[t] = 0;
    __syncthreads();
    for (int i = t; i < n; i += 256) atomicAdd(&cnt2[ebuf[base + i] & 255], 1);
    __syncthreads();
    int v = cnt2[t];
    sc[t] = v;
    __syncthreads();
    for (int off = 1; off < 256; off <<= 1) {
        int y = (t >= off) ? sc[t - off] : 0;
        __syncthreads();
        sc[t] += y;
        __syncthreads();
    }
    int excl = sc[t] - v;
    int d = b * 256 + t;
    if (d < NN) rowptr[d] = base + excl;
    if (b == 0 && t == 0) rowptr[NN] = ET;
    cur2[t] = excl;
    __syncthreads();
    for (int i = t; i < n; i += 256) {
        unsigned u = ebuf[base + i];
        int pos = atomicAdd(&cur2[u & 255], 1);
        colsrc[base + pos] = (unsigned short)(u >> 16);
    }
}

// ---------------- fp32 -> fp16 cast (layer-1 GEMM input) ----------------

__global__ __launch_bounds__(256) void k_cast(const float* __restrict__ x, __half* __restrict__ xh) {
    int i = blockIdx.x * 256 + threadIdx.x;       // one thread = 8 elements; NN*128 % 8 == 0
    size_t base = (size_t)i * 8;
    if (base >= (size_t)NN * 128) return;
    const float4* p = (const float4*)(x + base);
    float4 a = p[0], b = p[1];
    half8 h;
    h[0] = (_Float16)a.x; h[1] = (_Float16)a.y; h[2] = (_Float16)a.z; h[3] = (_Float16)a.w;
    h[4] = (_Float16)b.x; h[5] = (_Float16)b.y; h[6] = (_Float16)b.z; h[7] = (_Float16)b.w;
    *(half8*)(xh + base) = h;
}

// ---------------- weight prep: fp32 [K][M2]x2 -> fp16 MFMA-fragment order (all 3 layers fused) ----------------

template <int K, int M2>
__device__ __forceinline__ void wprep_fn(int chunk, const float* __restrict__ Wl, const float* __restrict__ Wr,
                                         _Float16* __restrict__ Wfrag) {
    constexpr int MTOT = 2 * M2, NT = MTOT / 16;
    if (chunk >= MTOT * K / 8) return;
    int lane = chunk & 63, tt = chunk >> 6;
    int t = tt % NT, kt = tt / NT;
    int n = t * 16 + (lane & 15);
    int kb = kt * 32 + (lane >> 4) * 8;
    const float* src = (n < M2) ? (Wl + n) : (Wr + (n - M2));
    half8 h;
#pragma unroll
    for (int j = 0; j < 8; ++j) h[j] = (_Float16)src[(size_t)(kb + j) * M2];
    *(half8*)(Wfrag + (size_t)chunk * 8) = h;
}

__global__ __launch_bounds__(256) void k_wprep_all(const float* __restrict__ Wl1, const float* __restrict__ Wr1,
                                                   const float* __restrict__ Wl2, const float* __restrict__ Wr2,
                                                   const float* __restrict__ Wl3, const float* __restrict__ Wr3,
                                                   _Float16* __restrict__ Wf1, _Float16* __restrict__ Wf2,
                                                   _Float16* __restrict__ Wf3) {
    int b = blockIdx.x, t = threadIdx.x;
    if (b < 16)      wprep_fn<128, 128>(b * 256 + t, Wl1, Wr1, Wf1);
    else if (b < 24) wprep_fn<128, 64>((b - 16) * 256 + t, Wl2, Wr2, Wf2);
    else             wprep_fn<64, 32>((b - 24) * 256 + t, Wl3, Wr3, Wf3);
}

// ---------------- fused dual MFMA GEMM, LDS-free ----------------

template <int K, int M2>
__global__ __launch_bounds__(256) void k_dualgemm(const __half* __restrict__ Ain,
                                                  const _Float16* __restrict__ Wfrag,
                                                  __half* __restrict__ Ol, float* __restrict__ Or) {
    constexpr int MTOT = 2 * M2;
    constexpr int NT = MTOT / 16;
    constexpr int KT = K / 32;
    int tid = threadIdx.x;
    int wid = tid >> 6, lane = tid & 63;
    int q = lane >> 4, l15 = lane & 15;
    int r0 = blockIdx.x * 64 + wid * 16;
    int arow = min(r0 + l15, NN - 1);
    const _Float16* A = (const _Float16*)Ain;
    const _Float16* ap = A + (size_t)arow * K + q * 8;

    floatx4 acc[NT];
#pragma unroll
    for (int t = 0; t < NT; ++t) acc[t] = (floatx4){0.f, 0.f, 0.f, 0.f};

#pragma unroll
    for (int kt = 0; kt < KT; ++kt) {
        half8 a8 = *(const half8*)(ap + kt * 32);
        const _Float16* wp = Wfrag + ((size_t)(kt * NT) * 64 + lane) * 8;
#pragma unroll
        for (int t = 0; t < NT; ++t) {
            half8 b8 = *(const half8*)(wp + (size_t)t * 64 * 8);
            acc[t] = __builtin_amdgcn_mfma_f32_16x16x32_f16(a8, b8, acc[t], 0, 0, 0);
        }
    }

#pragma unroll
    for (int t = 0; t < NT; ++t) {
        int cn = t * 16 + l15;
#pragma unroll
        for (int reg = 0; reg < 4; ++reg) {
            int r = r0 + q * 4 + reg;
            if (r < NN) {
                if (cn < M2) Ol[(size_t)r * M2 + cn] = __float2half(acc[t][reg]);
                else         Or[(size_t)r * M2 + (cn - M2)] = acc[t][reg];
            }
        }
    }
}

// ---------------- GATv2 attention: channel-split + packed fp16 + no-max softmax ----------------
// __launch_bounds__(256, 8): VGPR ~40 fits 8 waves/SIMD -> 2x resident waves vs r11 -> 2x MLP
// for the latency-bound gather stream.

template <int CP> struct HVec { hv2 h2[CP / 2]; };

template <int CP>
__device__ __forceinline__ HVec<CP> load_hv(const __half* __restrict__ p) {
    HVec<CP> r;
    if constexpr (CP == 8) { float4 t = *(const float4*)p; r = *(HVec<CP>*)&t; }
    else if constexpr (CP == 4) { float2 t = *(const float2*)p; r = *(HVec<CP>*)&t; }
    else { r.h2[0] = *(const hv2*)p; }
    return r;
}

template <int C, int EP, bool CONCAT>
__global__ __launch_bounds__(256, 8) void k_attn(const __half* __restrict__ xl, const float* __restrict__ xr,
                                                 const int* __restrict__ rowptr,
                                                 const unsigned short* __restrict__ colsrc,
                                                 const float* __restrict__ att, const float* __restrict__ bias,
                                                 float* __restrict__ out) {
    constexpr int CP = C / EP;
    int t = blockIdx.x * 256 + threadIdx.x;
    int part = t & (EP - 1);
    int nh = t >> 2;                          // EP == 4
    if (nh >= NN * H) return;
    int node = nh >> 2, h = nh & 3;           // H == 4
    int cbase = h * C + part * CP;
    hv2 xrr2[CP / 2], attv2[CP / 2];
    float acc[CP];
    {
        const float* p = xr + (size_t)node * (H * C) + cbase;
        const float* q = att + cbase;
#pragma unroll
        for (int j = 0; j < CP / 2; ++j) {
            xrr2[j] = (hv2){(_Float16)p[2 * j], (_Float16)p[2 * j + 1]};
            attv2[j] = (hv2){(_Float16)q[2 * j], (_Float16)q[2 * j + 1]};
        }
#pragma unroll
        for (int c = 0; c < CP; ++c) acc[c] = 0.f;
    }
    float denom = 0.f;
    int beg = rowptr[node], end = rowptr[node + 1];

    auto process = [&](const HVec<CP>& xv) {
        float part_s = 0.f;
#pragma unroll
        for (int j = 0; j < CP / 2; ++j) {
            hv2 z = xv.h2[j] + xrr2[j];
            hv2 l = __builtin_elementwise_max(z, z * (_Float16)0.2f);   // leaky_relu
            part_s = __builtin_amdgcn_fdot2(l, attv2[j], part_s, false);
        }
        float score = part_s;
#pragma unroll
        for (int mask = 1; mask < EP; mask <<= 1) score += __shfl_xor(score, mask, 64);
        float w = __expf(score);
        denom += w;
        const _Float16* xh = (const _Float16*)&xv;
#pragma unroll
        for (int c = 0; c < CP; ++c) acc[c] = fmaf(w, (float)xh[c], acc[c]);
    };

    int idx = beg;
    for (; idx + 2 <= end; idx += 2) {
        int s0 = colsrc[idx], s1 = colsrc[idx + 1];
        HVec<CP> xv0 = load_hv<CP>(xl + (size_t)s0 * (H * C) + cbase);
        HVec<CP> xv1 = load_hv<CP>(xl + (size_t)s1 * (H * C) + cbase);
        process(xv0);
        process(xv1);
    }
    if (idx < end) {
        int s = colsrc[idx];
        HVec<CP> xv = load_hv<CP>(xl + (size_t)s * (H * C) + cbase);
        process(xv);
    }

    float inv = 1.f / denom;
    float* op = out + (size_t)node * (H * C) + cbase;
    float v[CP];
#pragma unroll
    for (int c = 0; c < CP; ++c) {
        v[c] = acc[c] * inv;
        if (CONCAT) v[c] += bias[cbase + c];
    }
    if constexpr (CP == 8) {
        *(float4*)(op) = make_float4(v[0], v[1], v[2], v[3]);
        *(float4*)(op + 4) = make_float4(v[4], v[5], v[6], v[7]);
    } else if constexpr (CP == 4) {
        *(float4*)(op) = make_float4(v[0], v[1], v[2], v[3]);
    } else {
        *(float2*)(op) = make_float2(v[0], v[1]);
    }
}

// ---------------- GraphNorm reduce: one block per (graph, segment), LDS tree, C*2 atomics/block ----------------

template <int LOGC, int SPLIT>
__global__ __launch_bounds__(256) void k_gnred2(const float* __restrict__ h, const int* __restrict__ bpos,
                                                float* __restrict__ sum, float* __restrict__ sumsq) {
    constexpr int C = 1 << LOGC;
    constexpr int RG = 256 >> LOGC;      // row-groups per block
    int g = blockIdx.x / SPLIT, s = blockIdx.x % SPLIT;
    int c = threadIdx.x & (C - 1);
    int rg = threadIdx.x >> LOGC;
    int b0 = bpos[g], b1 = bpos[g + 1];
    int n = b1 - b0;
    int seg = (n + SPLIT - 1) / SPLIT;
    int r0 = b0 + s * seg;
    int r1 = min(r0 + seg, b1);
    float sv = 0.f, ssv = 0.f;
    for (int r = r0 + rg; r < r1; r += RG) {
        float x = h[(size_t)r * C + c];
        sv += x; ssv += x * x;
    }
    __shared__ float ls[256], lss[256];
    ls[threadIdx.x] = sv; lss[threadIdx.x] = ssv;
    __syncthreads();
    for (int off = 128; off >= C; off >>= 1) {
        if (threadIdx.x < off) {
            ls[threadIdx.x] += ls[threadIdx.x + off];
            lss[threadIdx.x] += lss[threadIdx.x + off];
        }
        __syncthreads();
    }
    if (threadIdx.x < C) {
        atomicAdd(&sum[g * C + threadIdx.x], ls[threadIdx.x]);
        atomicAdd(&sumsq[g * C + threadIdx.x], lss[threadIdx.x]);
    }
}

// var(out) = E[x^2] - (2s - s^2) mu^2  where out = x - mu*s; optional fp16 copy for next GEMM
__global__ __launch_bounds__(256) void k_gnnorm(float* __restrict__ h, const int* __restrict__ batch,
                                                const float* __restrict__ sum, const float* __restrict__ sumsq,
                                                const int* __restrict__ cnt, const float* __restrict__ w,
                                                const float* __restrict__ b, const float* __restrict__ ms,
                                                int logC, __half* __restrict__ h16) {
    int C = 1 << logC;
    int i = blockIdx.x * 256 + threadIdx.x;
    if (i >= NN * C) return;
    int nd = i >> logC, c = i & (C - 1);
    int g = batch[nd];
    float cg = fmaxf((float)cnt[g], 1.f);
    float mu = sum[g * C + c] / cg;
    float ex2 = sumsq[g * C + c] / cg;
    float s_ = ms[c];
    float var = ex2 - (2.f * s_ - s_ * s_) * mu * mu;
    float y = (h[i] - mu * s_) * rsqrtf(var + 1e-5f) * w[c] + b[c];
    y = fmaxf(y, 0.f);   // fused ReLU
    h[i] = y;
    if (h16) h16[i] = __float2half(y);
}

// ---------------- fused layer-3 tail ----------------
// k_headgn: headmean+bias (from 32-ch attn out) fused with GN sum/sumsq reduction; writes Af.

template <int SPLIT>
__global__ __launch_bounds__(256) void k_headgn(const float* __restrict__ tmp, const float* __restrict__ b3,
                                                const int* __restrict__ bpos, float* __restrict__ Af,
                                                float* __restrict__ sum, float* __restrict__ sumsq) {
    constexpr int C = 8, RG = 32;
    int g = blockIdx.x / SPLIT, s = blockIdx.x % SPLIT;
    int c = threadIdx.x & 7;
    int rg = threadIdx.x >> 3;
    int b0 = bpos[g], b1 = bpos[g + 1];
    int n = b1 - b0;
    int seg = (n + SPLIT - 1) / SPLIT;
    int r0 = b0 + s * seg;
    int r1 = min(r0 + seg, b1);
    float bias = b3[c];
    float sv = 0.f, ssv = 0.f;
    for (int r = r0 + rg; r < r1; r += RG) {
        const float* p = tmp + (size_t)r * 32 + c;
        float v = 0.25f * (p[0] + p[8] + p[16] + p[24]) + bias;
        Af[(size_t)r * C + c] = v;
        sv += v; ssv += v * v;
    }
    __shared__ float ls[256], lss[256];
    ls[threadIdx.x] = sv; lss[threadIdx.x] = ssv;
    __syncthreads();
    for (int off = 128; off >= C; off >>= 1) {
        if (threadIdx.x < off) {
            ls[threadIdx.x] += ls[threadIdx.x + off];
            lss[threadIdx.x] += lss[threadIdx.x + off];
        }
        __syncthreads();
    }
    if (threadIdx.x < C) {
        atomicAdd(&sum[g * C + threadIdx.x], ls[threadIdx.x]);
        atomicAdd(&sumsq[g * C + threadIdx.x], lss[threadIdx.x]);
    }
}

// k_gnpool: GN normalize + ReLU (C=8) fused with pool-sum reduction (writes y and per-graph sums).

template <int SPLIT>
__global__ __launch_bounds__(256) void k_gnpool(float* __restrict__ Af, const int* __restrict__ bpos,
                                                const float* __restrict__ sum, const float* __restrict__ sumsq,
                                                const int* __restrict__ cnt, const float* __restrict__ w,
                                                const float* __restrict__ b, const float* __restrict__ ms,
                                                float* __restrict__ pool) {
    constexpr int C = 8, RG = 32;
    int g = blockIdx.x / SPLIT, s = blockIdx.x % SPLIT;
    int c = threadIdx.x & 7;
    int rg = threadIdx.x >> 3;
    int b0 = bpos[g], b1 = bpos[g + 1];
    int n = b1 - b0;
    int seg = (n + SPLIT - 1) / SPLIT;
    int r0 = b0 + s * seg;
    int r1 = min(r0 + seg, b1);
    float cg = fmaxf((float)cnt[g], 1.f);
    float mu = sum[g * C + c] / cg;
    float ex2 = sumsq[g * C + c] / cg;
    float s_ = ms[c];
    float var = ex2 - (2.f * s_ - s_ * s_) * mu * mu;
    float rs = rsqrtf(var + 1e-5f) * w[c];
    float bb = b[c], mus = mu * s_;
    float pv = 0.f;
    for (int r = r0 + rg; r < r1; r += RG) {
        size_t i = (size_t)r * C + c;
        float y = fmaxf((Af[i] - mus) * rs + bb, 0.f);
        Af[i] = y;
        pv += y;
    }
    __shared__ float ls[256];
    ls[threadIdx.x] = pv;
    __syncthreads();
    for (int off = 128; off >= C; off >>= 1) {
        if (threadIdx.x < off) ls[threadIdx.x] += ls[threadIdx.x + off];
        __syncthreads();
    }
    if (threadIdx.x < C) atomicAdd(&pool[g * C + threadIdx.x], ls[threadIdx.x]);
}

// ---------------- pool mean + linear head ----------------

__global__ __launch_bounds__(512) void k_final(const float* __restrict__ pool, const int* __restrict__ cnt,
                                               const float* __restrict__ lw, const float* __restrict__ lb,
                                               float* __restrict__ outp) {
    __shared__ float feat[512];
    int t = threadIdx.x;
    int g = t >> 3;
    float f = pool[t] / fmaxf((float)cnt[g], 1.f);
    feat[t] = f;
    outp[256 + t] = f;          // features: d_out[256 .. 768)
    __syncthreads();
    if (t < 256) {
        int g2 = t >> 2, o = t & 3;
        float a = lb[o];
#pragma unroll
        for (int cc = 0; cc < 8; ++cc) a += feat[g2 * 8 + cc] * lw[cc * 4 + o];
        outp[t] = a;            // logits: d_out[0 .. 256)
    }
}

// ---------------- host ----------------

extern "C" void kernel_launch(void* const* d_in, const int* in_sizes, int n_in,
                              void* d_out, int out_size, void* d_ws, size_t ws_size,
                              hipStream_t stream) {
    const float* x    = (const float*)d_in[0];
    const int*   ei   = (const int*)d_in[1];
    const int*   batch= (const int*)d_in[2];
    const float *w_l1 = (const float*)d_in[3],  *w_r1 = (const float*)d_in[4];
    const float *att1 = (const float*)d_in[5],  *b1   = (const float*)d_in[6];
    const float *gn1w = (const float*)d_in[7],  *gn1b = (const float*)d_in[8],  *gn1s = (const float*)d_in[9];
    const float *w_l2 = (const float*)d_in[10], *w_r2 = (const float*)d_in[11];
    const float *att2 = (const float*)d_in[12], *b2   = (const float*)d_in[13];
    const float *gn2w = (const float*)d_in[14], *gn2b = (const float*)d_in[15], *gn2s = (const float*)d_in[16];
    const float *w_l3 = (const float*)d_in[17], *w_r3 = (const float*)d_in[18];
    const float *att3 = (const float*)d_in[19], *b3   = (const float*)d_in[20];
    const float *gn3w = (const float*)d_in[21], *gn3b = (const float*)d_in[22], *gn3s = (const float*)d_in[23];
    const float *lw   = (const float*)d_in[24], *lb   = (const float*)d_in[25];

    char* ws = (char*)d_ws;
    size_t off = 0;
    auto alloc = [&](size_t bytes) -> void* {
        void* p = ws + off;
        off += (bytes + 255) & ~(size_t)255;
        return p;
    };
    __half* Ah  = (__half*)alloc((size_t)NN * 128 * 2);  // x_l fp16 (GEMM out, attn gather operand)
    __half* Xh  = (__half*)alloc((size_t)NN * 128 * 2);  // GEMM fp16 input (cast of x / gnnorm out)
    float*  B   = (float*)alloc((size_t)NN * 128 * 4);   // x_r / layer-out scratch
    float*  Cb  = (float*)alloc((size_t)NN * 64 * 4);    // h2 scratch
    float*  Af  = (float*)alloc((size_t)NN * 8 * 4);     // layer-3 final node features
    _Float16* Wf1 = (_Float16*)alloc((size_t)256 * 128 * 2);  // frag-ordered weights l1
    _Float16* Wf2 = (_Float16*)alloc((size_t)128 * 128 * 2);  // l2
    _Float16* Wf3 = (_Float16*)alloc((size_t)64 * 64 * 2);    // l3
    int* rowptr = (int*)alloc((size_t)(NN + 1) * 4);
    unsigned short* colsrc = (unsigned short*)alloc((size_t)ET * 2);
    unsigned int* ebuf = (unsigned int*)alloc((size_t)ET * 4);
    int* bcnt   = (int*)alloc((size_t)NBK * SB * 4);
    int* boff   = (int*)alloc((size_t)NBK * SB * 4);
    int* tot    = (int*)alloc((size_t)NBK * 4);
    int* ebase  = (int*)alloc((size_t)(NBK + 1) * 4);
    int* bpos   = (int*)alloc((size_t)(NG + 1) * 4);
    int* cnt    = (int*)alloc((size_t)NG * 4);
    char* zbase = ws + off;                              // everything below gets one memset
    float* sum1 = (float*)alloc((size_t)NG * 128 * 4);
    float* sq1  = (float*)alloc((size_t)NG * 128 * 4);
    float* sum2 = (float*)alloc((size_t)NG * 64 * 4);
    float* sq2  = (float*)alloc((size_t)NG * 64 * 4);
    float* sum3 = (float*)alloc((size_t)NG * 8 * 4);
    float* sq3  = (float*)alloc((size_t)NG * 8 * 4);
    float* pool = (float*)alloc((size_t)NG * 8 * 4);
    size_t zbytes = (size_t)((ws + off) - zbase);
    (void)hipMemsetAsync(zbase, 0, zbytes, stream);

    k_cast<<<(NN * 128 / 8 + 255) / 256, 256, 0, stream>>>(x, Xh);
    k_wprep_all<<<26, 256, 0, stream>>>(w_l1, w_r1, w_l2, w_r2, w_l3, w_r3, Wf1, Wf2, Wf3);
    k_bounds<<<(NN + 255) / 256, 256, 0, stream>>>(batch, bpos);
    k_bhist<<<SB, 256, 0, stream>>>(ei, bcnt);
    k_bscanA<<<NBK, 256, 0, stream>>>(bcnt, boff, tot);
    k_bscanB<<<1, 256, 0, stream>>>(tot, ebase, bpos, cnt);
    k_bscatter<<<SB, 256, 0, stream>>>(ei, ebase, boff, ebuf);
    k_bsort<<<NBK, 256, 0, stream>>>(ebuf, ebase, rowptr, colsrc);

    int gA4 = (NN * H * 4) / 256;            // attention grid, EP=4 -> 3125 blocks exact
    int gD  = (NN + 63) / 64;                // dualgemm grid, 64 rows/block

    // ---- layer 1: 128 -> 4x32 concat -> 128
    k_dualgemm<128, 128><<<gD, 256, 0, stream>>>(Xh, Wf1, Ah, B);
    k_attn<32, 4, true><<<gA4, 256, 0, stream>>>(Ah, B, rowptr, colsrc, att1, b1, B);
    k_gnred2<7, 8><<<NG * 8, 256, 0, stream>>>(B, bpos, sum1, sq1);
    k_gnnorm<<<(NN * 128 + 255) / 256, 256, 0, stream>>>(B, batch, sum1, sq1, cnt, gn1w, gn1b, gn1s, 7, Xh);

    // ---- layer 2: 128 -> 4x16 concat -> 64
    k_dualgemm<128, 64><<<gD, 256, 0, stream>>>(Xh, Wf2, Ah, Cb);
    k_attn<16, 4, true><<<gA4, 256, 0, stream>>>(Ah, Cb, rowptr, colsrc, att2, b2, Cb);
    k_gnred2<6, 8><<<NG * 8, 256, 0, stream>>>(Cb, bpos, sum2, sq2);
    k_gnnorm<<<(NN * 64 + 255) / 256, 256, 0, stream>>>(Cb, batch, sum2, sq2, cnt, gn2w, gn2b, gn2s, 6, Xh);

    // ---- layer 3: 64 -> 4x8 mean -> 8, fused tail
    k_dualgemm<64, 32><<<gD, 256, 0, stream>>>(Xh, Wf3, Ah, B);
    k_attn<8, 4, false><<<gA4, 256, 0, stream>>>(Ah, B, rowptr, colsrc, att3, nullptr, B);
    k_headgn<8><<<NG * 8, 256, 0, stream>>>(B, b3, bpos, Af, sum3, sq3);
    k_gnpool<8><<<NG * 8, 256, 0, stream>>>(Af, bpos, sum3, sq3, cnt, gn3w, gn3b, gn3s, pool);
    k_final<<<1, 512, 0, stream>>>(pool, cnt, lw, lb, (float*)d_out);
}

// Round 14
// 336.302 us; speedup vs baseline: 1.5079x; 1.0562x over previous
//
#include <hip/hip_runtime.h>
#include <hip/hip_fp16.h>
#include <math.h>

#define NN 50000
#define NE 800000
#define ET (NE + NN)
#define NG 64
#define H 4
#define NBK 196                   // dst buckets (dst >> 8)
#define CH 4096                   // edges per chunk
#define SB ((ET + CH - 1) / CH)   // 208 edge chunks

typedef _Float16 half8 __attribute__((ext_vector_type(8)));
typedef _Float16 hv2 __attribute__((ext_vector_type(2)));
typedef float floatx4 __attribute__((ext_vector_type(4)));

// ---------------- CSR build: two-level bucketed counting sort, LDS atomics only ----------------

__device__ __forceinline__ void edge_sd(int e, const int* __restrict__ ei, int& s, int& d) {
    if (e < NE) { s = ei[e]; d = ei[NE + e]; } else { s = e - NE; d = s; }
}

// Phase 1: per-(chunk, bucket) histogram.  bcnt layout: [bucket * SB + chunk]
__global__ __launch_bounds__(256) void k_bhist(const int* __restrict__ ei, int* __restrict__ bcnt) {
    __shared__ int hist[NBK];
    int b0 = blockIdx.x, tid = threadIdx.x;
    for (int i = tid; i < NBK; i += 256) hist[i] = 0;
    __syncthreads();
#pragma unroll
    for (int pass = 0; pass < CH / 256; ++pass) {
        int e = b0 * CH + pass * 256 + tid;
        if (e < ET) {
            int d = (e < NE) ? ei[NE + e] : (e - NE);
            atomicAdd(&hist[d >> 8], 1);
        }
    }
    __syncthreads();
    if (tid < NBK) bcnt[tid * SB + b0] = hist[tid];
}

// Phase 2a: per-bucket exclusive scan over its SB chunk-counts (coalesced). tot[b] = bucket total.
__global__ __launch_bounds__(256) void k_bscanA(const int* __restrict__ bcnt, int* __restrict__ boff,
                                                int* __restrict__ tot) {
    __shared__ int lds[256];
    int b = blockIdx.x, t = threadIdx.x;
    int v = (t < SB) ? bcnt[b * SB + t] : 0;
    lds[t] = v;
    __syncthreads();
    for (int off = 1; off < 256; off <<= 1) {
        int y = (t >= off) ? lds[t - off] : 0;
        __syncthreads();
        lds[t] += y;
        __syncthreads();
    }
    if (t < SB) boff[b * SB + t] = lds[t] - v;   // exclusive within bucket
    if (t == 255) tot[b] = lds[255];
}

// Phase 2b: scan bucket totals -> ebase; fold per-graph counts from bpos.
__global__ __launch_bounds__(256) void k_bscanB(const int* __restrict__ tot, int* __restrict__ ebase,
                                                const int* __restrict__ bpos, int* __restrict__ cnt) {
    __shared__ int lds[256];
    int t = threadIdx.x;
    int v = (t < NBK) ? tot[t] : 0;
    lds[t] = v;
    __syncthreads();
    for (int off = 1; off < 256; off <<= 1) {
        int y = (t >= off) ? lds[t - off] : 0;
        __syncthreads();
        lds[t] += y;
        __syncthreads();
    }
    if (t < NBK) ebase[t] = lds[t] - v;
    if (t == 0) ebase[NBK] = ET;
    if (t < NG) cnt[t] = bpos[t + 1] - bpos[t];
}

// batch is sorted: graph boundaries without atomics.
__global__ __launch_bounds__(256) void k_bounds(const int* __restrict__ batch, int* __restrict__ bpos) {
    int i = blockIdx.x * 256 + threadIdx.x;
    if (i >= NN) return;
    int cur = batch[i];
    int prev = (i == 0) ? -1 : batch[i - 1];
    for (int g = prev + 1; g <= cur; ++g) bpos[g] = i;
    if (i == NN - 1)
        for (int g = cur + 1; g <= NG; ++g) bpos[g] = NN;
}

// Phase 3: scatter edges into bucket-major ebuf. Block-private offsets -> no global atomics.
// ebuf entry: (src << 16) | (dst & 255)
__global__ __launch_bounds__(256) void k_bscatter(const int* __restrict__ ei, const int* __restrict__ ebase,
                                                  const int* __restrict__ boff, unsigned int* __restrict__ ebuf) {
    __shared__ int cur[NBK];
    int b0 = blockIdx.x, tid = threadIdx.x;
    for (int i = tid; i < NBK; i += 256) cur[i] = ebase[i] + boff[i * SB + b0];
    __syncthreads();
#pragma unroll
    for (int pass = 0; pass < CH / 256; ++pass) {
        int e = b0 * CH + pass * 256 + tid;
        if (e < ET) {
            int s, d;
            edge_sd(e, ei, s, d);
            int pos = atomicAdd(&cur[d >> 8], 1);
            ebuf[pos] = ((unsigned)s << 16) | (unsigned)(d & 255);
        }
    }
}

// Phase 4: one block per bucket. Exact-dst LDS counting sort -> rowptr + colsrc.
__global__ __launch_bounds__(256) void k_bsort(const unsigned int* __restrict__ ebuf,
                                               const int* __restrict__ ebase,
                                               int* __restrict__ rowptr, unsigned short* __restrict__ colsrc) {
    __shared__ int cnt2[256];
    __shared__ int sc[256];
    __shared__ int cur2[256];
    int b = blockIdx.x, t = threadIdx.x;
    int base = ebase[b], n = ebase[b + 1] - base;
    cnt2[t] = 0;
    __syncthreads();
    for (int i = t; i < n; i += 256) atomicAdd(&cnt2[ebuf[base + i] & 255], 1);
    __syncthreads();
    int v = cnt2[t];
    sc[t] = v;
    __syncthreads();
    for (int off = 1; off < 256; off <<= 1) {
        int y = (t >= off) ? sc[t - off] : 0;
        __syncthreads();
        sc[t] += y;
        __syncthreads();
    }
    int excl = sc[t] - v;
    int d = b * 256 + t;
    if (d < NN) rowptr[d] = base + excl;
    if (b == 0 && t == 0) rowptr[NN] = ET;
    cur2[t] = excl;
    __syncthreads();
    for (int i = t; i < n; i += 256) {
        unsigned u = ebuf[base + i];
        int pos = atomicAdd(&cur2[u & 255], 1);
        colsrc[base + pos] = (unsigned short)(u >> 16);
    }
}

// ---------------- weight prep: fp32 [K][M2]x2 -> fp16 MFMA-fragment order (all 3 layers fused) ----------------

template <int K, int M2>
__device__ __forceinline__ void wprep_fn(int chunk, const float* __restrict__ Wl, const float* __restrict__ Wr,
                                         _Float16* __restrict__ Wfrag) {
    constexpr int MTOT = 2 * M2, NT = MTOT / 16;
    if (chunk >= MTOT * K / 8) return;
    int lane = chunk & 63, tt = chunk >> 6;
    int t = tt % NT, kt = tt / NT;
    int n = t * 16 + (lane & 15);
    int kb = kt * 32 + (lane >> 4) * 8;
    const float* src = (n < M2) ? (Wl + n) : (Wr + (n - M2));
    half8 h;
#pragma unroll
    for (int j = 0; j < 8; ++j) h[j] = (_Float16)src[(size_t)(kb + j) * M2];
    *(half8*)(Wfrag + (size_t)chunk * 8) = h;
}

__global__ __launch_bounds__(256) void k_wprep_all(const float* __restrict__ Wl1, const float* __restrict__ Wr1,
                                                   const float* __restrict__ Wl2, const float* __restrict__ Wr2,
                                                   const float* __restrict__ Wl3, const float* __restrict__ Wr3,
                                                   _Float16* __restrict__ Wf1, _Float16* __restrict__ Wf2,
                                                   _Float16* __restrict__ Wf3) {
    int b = blockIdx.x, t = threadIdx.x;
    if (b < 16)      wprep_fn<128, 128>(b * 256 + t, Wl1, Wr1, Wf1);
    else if (b < 24) wprep_fn<128, 64>((b - 16) * 256 + t, Wl2, Wr2, Wf2);
    else             wprep_fn<64, 32>((b - 24) * 256 + t, Wl3, Wr3, Wf3);
}

// ---------------- fused dual MFMA GEMM, LDS-free; A input fp16 or fp32 (fused cast) ----------------

template <typename AT>
__device__ __forceinline__ half8 load_a8(const AT* __restrict__ ap) {
    if constexpr (__is_same(AT, _Float16)) {
        return *(const half8*)ap;
    } else {
        const float4* p = (const float4*)ap;
        float4 a = p[0], b = p[1];
        half8 h;
        h[0] = (_Float16)a.x; h[1] = (_Float16)a.y; h[2] = (_Float16)a.z; h[3] = (_Float16)a.w;
        h[4] = (_Float16)b.x; h[5] = (_Float16)b.y; h[6] = (_Float16)b.z; h[7] = (_Float16)b.w;
        return h;
    }
}

template <int K, int M2, typename AT>
__global__ __launch_bounds__(256) void k_dualgemm(const AT* __restrict__ Ain,
                                                  const _Float16* __restrict__ Wfrag,
                                                  __half* __restrict__ Ol, float* __restrict__ Or) {
    constexpr int MTOT = 2 * M2;
    constexpr int NT = MTOT / 16;
    constexpr int KT = K / 32;
    int tid = threadIdx.x;
    int wid = tid >> 6, lane = tid & 63;
    int q = lane >> 4, l15 = lane & 15;
    int r0 = blockIdx.x * 64 + wid * 16;
    int arow = min(r0 + l15, NN - 1);
    const AT* ap = Ain + (size_t)arow * K + q * 8;

    floatx4 acc[NT];
#pragma unroll
    for (int t = 0; t < NT; ++t) acc[t] = (floatx4){0.f, 0.f, 0.f, 0.f};

#pragma unroll
    for (int kt = 0; kt < KT; ++kt) {
        half8 a8 = load_a8<AT>(ap + kt * 32);
        const _Float16* wp = Wfrag + ((size_t)(kt * NT) * 64 + lane) * 8;
#pragma unroll
        for (int t = 0; t < NT; ++t) {
            half8 b8 = *(const half8*)(wp + (size_t)t * 64 * 8);
            acc[t] = __builtin_amdgcn_mfma_f32_16x16x32_f16(a8, b8, acc[t], 0, 0, 0);
        }
    }

#pragma unroll
    for (int t = 0; t < NT; ++t) {
        int cn = t * 16 + l15;
#pragma unroll
        for (int reg = 0; reg < 4; ++reg) {
            int r = r0 + q * 4 + reg;
            if (r < NN) {
                if (cn < M2) Ol[(size_t)r * M2 + cn] = __float2half(acc[t][reg]);
                else         Or[(size_t)r * M2 + (cn - M2)] = acc[t][reg];
            }
        }
    }
}

// ---------------- GATv2 attention: channel-split + packed fp16 + no-max softmax, unroll-4 ----------------

template <int CP> struct HVec { hv2 h2[CP / 2]; };

template <int CP>
__device__ __forceinline__ HVec<CP> load_hv(const __half* __restrict__ p) {
    HVec<CP> r;
    if constexpr (CP == 8) { float4 t = *(const float4*)p; r = *(HVec<CP>*)&t; }
    else if constexpr (CP == 4) { float2 t = *(const float2*)p; r = *(HVec<CP>*)&t; }
    else { r.h2[0] = *(const hv2*)p; }
    return r;
}

template <int C, int EP, bool CONCAT>
__global__ __launch_bounds__(256, 8) void k_attn(const __half* __restrict__ xl, const float* __restrict__ xr,
                                                 const int* __restrict__ rowptr,
                                                 const unsigned short* __restrict__ colsrc,
                                                 const float* __restrict__ att, const float* __restrict__ bias,
                                                 float* __restrict__ out) {
    constexpr int CP = C / EP;
    int t = blockIdx.x * 256 + threadIdx.x;
    int part = t & (EP - 1);
    int nh = t >> 2;                          // EP == 4
    if (nh >= NN * H) return;
    int node = nh >> 2, h = nh & 3;           // H == 4
    int cbase = h * C + part * CP;
    hv2 xrr2[CP / 2], attv2[CP / 2];
    float acc[CP];
    {
        const float* p = xr + (size_t)node * (H * C) + cbase;
        const float* q = att + cbase;
#pragma unroll
        for (int j = 0; j < CP / 2; ++j) {
            xrr2[j] = (hv2){(_Float16)p[2 * j], (_Float16)p[2 * j + 1]};
            attv2[j] = (hv2){(_Float16)q[2 * j], (_Float16)q[2 * j + 1]};
        }
#pragma unroll
        for (int c = 0; c < CP; ++c) acc[c] = 0.f;
    }
    float denom = 0.f;
    int beg = rowptr[node], end = rowptr[node + 1];

    auto process = [&](const HVec<CP>& xv) {
        float part_s = 0.f;
#pragma unroll
        for (int j = 0; j < CP / 2; ++j) {
            hv2 z = xv.h2[j] + xrr2[j];
            hv2 l = __builtin_elementwise_max(z, z * (_Float16)0.2f);   // leaky_relu
            part_s = __builtin_amdgcn_fdot2(l, attv2[j], part_s, false);
        }
        float score = part_s;
#pragma unroll
        for (int mask = 1; mask < EP; mask <<= 1) score += __shfl_xor(score, mask, 64);
        float w = __expf(score);
        denom += w;
        const _Float16* xh = (const _Float16*)&xv;
#pragma unroll
        for (int c = 0; c < CP; ++c) acc[c] = fmaf(w, (float)xh[c], acc[c]);
    };

    int idx = beg;
    for (; idx + 4 <= end; idx += 4) {
        int s0 = colsrc[idx], s1 = colsrc[idx + 1], s2 = colsrc[idx + 2], s3 = colsrc[idx + 3];
        HVec<CP> xv0 = load_hv<CP>(xl + (size_t)s0 * (H * C) + cbase);
        HVec<CP> xv1 = load_hv<CP>(xl + (size_t)s1 * (H * C) + cbase);
        HVec<CP> xv2 = load_hv<CP>(xl + (size_t)s2 * (H * C) + cbase);
        HVec<CP> xv3 = load_hv<CP>(xl + (size_t)s3 * (H * C) + cbase);
        process(xv0);
        process(xv1);
        process(xv2);
        process(xv3);
    }
    for (; idx < end; ++idx) {
        int s = colsrc[idx];
        HVec<CP> xv = load_hv<CP>(xl + (size_t)s * (H * C) + cbase);
        process(xv);
    }

    float inv = 1.f / denom;
    float* op = out + (size_t)node * (H * C) + cbase;
    float v[CP];
#pragma unroll
    for (int c = 0; c < CP; ++c) {
        v[c] = acc[c] * inv;
        if (CONCAT) v[c] += bias[cbase + c];
    }
    if constexpr (CP == 8) {
        *(float4*)(op) = make_float4(v[0], v[1], v[2], v[3]);
        *(float4*)(op + 4) = make_float4(v[4], v[5], v[6], v[7]);
    } else if constexpr (CP == 4) {
        *(float4*)(op) = make_float4(v[0], v[1], v[2], v[3]);
    } else {
        *(float2*)(op) = make_float2(v[0], v[1]);
    }
}

// ---------------- GraphNorm reduce: one block per (graph, segment), LDS tree, C*2 atomics/block ----------------

template <int LOGC, int SPLIT>
__global__ __launch_bounds__(256) void k_gnred2(const float* __restrict__ h, const int* __restrict__ bpos,
                                                float* __restrict__ sum, float* __restrict__ sumsq) {
    constexpr int C = 1 << LOGC;
    constexpr int RG = 256 >> LOGC;      // row-groups per block
    int g = blockIdx.x / SPLIT, s = blockIdx.x % SPLIT;
    int c = threadIdx.x & (C - 1);
    int rg = threadIdx.x >> LOGC;
    int b0 = bpos[g], b1 = bpos[g + 1];
    int n = b1 - b0;
    int seg = (n + SPLIT - 1) / SPLIT;
    int r0 = b0 + s * seg;
    int r1 = min(r0 + seg, b1);
    float sv = 0.f, ssv = 0.f;
    for (int r = r0 + rg; r < r1; r += RG) {
        float x = h[(size_t)r * C + c];
        sv += x; ssv += x * x;
    }
    __shared__ float ls[256], lss[256];
    ls[threadIdx.x] = sv; lss[threadIdx.x] = ssv;
    __syncthreads();
    for (int off = 128; off >= C; off >>= 1) {
        if (threadIdx.x < off) {
            ls[threadIdx.x] += ls[threadIdx.x + off];
            lss[threadIdx.x] += lss[threadIdx.x + off];
        }
        __syncthreads();
    }
    if (threadIdx.x < C) {
        atomicAdd(&sum[g * C + threadIdx.x], ls[threadIdx.x]);
        atomicAdd(&sumsq[g * C + threadIdx.x], lss[threadIdx.x]);
    }
}

// var(out) = E[x^2] - (2s - s^2) mu^2  where out = x - mu*s.
// Writes ONLY the fp16 copy when h16 != null (fp32 h is dead downstream in that case).
__global__ __launch_bounds__(256) void k_gnnorm(float* __restrict__ h, const int* __restrict__ batch,
                                                const float* __restrict__ sum, const float* __restrict__ sumsq,
                                                const int* __restrict__ cnt, const float* __restrict__ w,
                                                const float* __restrict__ b, const float* __restrict__ ms,
                                                int logC, __half* __restrict__ h16) {
    int C = 1 << logC;
    int i = blockIdx.x * 256 + threadIdx.x;
    if (i >= NN * C) return;
    int nd = i >> logC, c = i & (C - 1);
    int g = batch[nd];
    float cg = fmaxf((float)cnt[g], 1.f);
    float mu = sum[g * C + c] / cg;
    float ex2 = sumsq[g * C + c] / cg;
    float s_ = ms[c];
    float var = ex2 - (2.f * s_ - s_ * s_) * mu * mu;
    float y = (h[i] - mu * s_) * rsqrtf(var + 1e-5f) * w[c] + b[c];
    y = fmaxf(y, 0.f);   // fused ReLU
    if (h16) h16[i] = __float2half(y);
    else     h[i] = y;
}

// ---------------- fused layer-3 tail ----------------
// k_headgn: headmean+bias (from 32-ch attn out) fused with GN sum/sumsq reduction; writes Af.

template <int SPLIT>
__global__ __launch_bounds__(256) void k_headgn(const float* __restrict__ tmp, const float* __restrict__ b3,
                                                const int* __restrict__ bpos, float* __restrict__ Af,
                                                float* __restrict__ sum, float* __restrict__ sumsq) {
    constexpr int C = 8, RG = 32;
    int g = blockIdx.x / SPLIT, s = blockIdx.x % SPLIT;
    int c = threadIdx.x & 7;
    int rg = threadIdx.x >> 3;
    int b0 = bpos[g], b1 = bpos[g + 1];
    int n = b1 - b0;
    int seg = (n + SPLIT - 1) / SPLIT;
    int r0 = b0 + s * seg;
    int r1 = min(r0 + seg, b1);
    float bias = b3[c];
    float sv = 0.f, ssv = 0.f;
    for (int r = r0 + rg; r < r1; r += RG) {
        const float* p = tmp + (size_t)r * 32 + c;
        float v = 0.25f * (p[0] + p[8] + p[16] + p[24]) + bias;
        Af[(size_t)r * C + c] = v;
        sv += v; ssv += v * v;
    }
    __shared__ float ls[256], lss[256];
    ls[threadIdx.x] = sv; lss[threadIdx.x] = ssv;
    __syncthreads();
    for (int off = 128; off >= C; off >>= 1) {
        if (threadIdx.x < off) {
            ls[threadIdx.x] += ls[threadIdx.x + off];
            lss[threadIdx.x] += lss[threadIdx.x + off];
        }
        __syncthreads();
    }
    if (threadIdx.x < C) {
        atomicAdd(&sum[g * C + threadIdx.x], ls[threadIdx.x]);
        atomicAdd(&sumsq[g * C + threadIdx.x], lss[threadIdx.x]);
    }
}

// k_gnpool: GN normalize + ReLU (C=8) fused with pool-sum reduction (pool sums only; y not stored).

template <int SPLIT>
__global__ __launch_bounds__(256) void k_gnpool(const float* __restrict__ Af, const int* __restrict__ bpos,
                                                const float* __restrict__ sum, const float* __restrict__ sumsq,
                                                const int* __restrict__ cnt, const float* __restrict__ w,
                                                const float* __restrict__ b, const float* __restrict__ ms,
                                                float* __restrict__ pool) {
    constexpr int C = 8, RG = 32;
    int g = blockIdx.x / SPLIT, s = blockIdx.x % SPLIT;
    int c = threadIdx.x & 7;
    int rg = threadIdx.x >> 3;
    int b0 = bpos[g], b1 = bpos[g + 1];
    int n = b1 - b0;
    int seg = (n + SPLIT - 1) / SPLIT;
    int r0 = b0 + s * seg;
    int r1 = min(r0 + seg, b1);
    float cg = fmaxf((float)cnt[g], 1.f);
    float mu = sum[g * C + c] / cg;
    float ex2 = sumsq[g * C + c] / cg;
    float s_ = ms[c];
    float var = ex2 - (2.f * s_ - s_ * s_) * mu * mu;
    float rs = rsqrtf(var + 1e-5f) * w[c];
    float bb = b[c], mus = mu * s_;
    float pv = 0.f;
    for (int r = r0 + rg; r < r1; r += RG) {
        float y = fmaxf((Af[(size_t)r * C + c] - mus) * rs + bb, 0.f);
        pv += y;
    }
    __shared__ float ls[256];
    ls[threadIdx.x] = pv;
    __syncthreads();
    for (int off = 128; off >= C; off >>= 1) {
        if (threadIdx.x < off) ls[threadIdx.x] += ls[threadIdx.x + off];
        __syncthreads();
    }
    if (threadIdx.x < C) atomicAdd(&pool[g * C + threadIdx.x], ls[threadIdx.x]);
}

// ---------------- pool mean + linear head ----------------

__global__ __launch_bounds__(512) void k_final(const float* __restrict__ pool, const int* __restrict__ cnt,
                                               const float* __restrict__ lw, const float* __restrict__ lb,
                                               float* __restrict__ outp) {
    __shared__ float feat[512];
    int t = threadIdx.x;
    int g = t >> 3;
    float f = pool[t] / fmaxf((float)cnt[g], 1.f);
    feat[t] = f;
    outp[256 + t] = f;          // features: d_out[256 .. 768)
    __syncthreads();
    if (t < 256) {
        int g2 = t >> 2, o = t & 3;
        float a = lb[o];
#pragma unroll
        for (int cc = 0; cc < 8; ++cc) a += feat[g2 * 8 + cc] * lw[cc * 4 + o];
        outp[t] = a;            // logits: d_out[0 .. 256)
    }
}

// ---------------- host ----------------

extern "C" void kernel_launch(void* const* d_in, const int* in_sizes, int n_in,
                              void* d_out, int out_size, void* d_ws, size_t ws_size,
                              hipStream_t stream) {
    const float* x    = (const float*)d_in[0];
    const int*   ei   = (const int*)d_in[1];
    const int*   batch= (const int*)d_in[2];
    const float *w_l1 = (const float*)d_in[3],  *w_r1 = (const float*)d_in[4];
    const float *att1 = (const float*)d_in[5],  *b1   = (const float*)d_in[6];
    const float *gn1w = (const float*)d_in[7],  *gn1b = (const float*)d_in[8],  *gn1s = (const float*)d_in[9];
    const float *w_l2 = (const float*)d_in[10], *w_r2 = (const float*)d_in[11];
    const float *att2 = (const float*)d_in[12], *b2   = (const float*)d_in[13];
    const float *gn2w = (const float*)d_in[14], *gn2b = (const float*)d_in[15], *gn2s = (const float*)d_in[16];
    const float *w_l3 = (const float*)d_in[17], *w_r3 = (const float*)d_in[18];
    const float *att3 = (const float*)d_in[19], *b3   = (const float*)d_in[20];
    const float *gn3w = (const float*)d_in[21], *gn3b = (const float*)d_in[22], *gn3s = (const float*)d_in[23];
    const float *lw   = (const float*)d_in[24], *lb   = (const float*)d_in[25];

    char* ws = (char*)d_ws;
    size_t off = 0;
    auto alloc = [&](size_t bytes) -> void* {
        void* p = ws + off;
        off += (bytes + 255) & ~(size_t)255;
        return p;
    };
    __half* Ah  = (__half*)alloc((size_t)NN * 128 * 2);  // x_l fp16 (GEMM out, attn gather operand)
    __half* Xh  = (__half*)alloc((size_t)NN * 128 * 2);  // fp16 layer activations (gnnorm out)
    float*  B   = (float*)alloc((size_t)NN * 128 * 4);   // x_r / layer-out scratch
    float*  Cb  = (float*)alloc((size_t)NN * 64 * 4);    // h2 scratch
    float*  Af  = (float*)alloc((size_t)NN * 8 * 4);     // layer-3 head-mean features
    _Float16* Wf1 = (_Float16*)alloc((size_t)256 * 128 * 2);  // frag-ordered weights l1
    _Float16* Wf2 = (_Float16*)alloc((size_t)128 * 128 * 2);  // l2
    _Float16* Wf3 = (_Float16*)alloc((size_t)64 * 64 * 2);    // l3
    int* rowptr = (int*)alloc((size_t)(NN + 1) * 4);
    unsigned short* colsrc = (unsigned short*)alloc((size_t)ET * 2);
    unsigned int* ebuf = (unsigned int*)alloc((size_t)ET * 4);
    int* bcnt   = (int*)alloc((size_t)NBK * SB * 4);
    int* boff   = (int*)alloc((size_t)NBK * SB * 4);
    int* tot    = (int*)alloc((size_t)NBK * 4);
    int* ebase  = (int*)alloc((size_t)(NBK + 1) * 4);
    int* bpos   = (int*)alloc((size_t)(NG + 1) * 4);
    int* cnt    = (int*)alloc((size_t)NG * 4);
    char* zbase = ws + off;                              // everything below gets one memset
    float* sum1 = (float*)alloc((size_t)NG * 128 * 4);
    float* sq1  = (float*)alloc((size_t)NG * 128 * 4);
    float* sum2 = (float*)alloc((size_t)NG * 64 * 4);
    float* sq2  = (float*)alloc((size_t)NG * 64 * 4);
    float* sum3 = (float*)alloc((size_t)NG * 8 * 4);
    float* sq3  = (float*)alloc((size_t)NG * 8 * 4);
    float* pool = (float*)alloc((size_t)NG * 8 * 4);
    size_t zbytes = (size_t)((ws + off) - zbase);
    (void)hipMemsetAsync(zbase, 0, zbytes, stream);

    k_wprep_all<<<26, 256, 0, stream>>>(w_l1, w_r1, w_l2, w_r2, w_l3, w_r3, Wf1, Wf2, Wf3);
    k_bounds<<<(NN + 255) / 256, 256, 0, stream>>>(batch, bpos);
    k_bhist<<<SB, 256, 0, stream>>>(ei, bcnt);
    k_bscanA<<<NBK, 256, 0, stream>>>(bcnt, boff, tot);
    k_bscanB<<<1, 256, 0, stream>>>(tot, ebase, bpos, cnt);
    k_bscatter<<<SB, 256, 0, stream>>>(ei, ebase, boff, ebuf);
    k_bsort<<<NBK, 256, 0, stream>>>(ebuf, ebase, rowptr, colsrc);

    int gA4 = (NN * H * 4) / 256;            // attention grid, EP=4 -> 3125 blocks exact
    int gD  = (NN + 63) / 64;                // dualgemm grid, 64 rows/block

    // ---- layer 1: 128 -> 4x32 concat -> 128  (fp32 input, fused cast)
    k_dualgemm<128, 128, float><<<gD, 256, 0, stream>>>(x, Wf1, Ah, B);
    k_attn<32, 4, true><<<gA4, 256, 0, stream>>>(Ah, B, rowptr, colsrc, att1, b1, B);
    k_gnred2<7, 8><<<NG * 8, 256, 0, stream>>>(B, bpos, sum1, sq1);
    k_gnnorm<<<(NN * 128 + 255) / 256, 256, 0, stream>>>(B, batch, sum1, sq1, cnt, gn1w, gn1b, gn1s, 7, Xh);

    // ---- layer 2: 128 -> 4x16 concat -> 64
    k_dualgemm<128, 64, _Float16><<<gD, 256, 0, stream>>>((const _Float16*)Xh, Wf2, Ah, Cb);
    k_attn<16, 4, true><<<gA4, 256, 0, stream>>>(Ah, Cb, rowptr, colsrc, att2, b2, Cb);
    k_gnred2<6, 8><<<NG * 8, 256, 0, stream>>>(Cb, bpos, sum2, sq2);
    k_gnnorm<<<(NN * 64 + 255) / 256, 256, 0, stream>>>(Cb, batch, sum2, sq2, cnt, gn2w, gn2b, gn2s, 6, Xh);

    // ---- layer 3: 64 -> 4x8 mean -> 8, fused tail
    k_dualgemm<64, 32, _Float16><<<gD, 256, 0, stream>>>((const _Float16*)Xh, Wf3, Ah, B);
    k_attn<8, 4, false><<<gA4, 256, 0, stream>>>(Ah, B, rowptr, colsrc, att3, nullptr, B);
    k_headgn<8><<<NG * 8, 256, 0, stream>>>(B, b3, bpos, Af, sum3, sq3);
    k_gnpool<8><<<NG * 8, 256, 0, stream>>>(Af, bpos, sum3, sq3, cnt, gn3w, gn3b, gn3s, pool);
    k_final<<<1, 512, 0, stream>>>(pool, cnt, lw, lb, (float*)d_out);
}

// Round 15
// 324.600 us; speedup vs baseline: 1.5623x; 1.0361x over previous
//
#include <hip/hip_runtime.h>
#include <hip/hip_fp16.h>
#include <math.h>

#define NN 50000
#define NE 800000
#define ET (NE + NN)
#define NG 64
#define H 4
#define NBK 196                   // dst buckets (dst >> 8)
#define CH 4096                   // edges per chunk
#define SB ((ET + CH - 1) / CH)   // 208 edge chunks

typedef _Float16 half8 __attribute__((ext_vector_type(8)));
typedef _Float16 hv2 __attribute__((ext_vector_type(2)));
typedef float floatx4 __attribute__((ext_vector_type(4)));

// ---------------- weight prep device fn ----------------

template <int K, int M2>
__device__ __forceinline__ void wprep_fn(int chunk, const float* __restrict__ Wl, const float* __restrict__ Wr,
                                         _Float16* __restrict__ Wfrag) {
    constexpr int MTOT = 2 * M2, NT = MTOT / 16;
    if (chunk >= MTOT * K / 8) return;
    int lane = chunk & 63, tt = chunk >> 6;
    int t = tt % NT, kt = tt / NT;
    int n = t * 16 + (lane & 15);
    int kb = kt * 32 + (lane >> 4) * 8;
    const float* src = (n < M2) ? (Wl + n) : (Wr + (n - M2));
    half8 h;
#pragma unroll
    for (int j = 0; j < 8; ++j) h[j] = (_Float16)src[(size_t)(kb + j) * M2];
    *(half8*)(Wfrag + (size_t)chunk * 8) = h;
}

// ---------------- fused prep: wprep (26 blocks) + bounds (196) + bhist (208) ----------------

__global__ __launch_bounds__(256) void k_prep(const float* __restrict__ Wl1, const float* __restrict__ Wr1,
                                              const float* __restrict__ Wl2, const float* __restrict__ Wr2,
                                              const float* __restrict__ Wl3, const float* __restrict__ Wr3,
                                              _Float16* __restrict__ Wf1, _Float16* __restrict__ Wf2,
                                              _Float16* __restrict__ Wf3,
                                              const int* __restrict__ batch, int* __restrict__ bpos,
                                              const int* __restrict__ ei, int* __restrict__ bcnt) {
    int b = blockIdx.x, t = threadIdx.x;
    if (b < 16) { wprep_fn<128, 128>(b * 256 + t, Wl1, Wr1, Wf1); return; }
    if (b < 24) { wprep_fn<128, 64>((b - 16) * 256 + t, Wl2, Wr2, Wf2); return; }
    if (b < 26) { wprep_fn<64, 32>((b - 24) * 256 + t, Wl3, Wr3, Wf3); return; }
    if (b < 26 + NBK) {
        int i = (b - 26) * 256 + t;
        if (i >= NN) return;
        int cur = batch[i];
        int prev = (i == 0) ? -1 : batch[i - 1];
        for (int g = prev + 1; g <= cur; ++g) bpos[g] = i;
        if (i == NN - 1)
            for (int g = cur + 1; g <= NG; ++g) bpos[g] = NN;
        return;
    }
    // bhist
    __shared__ int hist[NBK];
    int b0 = b - 26 - NBK;
    for (int i = t; i < NBK; i += 256) hist[i] = 0;
    __syncthreads();
#pragma unroll
    for (int pass = 0; pass < CH / 256; ++pass) {
        int e = b0 * CH + pass * 256 + t;
        if (e < ET) {
            int d = (e < NE) ? ei[NE + e] : (e - NE);
            atomicAdd(&hist[d >> 8], 1);
        }
    }
    __syncthreads();
    if (t < NBK) bcnt[t * SB + b0] = hist[t];
}

// ---------------- CSR: per-bucket scan of chunk counts ----------------

__global__ __launch_bounds__(256) void k_bscanA(const int* __restrict__ bcnt, int* __restrict__ boff,
                                                int* __restrict__ tot) {
    __shared__ int lds[256];
    int b = blockIdx.x, t = threadIdx.x;
    int v = (t < SB) ? bcnt[b * SB + t] : 0;
    lds[t] = v;
    __syncthreads();
    for (int off = 1; off < 256; off <<= 1) {
        int y = (t >= off) ? lds[t - off] : 0;
        __syncthreads();
        lds[t] += y;
        __syncthreads();
    }
    if (t < SB) boff[b * SB + t] = lds[t] - v;   // exclusive within bucket
    if (t == 255) tot[b] = lds[255];
}

// ---------------- CSR: scatter into bucket-major ebuf (ebase derived locally from tot) ----------------
// ebuf entry: (src << 16) | (dst & 255)

__device__ __forceinline__ void edge_sd(int e, const int* __restrict__ ei, int& s, int& d) {
    if (e < NE) { s = ei[e]; d = ei[NE + e]; } else { s = e - NE; d = s; }
}

__global__ __launch_bounds__(256) void k_bscatter(const int* __restrict__ ei, const int* __restrict__ tot,
                                                  const int* __restrict__ boff, unsigned int* __restrict__ ebuf) {
    __shared__ int eb[256];
    __shared__ int cur[NBK];
    int b0 = blockIdx.x, t = threadIdx.x;
    int v = (t < NBK) ? tot[t] : 0;
    eb[t] = v;
    __syncthreads();
    for (int off = 1; off < 256; off <<= 1) {
        int y = (t >= off) ? eb[t - off] : 0;
        __syncthreads();
        eb[t] += y;
        __syncthreads();
    }
    if (t < NBK) cur[t] = (eb[t] - v) + boff[t * SB + b0];
    __syncthreads();
#pragma unroll
    for (int pass = 0; pass < CH / 256; ++pass) {
        int e = b0 * CH + pass * 256 + t;
        if (e < ET) {
            int s, d;
            edge_sd(e, ei, s, d);
            int pos = atomicAdd(&cur[d >> 8], 1);
            ebuf[pos] = ((unsigned)s << 16) | (unsigned)(d & 255);
        }
    }
}

// ---------------- CSR: per-bucket exact-dst counting sort -> rowptr + colsrc ----------------

__global__ __launch_bounds__(256) void k_bsort(const unsigned int* __restrict__ ebuf,
                                               const int* __restrict__ tot,
                                               int* __restrict__ rowptr, unsigned short* __restrict__ colsrc) {
    __shared__ int eb[256];
    __shared__ int sbase;
    __shared__ int cnt2[256];
    __shared__ int sc[256];
    __shared__ int cur2[256];
    int b = blockIdx.x, t = threadIdx.x;
    int v = (t < NBK) ? tot[t] : 0;
    eb[t] = v;
    __syncthreads();
    for (int off = 1; off < 256; off <<= 1) {
        int y = (t >= off) ? eb[t - off] : 0;
        __syncthreads();
        eb[t] += y;
        __syncthreads();
    }
    if (t == b) sbase = eb[t] - v;
    __syncthreads();
    int base = sbase, n = tot[b];
    cnt2[t] = 0;
    __syncthreads();
    for (int i = t; i < n; i += 256) atomicAdd(&cnt2[ebuf[base + i] & 255], 1);
    __syncthreads();
    int cv = cnt2[t];
    sc[t] = cv;
    __syncthreads();
    for (int off = 1; off < 256; off <<= 1) {
        int y = (t >= off) ? sc[t - off] : 0;
        __syncthreads();
        sc[t] += y;
        __syncthreads();
    }
    int excl = sc[t] - cv;
    int d = b * 256 + t;
    if (d < NN) rowptr[d] = base + excl;
    if (b == 0 && t == 0) rowptr[NN] = ET;
    cur2[t] = excl;
    __syncthreads();
    for (int i = t; i < n; i += 256) {
        unsigned u = ebuf[base + i];
        int pos = atomicAdd(&cur2[u & 255], 1);
        colsrc[base + pos] = (unsigned short)(u >> 16);
    }
}

// ---------------- fused dual MFMA GEMM, LDS-free; A input fp16 or fp32 (fused cast) ----------------

template <typename AT>
__device__ __forceinline__ half8 load_a8(const AT* __restrict__ ap) {
    if constexpr (__is_same(AT, _Float16)) {
        return *(const half8*)ap;
    } else {
        const float4* p = (const float4*)ap;
        float4 a = p[0], b = p[1];
        half8 h;
        h[0] = (_Float16)a.x; h[1] = (_Float16)a.y; h[2] = (_Float16)a.z; h[3] = (_Float16)a.w;
        h[4] = (_Float16)b.x; h[5] = (_Float16)b.y; h[6] = (_Float16)b.z; h[7] = (_Float16)b.w;
        return h;
    }
}

template <int K, int M2, typename AT>
__global__ __launch_bounds__(256) void k_dualgemm(const AT* __restrict__ Ain,
                                                  const _Float16* __restrict__ Wfrag,
                                                  __half* __restrict__ Ol, float* __restrict__ Or) {
    constexpr int MTOT = 2 * M2;
    constexpr int NT = MTOT / 16;
    constexpr int KT = K / 32;
    int tid = threadIdx.x;
    int wid = tid >> 6, lane = tid & 63;
    int q = lane >> 4, l15 = lane & 15;
    int r0 = blockIdx.x * 64 + wid * 16;
    int arow = min(r0 + l15, NN - 1);
    const AT* ap = Ain + (size_t)arow * K + q * 8;

    floatx4 acc[NT];
#pragma unroll
    for (int t = 0; t < NT; ++t) acc[t] = (floatx4){0.f, 0.f, 0.f, 0.f};

#pragma unroll
    for (int kt = 0; kt < KT; ++kt) {
        half8 a8 = load_a8<AT>(ap + kt * 32);
        const _Float16* wp = Wfrag + ((size_t)(kt * NT) * 64 + lane) * 8;
#pragma unroll
        for (int t = 0; t < NT; ++t) {
            half8 b8 = *(const half8*)(wp + (size_t)t * 64 * 8);
            acc[t] = __builtin_amdgcn_mfma_f32_16x16x32_f16(a8, b8, acc[t], 0, 0, 0);
        }
    }

#pragma unroll
    for (int t = 0; t < NT; ++t) {
        int cn = t * 16 + l15;
#pragma unroll
        for (int reg = 0; reg < 4; ++reg) {
            int r = r0 + q * 4 + reg;
            if (r < NN) {
                if (cn < M2) Ol[(size_t)r * M2 + cn] = __float2half(acc[t][reg]);
                else         Or[(size_t)r * M2 + (cn - M2)] = acc[t][reg];
            }
        }
    }
}

// ---------------- GATv2 attention: channel-split (generic EP) + packed fp16 + no-max softmax ----------------
// EP lanes split C channels; all walk the same edge list. 16B loads at CP=8 for all layers now
// (l1 EP=4, l2 EP=2, l3 EP=1 -> zero shuffles).

template <int CP> struct HVec { hv2 h2[CP / 2]; };

template <int CP>
__device__ __forceinline__ HVec<CP> load_hv(const __half* __restrict__ p) {
    HVec<CP> r;
    if constexpr (CP == 8) { float4 t = *(const float4*)p; r = *(HVec<CP>*)&t; }
    else if constexpr (CP == 4) { float2 t = *(const float2*)p; r = *(HVec<CP>*)&t; }
    else { r.h2[0] = *(const hv2*)p; }
    return r;
}

template <int C, int EP, bool CONCAT>
__global__ __launch_bounds__(256, 8) void k_attn(const __half* __restrict__ xl, const float* __restrict__ xr,
                                                 const int* __restrict__ rowptr,
                                                 const unsigned short* __restrict__ colsrc,
                                                 const float* __restrict__ att, const float* __restrict__ bias,
                                                 float* __restrict__ out) {
    constexpr int CP = C / EP;
    constexpr int LEP = (EP == 4) ? 2 : ((EP == 2) ? 1 : 0);
    int t = blockIdx.x * 256 + threadIdx.x;
    int part = t & (EP - 1);
    int nh = t >> LEP;
    if (nh >= NN * H) return;
    int node = nh >> 2, h = nh & 3;           // H == 4
    int cbase = h * C + part * CP;
    hv2 xrr2[CP / 2], attv2[CP / 2];
    float acc[CP];
    {
        const float* p = xr + (size_t)node * (H * C) + cbase;
        const float* q = att + cbase;
#pragma unroll
        for (int j = 0; j < CP / 2; ++j) {
            xrr2[j] = (hv2){(_Float16)p[2 * j], (_Float16)p[2 * j + 1]};
            attv2[j] = (hv2){(_Float16)q[2 * j], (_Float16)q[2 * j + 1]};
        }
#pragma unroll
        for (int c = 0; c < CP; ++c) acc[c] = 0.f;
    }
    float denom = 0.f;
    int beg = rowptr[node], end = rowptr[node + 1];

    auto process = [&](const HVec<CP>& xv) {
        float part_s = 0.f;
#pragma unroll
        for (int j = 0; j < CP / 2; ++j) {
            hv2 z = xv.h2[j] + xrr2[j];
            hv2 l = __builtin_elementwise_max(z, z * (_Float16)0.2f);   // leaky_relu
            part_s = __builtin_amdgcn_fdot2(l, attv2[j], part_s, false);
        }
        float score = part_s;
#pragma unroll
        for (int mask = 1; mask < EP; mask <<= 1) score += __shfl_xor(score, mask, 64);
        float w = __expf(score);
        denom += w;
        const _Float16* xh = (const _Float16*)&xv;
#pragma unroll
        for (int c = 0; c < CP; ++c) acc[c] = fmaf(w, (float)xh[c], acc[c]);
    };

    int idx = beg;
    for (; idx + 4 <= end; idx += 4) {
        int s0 = colsrc[idx], s1 = colsrc[idx + 1], s2 = colsrc[idx + 2], s3 = colsrc[idx + 3];
        HVec<CP> xv0 = load_hv<CP>(xl + (size_t)s0 * (H * C) + cbase);
        HVec<CP> xv1 = load_hv<CP>(xl + (size_t)s1 * (H * C) + cbase);
        HVec<CP> xv2 = load_hv<CP>(xl + (size_t)s2 * (H * C) + cbase);
        HVec<CP> xv3 = load_hv<CP>(xl + (size_t)s3 * (H * C) + cbase);
        process(xv0);
        process(xv1);
        process(xv2);
        process(xv3);
    }
    for (; idx < end; ++idx) {
        int s = colsrc[idx];
        HVec<CP> xv = load_hv<CP>(xl + (size_t)s * (H * C) + cbase);
        process(xv);
    }

    float inv = 1.f / denom;
    float* op = out + (size_t)node * (H * C) + cbase;
    float v[CP];
#pragma unroll
    for (int c = 0; c < CP; ++c) {
        v[c] = acc[c] * inv;
        if (CONCAT) v[c] += bias[cbase + c];
    }
    if constexpr (CP == 8) {
        *(float4*)(op) = make_float4(v[0], v[1], v[2], v[3]);
        *(float4*)(op + 4) = make_float4(v[4], v[5], v[6], v[7]);
    } else if constexpr (CP == 4) {
        *(float4*)(op) = make_float4(v[0], v[1], v[2], v[3]);
    } else {
        *(float2*)(op) = make_float2(v[0], v[1]);
    }
}

// ---------------- GraphNorm reduce: one block per (graph, segment), LDS tree, C*2 atomics/block ----------------

template <int LOGC, int SPLIT>
__global__ __launch_bounds__(256) void k_gnred2(const float* __restrict__ h, const int* __restrict__ bpos,
                                                float* __restrict__ sum, float* __restrict__ sumsq) {
    constexpr int C = 1 << LOGC;
    constexpr int RG = 256 >> LOGC;      // row-groups per block
    int g = blockIdx.x / SPLIT, s = blockIdx.x % SPLIT;
    int c = threadIdx.x & (C - 1);
    int rg = threadIdx.x >> LOGC;
    int b0 = bpos[g], b1 = bpos[g + 1];
    int n = b1 - b0;
    int seg = (n + SPLIT - 1) / SPLIT;
    int r0 = b0 + s * seg;
    int r1 = min(r0 + seg, b1);
    float sv = 0.f, ssv = 0.f;
    for (int r = r0 + rg; r < r1; r += RG) {
        float x = h[(size_t)r * C + c];
        sv += x; ssv += x * x;
    }
    __shared__ float ls[256], lss[256];
    ls[threadIdx.x] = sv; lss[threadIdx.x] = ssv;
    __syncthreads();
    for (int off = 128; off >= C; off >>= 1) {
        if (threadIdx.x < off) {
            ls[threadIdx.x] += ls[threadIdx.x + off];
            lss[threadIdx.x] += lss[threadIdx.x + off];
        }
        __syncthreads();
    }
    if (threadIdx.x < C) {
        atomicAdd(&sum[g * C + threadIdx.x], ls[threadIdx.x]);
        atomicAdd(&sumsq[g * C + threadIdx.x], lss[threadIdx.x]);
    }
}

// var(out) = E[x^2] - (2s - s^2) mu^2  where out = x - mu*s.
// Writes ONLY the fp16 copy when h16 != null (fp32 h is dead downstream then).
__global__ __launch_bounds__(256) void k_gnnorm(float* __restrict__ h, const int* __restrict__ batch,
                                                const float* __restrict__ sum, const float* __restrict__ sumsq,
                                                const int* __restrict__ bpos, const float* __restrict__ w,
                                                const float* __restrict__ b, const float* __restrict__ ms,
                                                int logC, __half* __restrict__ h16) {
    int C = 1 << logC;
    int i = blockIdx.x * 256 + threadIdx.x;
    if (i >= NN * C) return;
    int nd = i >> logC, c = i & (C - 1);
    int g = batch[nd];
    float cg = fmaxf((float)(bpos[g + 1] - bpos[g]), 1.f);
    float mu = sum[g * C + c] / cg;
    float ex2 = sumsq[g * C + c] / cg;
    float s_ = ms[c];
    float var = ex2 - (2.f * s_ - s_ * s_) * mu * mu;
    float y = (h[i] - mu * s_) * rsqrtf(var + 1e-5f) * w[c] + b[c];
    y = fmaxf(y, 0.f);   // fused ReLU
    if (h16) h16[i] = __float2half(y);
    else     h[i] = y;
}

// ---------------- fused layer-3 tail ----------------
// k_headgn: headmean+bias (from 32-ch attn out) fused with GN sum/sumsq reduction; writes Af.

template <int SPLIT>
__global__ __launch_bounds__(256) void k_headgn(const float* __restrict__ tmp, const float* __restrict__ b3,
                                                const int* __restrict__ bpos, float* __restrict__ Af,
                                                float* __restrict__ sum, float* __restrict__ sumsq) {
    constexpr int C = 8, RG = 32;
    int g = blockIdx.x / SPLIT, s = blockIdx.x % SPLIT;
    int c = threadIdx.x & 7;
    int rg = threadIdx.x >> 3;
    int b0 = bpos[g], b1 = bpos[g + 1];
    int n = b1 - b0;
    int seg = (n + SPLIT - 1) / SPLIT;
    int r0 = b0 + s * seg;
    int r1 = min(r0 + seg, b1);
    float bias = b3[c];
    float sv = 0.f, ssv = 0.f;
    for (int r = r0 + rg; r < r1; r += RG) {
        const float* p = tmp + (size_t)r * 32 + c;
        float v = 0.25f * (p[0] + p[8] + p[16] + p[24]) + bias;
        Af[(size_t)r * C + c] = v;
        sv += v; ssv += v * v;
    }
    __shared__ float ls[256], lss[256];
    ls[threadIdx.x] = sv; lss[threadIdx.x] = ssv;
    __syncthreads();
    for (int off = 128; off >= C; off >>= 1) {
        if (threadIdx.x < off) {
            ls[threadIdx.x] += ls[threadIdx.x + off];
            lss[threadIdx.x] += lss[threadIdx.x + off];
        }
        __syncthreads();
    }
    if (threadIdx.x < C) {
        atomicAdd(&sum[g * C + threadIdx.x], ls[threadIdx.x]);
        atomicAdd(&sumsq[g * C + threadIdx.x], lss[threadIdx.x]);
    }
}

// k_gnpool: GN normalize + ReLU (C=8) fused with pool-sum reduction (pool sums only).

template <int SPLIT>
__global__ __launch_bounds__(256) void k_gnpool(const float* __restrict__ Af, const int* __restrict__ bpos,
                                                const float* __restrict__ sum, const float* __restrict__ sumsq,
                                                const float* __restrict__ w,
                                                const float* __restrict__ b, const float* __restrict__ ms,
                                                float* __restrict__ pool) {
    constexpr int C = 8, RG = 32;
    int g = blockIdx.x / SPLIT, s = blockIdx.x % SPLIT;
    int c = threadIdx.x & 7;
    int rg = threadIdx.x >> 3;
    int b0 = bpos[g], b1 = bpos[g + 1];
    int n = b1 - b0;
    int seg = (n + SPLIT - 1) / SPLIT;
    int r0 = b0 + s * seg;
    int r1 = min(r0 + seg, b1);
    float cg = fmaxf((float)n, 1.f);
    float mu = sum[g * C + c] / cg;
    float ex2 = sumsq[g * C + c] / cg;
    float s_ = ms[c];
    float var = ex2 - (2.f * s_ - s_ * s_) * mu * mu;
    float rs = rsqrtf(var + 1e-5f) * w[c];
    float bb = b[c], mus = mu * s_;
    float pv = 0.f;
    for (int r = r0 + rg; r < r1; r += RG) {
        float y = fmaxf((Af[(size_t)r * C + c] - mus) * rs + bb, 0.f);
        pv += y;
    }
    __shared__ float ls[256];
    ls[threadIdx.x] = pv;
    __syncthreads();
    for (int off = 128; off >= C; off >>= 1) {
        if (threadIdx.x < off) ls[threadIdx.x] += ls[threadIdx.x + off];
        __syncthreads();
    }
    if (threadIdx.x < C) atomicAdd(&pool[g * C + threadIdx.x], ls[threadIdx.x]);
}

// ---------------- pool mean + linear head ----------------

__global__ __launch_bounds__(512) void k_final(const float* __restrict__ pool, const int* __restrict__ bpos,
                                               const float* __restrict__ lw, const float* __restrict__ lb,
                                               float* __restrict__ outp) {
    __shared__ float feat[512];
    int t = threadIdx.x;
    int g = t >> 3;
    float f = pool[t] / fmaxf((float)(bpos[g + 1] - bpos[g]), 1.f);
    feat[t] = f;
    outp[256 + t] = f;          // features: d_out[256 .. 768)
    __syncthreads();
    if (t < 256) {
        int g2 = t >> 2, o = t & 3;
        float a = lb[o];
#pragma unroll
        for (int cc = 0; cc < 8; ++cc) a += feat[g2 * 8 + cc] * lw[cc * 4 + o];
        outp[t] = a;            // logits: d_out[0 .. 256)
    }
}

// ---------------- host ----------------

extern "C" void kernel_launch(void* const* d_in, const int* in_sizes, int n_in,
                              void* d_out, int out_size, void* d_ws, size_t ws_size,
                              hipStream_t stream) {
    const float* x    = (const float*)d_in[0];
    const int*   ei   = (const int*)d_in[1];
    const int*   batch= (const int*)d_in[2];
    const float *w_l1 = (const float*)d_in[3],  *w_r1 = (const float*)d_in[4];
    const float *att1 = (const float*)d_in[5],  *b1   = (const float*)d_in[6];
    const float *gn1w = (const float*)d_in[7],  *gn1b = (const float*)d_in[8],  *gn1s = (const float*)d_in[9];
    const float *w_l2 = (const float*)d_in[10], *w_r2 = (const float*)d_in[11];
    const float *att2 = (const float*)d_in[12], *b2   = (const float*)d_in[13];
    const float *gn2w = (const float*)d_in[14], *gn2b = (const float*)d_in[15], *gn2s = (const float*)d_in[16];
    const float *w_l3 = (const float*)d_in[17], *w_r3 = (const float*)d_in[18];
    const float *att3 = (const float*)d_in[19], *b3   = (const float*)d_in[20];
    const float *gn3w = (const float*)d_in[21], *gn3b = (const float*)d_in[22], *gn3s = (const float*)d_in[23];
    const float *lw   = (const float*)d_in[24], *lb   = (const float*)d_in[25];

    char* ws = (char*)d_ws;
    size_t off = 0;
    auto alloc = [&](size_t bytes) -> void* {
        void* p = ws + off;
        off += (bytes + 255) & ~(size_t)255;
        return p;
    };
    __half* Ah  = (__half*)alloc((size_t)NN * 128 * 2);  // x_l fp16 (GEMM out, attn gather operand)
    __half* Xh  = (__half*)alloc((size_t)NN * 128 * 2);  // fp16 layer activations (gnnorm out)
    float*  B   = (float*)alloc((size_t)NN * 128 * 4);   // x_r / layer-out scratch
    float*  Cb  = (float*)alloc((size_t)NN * 64 * 4);    // h2 scratch
    float*  Af  = (float*)alloc((size_t)NN * 8 * 4);     // layer-3 head-mean features
    _Float16* Wf1 = (_Float16*)alloc((size_t)256 * 128 * 2);  // frag-ordered weights l1
    _Float16* Wf2 = (_Float16*)alloc((size_t)128 * 128 * 2);  // l2
    _Float16* Wf3 = (_Float16*)alloc((size_t)64 * 64 * 2);    // l3
    int* rowptr = (int*)alloc((size_t)(NN + 1) * 4);
    unsigned short* colsrc = (unsigned short*)alloc((size_t)ET * 2);
    unsigned int* ebuf = (unsigned int*)alloc((size_t)ET * 4);
    int* bcnt   = (int*)alloc((size_t)NBK * SB * 4);
    int* boff   = (int*)alloc((size_t)NBK * SB * 4);
    int* tot    = (int*)alloc((size_t)NBK * 4);
    int* bpos   = (int*)alloc((size_t)(NG + 1) * 4);
    char* zbase = ws + off;                              // everything below gets one memset
    float* sum1 = (float*)alloc((size_t)NG * 128 * 4);
    float* sq1  = (float*)alloc((size_t)NG * 128 * 4);
    float* sum2 = (float*)alloc((size_t)NG * 64 * 4);
    float* sq2  = (float*)alloc((size_t)NG * 64 * 4);
    float* sum3 = (float*)alloc((size_t)NG * 8 * 4);
    float* sq3  = (float*)alloc((size_t)NG * 8 * 4);
    float* pool = (float*)alloc((size_t)NG * 8 * 4);
    size_t zbytes = (size_t)((ws + off) - zbase);
    (void)hipMemsetAsync(zbase, 0, zbytes, stream);

    k_prep<<<26 + NBK + SB, 256, 0, stream>>>(w_l1, w_r1, w_l2, w_r2, w_l3, w_r3, Wf1, Wf2, Wf3,
                                              batch, bpos, ei, bcnt);
    k_bscanA<<<NBK, 256, 0, stream>>>(bcnt, boff, tot);
    k_bscatter<<<SB, 256, 0, stream>>>(ei, tot, boff, ebuf);
    k_bsort<<<NBK, 256, 0, stream>>>(ebuf, tot, rowptr, colsrc);

    int gA1 = (NN * H * 4) / 256;                 // l1: EP=4 -> 3125 blocks exact
    int gA2 = (NN * H * 2 + 255) / 256;           // l2: EP=2
    int gA3 = (NN * H + 255) / 256;               // l3: EP=1
    int gD  = (NN + 63) / 64;                     // dualgemm grid, 64 rows/block

    // ---- layer 1: 128 -> 4x32 concat -> 128  (fp32 input, fused cast)
    k_dualgemm<128, 128, float><<<gD, 256, 0, stream>>>(x, Wf1, Ah, B);
    k_attn<32, 4, true><<<gA1, 256, 0, stream>>>(Ah, B, rowptr, colsrc, att1, b1, B);
    k_gnred2<7, 8><<<NG * 8, 256, 0, stream>>>(B, bpos, sum1, sq1);
    k_gnnorm<<<(NN * 128 + 255) / 256, 256, 0, stream>>>(B, batch, sum1, sq1, bpos, gn1w, gn1b, gn1s, 7, Xh);

    // ---- layer 2: 128 -> 4x16 concat -> 64
    k_dualgemm<128, 64, _Float16><<<gD, 256, 0, stream>>>((const _Float16*)Xh, Wf2, Ah, Cb);
    k_attn<16, 2, true><<<gA2, 256, 0, stream>>>(Ah, Cb, rowptr, colsrc, att2, b2, Cb);
    k_gnred2<6, 8><<<NG * 8, 256, 0, stream>>>(Cb, bpos, sum2, sq2);
    k_gnnorm<<<(NN * 64 + 255) / 256, 256, 0, stream>>>(Cb, batch, sum2, sq2, bpos, gn2w, gn2b, gn2s, 6, Xh);

    // ---- layer 3: 64 -> 4x8 mean -> 8, fused tail
    k_dualgemm<64, 32, _Float16><<<gD, 256, 0, stream>>>((const _Float16*)Xh, Wf3, Ah, B);
    k_attn<8, 1, false><<<gA3, 256, 0, stream>>>(Ah, B, rowptr, colsrc, att3, nullptr, B);
    k_headgn<8><<<NG * 8, 256, 0, stream>>>(B, b3, bpos, Af, sum3, sq3);
    k_gnpool<8><<<NG * 8, 256, 0, stream>>>(Af, bpos, sum3, sq3, gn3w, gn3b, gn3s, pool);
    k_final<<<1, 512, 0, stream>>>(pool, bpos, lw, lb, (float*)d_out);
}

// Round 16
// 323.411 us; speedup vs baseline: 1.5680x; 1.0037x over previous
//
#include <hip/hip_runtime.h>
#include <hip/hip_fp16.h>
#include <math.h>

#define NN 50000
#define NE 800000
#define ET (NE + NN)
#define NG 64
#define H 4
#define NBK 196                   // dst buckets (dst >> 8)
#define CH 2048                   // edges per chunk
#define SB ((ET + CH - 1) / CH)   // 416 edge chunks
#define GD ((NN + 63) / 64)       // dualgemm grid (782)

typedef _Float16 half8 __attribute__((ext_vector_type(8)));
typedef _Float16 hv2 __attribute__((ext_vector_type(2)));
typedef float floatx4 __attribute__((ext_vector_type(4)));

// ---------------- weight prep device fn ----------------

template <int K, int M2>
__device__ __forceinline__ void wprep_fn(int chunk, const float* __restrict__ Wl, const float* __restrict__ Wr,
                                         _Float16* __restrict__ Wfrag) {
    constexpr int MTOT = 2 * M2, NT = MTOT / 16;
    if (chunk >= MTOT * K / 8) return;
    int lane = chunk & 63, tt = chunk >> 6;
    int t = tt % NT, kt = tt / NT;
    int n = t * 16 + (lane & 15);
    int kb = kt * 32 + (lane >> 4) * 8;
    const float* src = (n < M2) ? (Wl + n) : (Wr + (n - M2));
    half8 h;
#pragma unroll
    for (int j = 0; j < 8; ++j) h[j] = (_Float16)src[(size_t)(kb + j) * M2];
    *(half8*)(Wfrag + (size_t)chunk * 8) = h;
}

// ---------------- fused prep: wprep (26) + bounds (196) + bhist (416) ----------------

__global__ __launch_bounds__(256) void k_prep(const float* __restrict__ Wl1, const float* __restrict__ Wr1,
                                              const float* __restrict__ Wl2, const float* __restrict__ Wr2,
                                              const float* __restrict__ Wl3, const float* __restrict__ Wr3,
                                              _Float16* __restrict__ Wf1, _Float16* __restrict__ Wf2,
                                              _Float16* __restrict__ Wf3,
                                              const int* __restrict__ batch, int* __restrict__ bpos,
                                              const int* __restrict__ ei, int* __restrict__ bcnt) {
    int b = blockIdx.x, t = threadIdx.x;
    if (b < 16) { wprep_fn<128, 128>(b * 256 + t, Wl1, Wr1, Wf1); return; }
    if (b < 24) { wprep_fn<128, 64>((b - 16) * 256 + t, Wl2, Wr2, Wf2); return; }
    if (b < 26) { wprep_fn<64, 32>((b - 24) * 256 + t, Wl3, Wr3, Wf3); return; }
    if (b < 26 + NBK) {
        int i = (b - 26) * 256 + t;
        if (i >= NN) return;
        int cur = batch[i];
        int prev = (i == 0) ? -1 : batch[i - 1];
        for (int g = prev + 1; g <= cur; ++g) bpos[g] = i;
        if (i == NN - 1)
            for (int g = cur + 1; g <= NG; ++g) bpos[g] = NN;
        return;
    }
    // bhist
    __shared__ int hist[NBK];
    int b0 = b - 26 - NBK;
    for (int i = t; i < NBK; i += 256) hist[i] = 0;
    __syncthreads();
#pragma unroll
    for (int pass = 0; pass < CH / 256; ++pass) {
        int e = b0 * CH + pass * 256 + t;
        if (e < ET) {
            int d = (e < NE) ? ei[NE + e] : (e - NE);
            atomicAdd(&hist[d >> 8], 1);
        }
    }
    __syncthreads();
    if (t < NBK) bcnt[t * SB + b0] = hist[t];
}

// ---------------- dualgemm body (device fn; A fp16 or fp32 w/ fused cast) ----------------

template <typename AT>
__device__ __forceinline__ half8 load_a8(const AT* __restrict__ ap) {
    if constexpr (__is_same(AT, _Float16)) {
        return *(const half8*)ap;
    } else {
        const float4* p = (const float4*)ap;
        float4 a = p[0], b = p[1];
        half8 h;
        h[0] = (_Float16)a.x; h[1] = (_Float16)a.y; h[2] = (_Float16)a.z; h[3] = (_Float16)a.w;
        h[4] = (_Float16)b.x; h[5] = (_Float16)b.y; h[6] = (_Float16)b.z; h[7] = (_Float16)b.w;
        return h;
    }
}

template <int K, int M2, typename AT>
__device__ __forceinline__ void dualgemm_body(int blk, int tid, const AT* __restrict__ Ain,
                                              const _Float16* __restrict__ Wfrag,
                                              __half* __restrict__ Ol, float* __restrict__ Or) {
    constexpr int MTOT = 2 * M2;
    constexpr int NT = MTOT / 16;
    constexpr int KT = K / 32;
    int wid = tid >> 6, lane = tid & 63;
    int q = lane >> 4, l15 = lane & 15;
    int r0 = blk * 64 + wid * 16;
    int arow = min(r0 + l15, NN - 1);
    const AT* ap = Ain + (size_t)arow * K + q * 8;

    floatx4 acc[NT];
#pragma unroll
    for (int t = 0; t < NT; ++t) acc[t] = (floatx4){0.f, 0.f, 0.f, 0.f};

#pragma unroll
    for (int kt = 0; kt < KT; ++kt) {
        half8 a8 = load_a8<AT>(ap + kt * 32);
        const _Float16* wp = Wfrag + ((size_t)(kt * NT) * 64 + lane) * 8;
#pragma unroll
        for (int t = 0; t < NT; ++t) {
            half8 b8 = *(const half8*)(wp + (size_t)t * 64 * 8);
            acc[t] = __builtin_amdgcn_mfma_f32_16x16x32_f16(a8, b8, acc[t], 0, 0, 0);
        }
    }

#pragma unroll
    for (int t = 0; t < NT; ++t) {
        int cn = t * 16 + l15;
#pragma unroll
        for (int reg = 0; reg < 4; ++reg) {
            int r = r0 + q * 4 + reg;
            if (r < NN) {
                if (cn < M2) Ol[(size_t)r * M2 + cn] = __float2half(acc[t][reg]);
                else         Or[(size_t)r * M2 + (cn - M2)] = acc[t][reg];
            }
        }
    }
}

template <int K, int M2, typename AT>
__global__ __launch_bounds__(256) void k_dualgemm(const AT* __restrict__ Ain,
                                                  const _Float16* __restrict__ Wfrag,
                                                  __half* __restrict__ Ol, float* __restrict__ Or) {
    dualgemm_body<K, M2, AT>(blockIdx.x, threadIdx.x, Ain, Wfrag, Ol, Or);
}

// ---------------- bscanA device fn: pair-scan of SB(416) chunk-counts per bucket ----------------

__device__ __forceinline__ void bscanA_fn(int b, int t, const int* __restrict__ bcnt,
                                          int* __restrict__ boff, int* __restrict__ tot) {
    __shared__ int lds[256];
    int i0 = 2 * t, i1 = 2 * t + 1;
    int v0 = (i0 < SB) ? bcnt[b * SB + i0] : 0;
    int v1 = (i1 < SB) ? bcnt[b * SB + i1] : 0;
    int pair = v0 + v1;
    lds[t] = pair;
    __syncthreads();
    for (int off = 1; off < 256; off <<= 1) {
        int y = (t >= off) ? lds[t - off] : 0;
        __syncthreads();
        lds[t] += y;
        __syncthreads();
    }
    int excl = lds[t] - pair;
    if (i0 < SB) boff[b * SB + i0] = excl;
    if (i1 < SB) boff[b * SB + i1] = excl + v0;
    if (t == 255) tot[b] = lds[255];
}

// ---- fused: dualgemm l1 (782 blocks) + bscanA (196 blocks) — both depend only on k_prep

__global__ __launch_bounds__(256) void k_gemm1_scan(const float* __restrict__ x, const _Float16* __restrict__ Wf1,
                                                    __half* __restrict__ Ol, float* __restrict__ Or,
                                                    const int* __restrict__ bcnt, int* __restrict__ boff,
                                                    int* __restrict__ tot) {
    if (blockIdx.x < GD) dualgemm_body<128, 128, float>(blockIdx.x, threadIdx.x, x, Wf1, Ol, Or);
    else                 bscanA_fn(blockIdx.x - GD, threadIdx.x, bcnt, boff, tot);
}

// ---------------- CSR: scatter into bucket-major ebuf (ebase derived locally from tot) ----------------
// ebuf entry: (src << 16) | (dst & 255)

__device__ __forceinline__ void edge_sd(int e, const int* __restrict__ ei, int& s, int& d) {
    if (e < NE) { s = ei[e]; d = ei[NE + e]; } else { s = e - NE; d = s; }
}

__global__ __launch_bounds__(256) void k_bscatter(const int* __restrict__ ei, const int* __restrict__ tot,
                                                  const int* __restrict__ boff, unsigned int* __restrict__ ebuf) {
    __shared__ int eb[256];
    __shared__ int cur[NBK];
    int b0 = blockIdx.x, t = threadIdx.x;
    int v = (t < NBK) ? tot[t] : 0;
    eb[t] = v;
    __syncthreads();
    for (int off = 1; off < 256; off <<= 1) {
        int y = (t >= off) ? eb[t - off] : 0;
        __syncthreads();
        eb[t] += y;
        __syncthreads();
    }
    if (t < NBK) cur[t] = (eb[t] - v) + boff[t * SB + b0];
    __syncthreads();
#pragma unroll
    for (int pass = 0; pass < CH / 256; ++pass) {
        int e = b0 * CH + pass * 256 + t;
        if (e < ET) {
            int s, d;
            edge_sd(e, ei, s, d);
            int pos = atomicAdd(&cur[d >> 8], 1);
            ebuf[pos] = ((unsigned)s << 16) | (unsigned)(d & 255);
        }
    }
}

// ---------------- CSR: per-bucket exact-dst counting sort -> rowptr + colsrc ----------------

__global__ __launch_bounds__(256) void k_bsort(const unsigned int* __restrict__ ebuf,
                                               const int* __restrict__ tot,
                                               int* __restrict__ rowptr, unsigned short* __restrict__ colsrc) {
    __shared__ int eb[256];
    __shared__ int sbase;
    __shared__ int cnt2[256];
    __shared__ int sc[256];
    __shared__ int cur2[256];
    int b = blockIdx.x, t = threadIdx.x;
    int v = (t < NBK) ? tot[t] : 0;
    eb[t] = v;
    __syncthreads();
    for (int off = 1; off < 256; off <<= 1) {
        int y = (t >= off) ? eb[t - off] : 0;
        __syncthreads();
        eb[t] += y;
        __syncthreads();
    }
    if (t == b) sbase = eb[t] - v;
    __syncthreads();
    int base = sbase, n = tot[b];
    cnt2[t] = 0;
    __syncthreads();
    for (int i = t; i < n; i += 256) atomicAdd(&cnt2[ebuf[base + i] & 255], 1);
    __syncthreads();
    int cv = cnt2[t];
    sc[t] = cv;
    __syncthreads();
    for (int off = 1; off < 256; off <<= 1) {
        int y = (t >= off) ? sc[t - off] : 0;
        __syncthreads();
        sc[t] += y;
        __syncthreads();
    }
    int excl = sc[t] - cv;
    int d = b * 256 + t;
    if (d < NN) rowptr[d] = base + excl;
    if (b == 0 && t == 0) rowptr[NN] = ET;
    cur2[t] = excl;
    __syncthreads();
    for (int i = t; i < n; i += 256) {
        unsigned u = ebuf[base + i];
        int pos = atomicAdd(&cur2[u & 255], 1);
        colsrc[base + pos] = (unsigned short)(u >> 16);
    }
}

// ---------------- GATv2 attention: channel-split (generic EP) + packed fp16 + no-max softmax ----------------
// l1 EP=2 (CP=16, 32B/lane/edge), l2 EP=2 (CP=8), l3 EP=1 (CP=8). All waves resident, no tail round.

template <int CP> struct HVec { hv2 h2[CP / 2]; };

template <int CP>
__device__ __forceinline__ HVec<CP> load_hv(const __half* __restrict__ p) {
    HVec<CP> r;
    if constexpr (CP == 16) {
        float4* rp = (float4*)&r;
        rp[0] = ((const float4*)p)[0];
        rp[1] = ((const float4*)p)[1];
    } else if constexpr (CP == 8) {
        float4 t = *(const float4*)p; r = *(HVec<CP>*)&t;
    } else if constexpr (CP == 4) {
        float2 t = *(const float2*)p; r = *(HVec<CP>*)&t;
    } else {
        r.h2[0] = *(const hv2*)p;
    }
    return r;
}

template <int C, int EP, bool CONCAT>
__global__ __launch_bounds__(256) void k_attn(const __half* __restrict__ xl, const float* __restrict__ xr,
                                              const int* __restrict__ rowptr,
                                              const unsigned short* __restrict__ colsrc,
                                              const float* __restrict__ att, const float* __restrict__ bias,
                                              float* __restrict__ out) {
    constexpr int CP = C / EP;
    constexpr int LEP = (EP == 4) ? 2 : ((EP == 2) ? 1 : 0);
    int t = blockIdx.x * 256 + threadIdx.x;
    int part = t & (EP - 1);
    int nh = t >> LEP;
    if (nh >= NN * H) return;
    int node = nh >> 2, h = nh & 3;           // H == 4
    int cbase = h * C + part * CP;
    hv2 xrr2[CP / 2], attv2[CP / 2];
    float acc[CP];
    {
        const float* p = xr + (size_t)node * (H * C) + cbase;
        const float* q = att + cbase;
#pragma unroll
        for (int j = 0; j < CP / 2; ++j) {
            xrr2[j] = (hv2){(_Float16)p[2 * j], (_Float16)p[2 * j + 1]};
            attv2[j] = (hv2){(_Float16)q[2 * j], (_Float16)q[2 * j + 1]};
        }
#pragma unroll
        for (int c = 0; c < CP; ++c) acc[c] = 0.f;
    }
    float denom = 0.f;
    int beg = rowptr[node], end = rowptr[node + 1];

    auto process = [&](const HVec<CP>& xv) {
        float part_s = 0.f;
#pragma unroll
        for (int j = 0; j < CP / 2; ++j) {
            hv2 z = xv.h2[j] + xrr2[j];
            hv2 l = __builtin_elementwise_max(z, z * (_Float16)0.2f);   // leaky_relu
            part_s = __builtin_amdgcn_fdot2(l, attv2[j], part_s, false);
        }
        float score = part_s;
#pragma unroll
        for (int mask = 1; mask < EP; mask <<= 1) score += __shfl_xor(score, mask, 64);
        float w = __expf(score);
        denom += w;
        const _Float16* xh = (const _Float16*)&xv;
#pragma unroll
        for (int c = 0; c < CP; ++c) acc[c] = fmaf(w, (float)xh[c], acc[c]);
    };

    int idx = beg;
    for (; idx + 4 <= end; idx += 4) {
        int s0 = colsrc[idx], s1 = colsrc[idx + 1], s2 = colsrc[idx + 2], s3 = colsrc[idx + 3];
        HVec<CP> xv0 = load_hv<CP>(xl + (size_t)s0 * (H * C) + cbase);
        HVec<CP> xv1 = load_hv<CP>(xl + (size_t)s1 * (H * C) + cbase);
        HVec<CP> xv2 = load_hv<CP>(xl + (size_t)s2 * (H * C) + cbase);
        HVec<CP> xv3 = load_hv<CP>(xl + (size_t)s3 * (H * C) + cbase);
        process(xv0);
        process(xv1);
        process(xv2);
        process(xv3);
    }
    for (; idx < end; ++idx) {
        int s = colsrc[idx];
        HVec<CP> xv = load_hv<CP>(xl + (size_t)s * (H * C) + cbase);
        process(xv);
    }

    float inv = 1.f / denom;
    float* op = out + (size_t)node * (H * C) + cbase;
    float v[CP];
#pragma unroll
    for (int c = 0; c < CP; ++c) {
        v[c] = acc[c] * inv;
        if (CONCAT) v[c] += bias[cbase + c];
    }
    if constexpr (CP == 16) {
#pragma unroll
        for (int j = 0; j < 4; ++j)
            *(float4*)(op + 4 * j) = make_float4(v[4 * j], v[4 * j + 1], v[4 * j + 2], v[4 * j + 3]);
    } else if constexpr (CP == 8) {
        *(float4*)(op) = make_float4(v[0], v[1], v[2], v[3]);
        *(float4*)(op + 4) = make_float4(v[4], v[5], v[6], v[7]);
    } else if constexpr (CP == 4) {
        *(float4*)(op) = make_float4(v[0], v[1], v[2], v[3]);
    } else {
        *(float2*)(op) = make_float2(v[0], v[1]);
    }
}

// ---------------- GraphNorm reduce: one block per (graph, segment), LDS tree, C*2 atomics/block ----------------

template <int LOGC, int SPLIT>
__global__ __launch_bounds__(256) void k_gnred2(const float* __restrict__ h, const int* __restrict__ bpos,
                                                float* __restrict__ sum, float* __restrict__ sumsq) {
    constexpr int C = 1 << LOGC;
    constexpr int RG = 256 >> LOGC;      // row-groups per block
    int g = blockIdx.x / SPLIT, s = blockIdx.x % SPLIT;
    int c = threadIdx.x & (C - 1);
    int rg = threadIdx.x >> LOGC;
    int b0 = bpos[g], b1 = bpos[g + 1];
    int n = b1 - b0;
    int seg = (n + SPLIT - 1) / SPLIT;
    int r0 = b0 + s * seg;
    int r1 = min(r0 + seg, b1);
    float sv = 0.f, ssv = 0.f;
    for (int r = r0 + rg; r < r1; r += RG) {
        float x = h[(size_t)r * C + c];
        sv += x; ssv += x * x;
    }
    __shared__ float ls[256], lss[256];
    ls[threadIdx.x] = sv; lss[threadIdx.x] = ssv;
    __syncthreads();
    for (int off = 128; off >= C; off >>= 1) {
        if (threadIdx.x < off) {
            ls[threadIdx.x] += ls[threadIdx.x + off];
            lss[threadIdx.x] += lss[threadIdx.x + off];
        }
        __syncthreads();
    }
    if (threadIdx.x < C) {
        atomicAdd(&sum[g * C + threadIdx.x], ls[threadIdx.x]);
        atomicAdd(&sumsq[g * C + threadIdx.x], lss[threadIdx.x]);
    }
}

// var(out) = E[x^2] - (2s - s^2) mu^2  where out = x - mu*s.
// Writes ONLY the fp16 copy when h16 != null (fp32 h is dead downstream then).
__global__ __launch_bounds__(256) void k_gnnorm(float* __restrict__ h, const int* __restrict__ batch,
                                                const float* __restrict__ sum, const float* __restrict__ sumsq,
                                                const int* __restrict__ bpos, const float* __restrict__ w,
                                                const float* __restrict__ b, const float* __restrict__ ms,
                                                int logC, __half* __restrict__ h16) {
    int C = 1 << logC;
    int i = blockIdx.x * 256 + threadIdx.x;
    if (i >= NN * C) return;
    int nd = i >> logC, c = i & (C - 1);
    int g = batch[nd];
    float cg = fmaxf((float)(bpos[g + 1] - bpos[g]), 1.f);
    float mu = sum[g * C + c] / cg;
    float ex2 = sumsq[g * C + c] / cg;
    float s_ = ms[c];
    float var = ex2 - (2.f * s_ - s_ * s_) * mu * mu;
    float y = (h[i] - mu * s_) * rsqrtf(var + 1e-5f) * w[c] + b[c];
    y = fmaxf(y, 0.f);   // fused ReLU
    if (h16) h16[i] = __float2half(y);
    else     h[i] = y;
}

// ---------------- fused layer-3 tail ----------------

template <int SPLIT>
__global__ __launch_bounds__(256) void k_headgn(const float* __restrict__ tmp, const float* __restrict__ b3,
                                                const int* __restrict__ bpos, float* __restrict__ Af,
                                                float* __restrict__ sum, float* __restrict__ sumsq) {
    constexpr int C = 8, RG = 32;
    int g = blockIdx.x / SPLIT, s = blockIdx.x % SPLIT;
    int c = threadIdx.x & 7;
    int rg = threadIdx.x >> 3;
    int b0 = bpos[g], b1 = bpos[g + 1];
    int n = b1 - b0;
    int seg = (n + SPLIT - 1) / SPLIT;
    int r0 = b0 + s * seg;
    int r1 = min(r0 + seg, b1);
    float bias = b3[c];
    float sv = 0.f, ssv = 0.f;
    for (int r = r0 + rg; r < r1; r += RG) {
        const float* p = tmp + (size_t)r * 32 + c;
        float v = 0.25f * (p[0] + p[8] + p[16] + p[24]) + bias;
        Af[(size_t)r * C + c] = v;
        sv += v; ssv += v * v;
    }
    __shared__ float ls[256], lss[256];
    ls[threadIdx.x] = sv; lss[threadIdx.x] = ssv;
    __syncthreads();
    for (int off = 128; off >= C; off >>= 1) {
        if (threadIdx.x < off) {
            ls[threadIdx.x] += ls[threadIdx.x + off];
            lss[threadIdx.x] += lss[threadIdx.x + off];
        }
        __syncthreads();
    }
    if (threadIdx.x < C) {
        atomicAdd(&sum[g * C + threadIdx.x], ls[threadIdx.x]);
        atomicAdd(&sumsq[g * C + threadIdx.x], lss[threadIdx.x]);
    }
}

template <int SPLIT>
__global__ __launch_bounds__(256) void k_gnpool(const float* __restrict__ Af, const int* __restrict__ bpos,
                                                const float* __restrict__ sum, const float* __restrict__ sumsq,
                                                const float* __restrict__ w,
                                                const float* __restrict__ b, const float* __restrict__ ms,
                                                float* __restrict__ pool) {
    constexpr int C = 8, RG = 32;
    int g = blockIdx.x / SPLIT, s = blockIdx.x % SPLIT;
    int c = threadIdx.x & 7;
    int rg = threadIdx.x >> 3;
    int b0 = bpos[g], b1 = bpos[g + 1];
    int n = b1 - b0;
    int seg = (n + SPLIT - 1) / SPLIT;
    int r0 = b0 + s * seg;
    int r1 = min(r0 + seg, b1);
    float cg = fmaxf((float)n, 1.f);
    float mu = sum[g * C + c] / cg;
    float ex2 = sumsq[g * C + c] / cg;
    float s_ = ms[c];
    float var = ex2 - (2.f * s_ - s_ * s_) * mu * mu;
    float rs = rsqrtf(var + 1e-5f) * w[c];
    float bb = b[c], mus = mu * s_;
    float pv = 0.f;
    for (int r = r0 + rg; r < r1; r += RG) {
        float y = fmaxf((Af[(size_t)r * C + c] - mus) * rs + bb, 0.f);
        pv += y;
    }
    __shared__ float ls[256];
    ls[threadIdx.x] = pv;
    __syncthreads();
    for (int off = 128; off >= C; off >>= 1) {
        if (threadIdx.x < off) ls[threadIdx.x] += ls[threadIdx.x + off];
        __syncthreads();
    }
    if (threadIdx.x < C) atomicAdd(&pool[g * C + threadIdx.x], ls[threadIdx.x]);
}

// ---------------- pool mean + linear head ----------------

__global__ __launch_bounds__(512) void k_final(const float* __restrict__ pool, const int* __restrict__ bpos,
                                               const float* __restrict__ lw, const float* __restrict__ lb,
                                               float* __restrict__ outp) {
    __shared__ float feat[512];
    int t = threadIdx.x;
    int g = t >> 3;
    float f = pool[t] / fmaxf((float)(bpos[g + 1] - bpos[g]), 1.f);
    feat[t] = f;
    outp[256 + t] = f;          // features: d_out[256 .. 768)
    __syncthreads();
    if (t < 256) {
        int g2 = t >> 2, o = t & 3;
        float a = lb[o];
#pragma unroll
        for (int cc = 0; cc < 8; ++cc) a += feat[g2 * 8 + cc] * lw[cc * 4 + o];
        outp[t] = a;            // logits: d_out[0 .. 256)
    }
}

// ---------------- host ----------------

extern "C" void kernel_launch(void* const* d_in, const int* in_sizes, int n_in,
                              void* d_out, int out_size, void* d_ws, size_t ws_size,
                              hipStream_t stream) {
    const float* x    = (const float*)d_in[0];
    const int*   ei   = (const int*)d_in[1];
    const int*   batch= (const int*)d_in[2];
    const float *w_l1 = (const float*)d_in[3],  *w_r1 = (const float*)d_in[4];
    const float *att1 = (const float*)d_in[5],  *b1   = (const float*)d_in[6];
    const float *gn1w = (const float*)d_in[7],  *gn1b = (const float*)d_in[8],  *gn1s = (const float*)d_in[9];
    const float *w_l2 = (const float*)d_in[10], *w_r2 = (const float*)d_in[11];
    const float *att2 = (const float*)d_in[12], *b2   = (const float*)d_in[13];
    const float *gn2w = (const float*)d_in[14], *gn2b = (const float*)d_in[15], *gn2s = (const float*)d_in[16];
    const float *w_l3 = (const float*)d_in[17], *w_r3 = (const float*)d_in[18];
    const float *att3 = (const float*)d_in[19], *b3   = (const float*)d_in[20];
    const float *gn3w = (const float*)d_in[21], *gn3b = (const float*)d_in[22], *gn3s = (const float*)d_in[23];
    const float *lw   = (const float*)d_in[24], *lb   = (const float*)d_in[25];

    char* ws = (char*)d_ws;
    size_t off = 0;
    auto alloc = [&](size_t bytes) -> void* {
        void* p = ws + off;
        off += (bytes + 255) & ~(size_t)255;
        return p;
    };
    __half* Ah  = (__half*)alloc((size_t)NN * 128 * 2);  // x_l fp16 (GEMM out, attn gather operand)
    __half* Xh  = (__half*)alloc((size_t)NN * 128 * 2);  // fp16 layer activations (gnnorm out)
    float*  B   = (float*)alloc((size_t)NN * 128 * 4);   // x_r / layer-out scratch
    float*  Cb  = (float*)alloc((size_t)NN * 64 * 4);    // h2 scratch
    float*  Af  = (float*)alloc((size_t)NN * 8 * 4);     // layer-3 head-mean features
    _Float16* Wf1 = (_Float16*)alloc((size_t)256 * 128 * 2);  // frag-ordered weights l1
    _Float16* Wf2 = (_Float16*)alloc((size_t)128 * 128 * 2);  // l2
    _Float16* Wf3 = (_Float16*)alloc((size_t)64 * 64 * 2);    // l3
    int* rowptr = (int*)alloc((size_t)(NN + 1) * 4);
    unsigned short* colsrc = (unsigned short*)alloc((size_t)ET * 2);
    unsigned int* ebuf = (unsigned int*)alloc((size_t)ET * 4);
    int* bcnt   = (int*)alloc((size_t)NBK * SB * 4);
    int* boff   = (int*)alloc((size_t)NBK * SB * 4);
    int* tot    = (int*)alloc((size_t)NBK * 4);
    int* bpos   = (int*)alloc((size_t)(NG + 1) * 4);
    char* zbase = ws + off;                              // everything below gets one memset
    float* sum1 = (float*)alloc((size_t)NG * 128 * 4);
    float* sq1  = (float*)alloc((size_t)NG * 128 * 4);
    float* sum2 = (float*)alloc((size_t)NG * 64 * 4);
    float* sq2  = (float*)alloc((size_t)NG * 64 * 4);
    float* sum3 = (float*)alloc((size_t)NG * 8 * 4);
    float* sq3  = (float*)alloc((size_t)NG * 8 * 4);
    float* pool = (float*)alloc((size_t)NG * 8 * 4);
    size_t zbytes = (size_t)((ws + off) - zbase);
    (void)hipMemsetAsync(zbase, 0, zbytes, stream);

    k_prep<<<26 + NBK + SB, 256, 0, stream>>>(w_l1, w_r1, w_l2, w_r2, w_l3, w_r3, Wf1, Wf2, Wf3,
                                              batch, bpos, ei, bcnt);
    // dualgemm l1 + bscanA fused (both depend only on k_prep)
    k_gemm1_scan<<<GD + NBK, 256, 0, stream>>>(x, Wf1, Ah, B, bcnt, boff, tot);
    k_bscatter<<<SB, 256, 0, stream>>>(ei, tot, boff, ebuf);
    k_bsort<<<NBK, 256, 0, stream>>>(ebuf, tot, rowptr, colsrc);

    int gA1 = (NN * H * 2 + 255) / 256;           // l1: EP=2
    int gA2 = (NN * H * 2 + 255) / 256;           // l2: EP=2
    int gA3 = (NN * H + 255) / 256;               // l3: EP=1

    // ---- layer 1: 128 -> 4x32 concat -> 128
    k_attn<32, 2, true><<<gA1, 256, 0, stream>>>(Ah, B, rowptr, colsrc, att1, b1, B);
    k_gnred2<7, 8><<<NG * 8, 256, 0, stream>>>(B, bpos, sum1, sq1);
    k_gnnorm<<<(NN * 128 + 255) / 256, 256, 0, stream>>>(B, batch, sum1, sq1, bpos, gn1w, gn1b, gn1s, 7, Xh);

    // ---- layer 2: 128 -> 4x16 concat -> 64
    k_dualgemm<128, 64, _Float16><<<GD, 256, 0, stream>>>((const _Float16*)Xh, Wf2, Ah, Cb);
    k_attn<16, 2, true><<<gA2, 256, 0, stream>>>(Ah, Cb, rowptr, colsrc, att2, b2, Cb);
    k_gnred2<6, 8><<<NG * 8, 256, 0, stream>>>(Cb, bpos, sum2, sq2);
    k_gnnorm<<<(NN * 64 + 255) / 256, 256, 0, stream>>>(Cb, batch, sum2, sq2, bpos, gn2w, gn2b, gn2s, 6, Xh);

    // ---- layer 3: 64 -> 4x8 mean -> 8, fused tail
    k_dualgemm<64, 32, _Float16><<<GD, 256, 0, stream>>>((const _Float16*)Xh, Wf3, Ah, B);
    k_attn<8, 1, false><<<gA3, 256, 0, stream>>>(Ah, B, rowptr, colsrc, att3, nullptr, B);
    k_headgn<8><<<NG * 8, 256, 0, stream>>>(B, b3, bpos, Af, sum3, sq3);
    k_gnpool<8><<<NG * 8, 256, 0, stream>>>(Af, bpos, sum3, sq3, gn3w, gn3b, gn3s, pool);
    k_final<<<1, 512, 0, stream>>>(pool, bpos, lw, lb, (float*)d_out);
}

// Round 17
// 318.197 us; speedup vs baseline: 1.5937x; 1.0164x over previous
//
#include <hip/hip_runtime.h>
#include <hip/hip_fp16.h>
#include <math.h>

#define NN 50000
#define NE 800000
#define ET (NE + NN)
#define NG 64
#define H 4
#define NBK 196                   // dst buckets (dst >> 8)
#define CH 2048                   // edges per chunk
#define SB ((ET + CH - 1) / CH)   // 416 edge chunks
#define GD ((NN + 63) / 64)       // dualgemm grid (782)

typedef _Float16 half8 __attribute__((ext_vector_type(8)));
typedef _Float16 half4 __attribute__((ext_vector_type(4)));
typedef _Float16 hv2 __attribute__((ext_vector_type(2)));
typedef float floatx4 __attribute__((ext_vector_type(4)));

// ---------------- weight prep device fn ----------------

template <int K, int M2>
__device__ __forceinline__ void wprep_fn(int chunk, const float* __restrict__ Wl, const float* __restrict__ Wr,
                                         _Float16* __restrict__ Wfrag) {
    constexpr int MTOT = 2 * M2, NT = MTOT / 16;
    if (chunk >= MTOT * K / 8) return;
    int lane = chunk & 63, tt = chunk >> 6;
    int t = tt % NT, kt = tt / NT;
    int n = t * 16 + (lane & 15);
    int kb = kt * 32 + (lane >> 4) * 8;
    const float* src = (n < M2) ? (Wl + n) : (Wr + (n - M2));
    half8 h;
#pragma unroll
    for (int j = 0; j < 8; ++j) h[j] = (_Float16)src[(size_t)(kb + j) * M2];
    *(half8*)(Wfrag + (size_t)chunk * 8) = h;
}

// ---------------- fused prep: wprep (26) + bounds (196) + bhist (416) ----------------

__global__ __launch_bounds__(256) void k_prep(const float* __restrict__ Wl1, const float* __restrict__ Wr1,
                                              const float* __restrict__ Wl2, const float* __restrict__ Wr2,
                                              const float* __restrict__ Wl3, const float* __restrict__ Wr3,
                                              _Float16* __restrict__ Wf1, _Float16* __restrict__ Wf2,
                                              _Float16* __restrict__ Wf3,
                                              const int* __restrict__ batch, int* __restrict__ bpos,
                                              const int* __restrict__ ei, int* __restrict__ bcnt) {
    int b = blockIdx.x, t = threadIdx.x;
    if (b < 16) { wprep_fn<128, 128>(b * 256 + t, Wl1, Wr1, Wf1); return; }
    if (b < 24) { wprep_fn<128, 64>((b - 16) * 256 + t, Wl2, Wr2, Wf2); return; }
    if (b < 26) { wprep_fn<64, 32>((b - 24) * 256 + t, Wl3, Wr3, Wf3); return; }
    if (b < 26 + NBK) {
        int i = (b - 26) * 256 + t;
        if (i >= NN) return;
        int cur = batch[i];
        int prev = (i == 0) ? -1 : batch[i - 1];
        for (int g = prev + 1; g <= cur; ++g) bpos[g] = i;
        if (i == NN - 1)
            for (int g = cur + 1; g <= NG; ++g) bpos[g] = NN;
        return;
    }
    // bhist
    __shared__ int hist[NBK];
    int b0 = b - 26 - NBK;
    for (int i = t; i < NBK; i += 256) hist[i] = 0;
    __syncthreads();
#pragma unroll
    for (int pass = 0; pass < CH / 256; ++pass) {
        int e = b0 * CH + pass * 256 + t;
        if (e < ET) {
            int d = (e < NE) ? ei[NE + e] : (e - NE);
            atomicAdd(&hist[d >> 8], 1);
        }
    }
    __syncthreads();
    if (t < NBK) bcnt[t * SB + b0] = hist[t];
}

// ---------------- dualgemm body (device fn; A fp16 or fp32 w/ fused cast) ----------------

template <typename AT>
__device__ __forceinline__ half8 load_a8(const AT* __restrict__ ap) {
    if constexpr (__is_same(AT, _Float16)) {
        return *(const half8*)ap;
    } else {
        const float4* p = (const float4*)ap;
        float4 a = p[0], b = p[1];
        half8 h;
        h[0] = (_Float16)a.x; h[1] = (_Float16)a.y; h[2] = (_Float16)a.z; h[3] = (_Float16)a.w;
        h[4] = (_Float16)b.x; h[5] = (_Float16)b.y; h[6] = (_Float16)b.z; h[7] = (_Float16)b.w;
        return h;
    }
}

template <int K, int M2, typename AT>
__device__ __forceinline__ void dualgemm_body(int blk, int tid, const AT* __restrict__ Ain,
                                              const _Float16* __restrict__ Wfrag,
                                              __half* __restrict__ Ol, float* __restrict__ Or) {
    constexpr int MTOT = 2 * M2;
    constexpr int NT = MTOT / 16;
    constexpr int KT = K / 32;
    int wid = tid >> 6, lane = tid & 63;
    int q = lane >> 4, l15 = lane & 15;
    int r0 = blk * 64 + wid * 16;
    int arow = min(r0 + l15, NN - 1);
    const AT* ap = Ain + (size_t)arow * K + q * 8;

    floatx4 acc[NT];
#pragma unroll
    for (int t = 0; t < NT; ++t) acc[t] = (floatx4){0.f, 0.f, 0.f, 0.f};

#pragma unroll
    for (int kt = 0; kt < KT; ++kt) {
        half8 a8 = load_a8<AT>(ap + kt * 32);
        const _Float16* wp = Wfrag + ((size_t)(kt * NT) * 64 + lane) * 8;
#pragma unroll
        for (int t = 0; t < NT; ++t) {
            half8 b8 = *(const half8*)(wp + (size_t)t * 64 * 8);
            acc[t] = __builtin_amdgcn_mfma_f32_16x16x32_f16(a8, b8, acc[t], 0, 0, 0);
        }
    }

#pragma unroll
    for (int t = 0; t < NT; ++t) {
        int cn = t * 16 + l15;
#pragma unroll
        for (int reg = 0; reg < 4; ++reg) {
            int r = r0 + q * 4 + reg;
            if (r < NN) {
                if (cn < M2) Ol[(size_t)r * M2 + cn] = __float2half(acc[t][reg]);
                else         Or[(size_t)r * M2 + (cn - M2)] = acc[t][reg];
            }
        }
    }
}

template <int K, int M2, typename AT>
__global__ __launch_bounds__(256) void k_dualgemm(const AT* __restrict__ Ain,
                                                  const _Float16* __restrict__ Wfrag,
                                                  __half* __restrict__ Ol, float* __restrict__ Or) {
    dualgemm_body<K, M2, AT>(blockIdx.x, threadIdx.x, Ain, Wfrag, Ol, Or);
}

// ---------------- bscanA device fn: pair-scan of SB(416) chunk-counts per bucket ----------------

__device__ __forceinline__ void bscanA_fn(int b, int t, const int* __restrict__ bcnt,
                                          int* __restrict__ boff, int* __restrict__ tot) {
    __shared__ int lds[256];
    int i0 = 2 * t, i1 = 2 * t + 1;
    int v0 = (i0 < SB) ? bcnt[b * SB + i0] : 0;
    int v1 = (i1 < SB) ? bcnt[b * SB + i1] : 0;
    int pair = v0 + v1;
    lds[t] = pair;
    __syncthreads();
    for (int off = 1; off < 256; off <<= 1) {
        int y = (t >= off) ? lds[t - off] : 0;
        __syncthreads();
        lds[t] += y;
        __syncthreads();
    }
    int excl = lds[t] - pair;
    if (i0 < SB) boff[b * SB + i0] = excl;
    if (i1 < SB) boff[b * SB + i1] = excl + v0;
    if (t == 255) tot[b] = lds[255];
}

// ---- fused: dualgemm l1 (782 blocks) + bscanA (196 blocks)

__global__ __launch_bounds__(256) void k_gemm1_scan(const float* __restrict__ x, const _Float16* __restrict__ Wf1,
                                                    __half* __restrict__ Ol, float* __restrict__ Or,
                                                    const int* __restrict__ bcnt, int* __restrict__ boff,
                                                    int* __restrict__ tot) {
    if (blockIdx.x < GD) dualgemm_body<128, 128, float>(blockIdx.x, threadIdx.x, x, Wf1, Ol, Or);
    else                 bscanA_fn(blockIdx.x - GD, threadIdx.x, bcnt, boff, tot);
}

// ---------------- CSR: scatter into bucket-major ebuf ----------------

__device__ __forceinline__ void edge_sd(int e, const int* __restrict__ ei, int& s, int& d) {
    if (e < NE) { s = ei[e]; d = ei[NE + e]; } else { s = e - NE; d = s; }
}

__global__ __launch_bounds__(256) void k_bscatter(const int* __restrict__ ei, const int* __restrict__ tot,
                                                  const int* __restrict__ boff, unsigned int* __restrict__ ebuf) {
    __shared__ int eb[256];
    __shared__ int cur[NBK];
    int b0 = blockIdx.x, t = threadIdx.x;
    int v = (t < NBK) ? tot[t] : 0;
    eb[t] = v;
    __syncthreads();
    for (int off = 1; off < 256; off <<= 1) {
        int y = (t >= off) ? eb[t - off] : 0;
        __syncthreads();
        eb[t] += y;
        __syncthreads();
    }
    if (t < NBK) cur[t] = (eb[t] - v) + boff[t * SB + b0];
    __syncthreads();
#pragma unroll
    for (int pass = 0; pass < CH / 256; ++pass) {
        int e = b0 * CH + pass * 256 + t;
        if (e < ET) {
            int s, d;
            edge_sd(e, ei, s, d);
            int pos = atomicAdd(&cur[d >> 8], 1);
            ebuf[pos] = ((unsigned)s << 16) | (unsigned)(d & 255);
        }
    }
}

// ---------------- CSR: per-bucket exact-dst counting sort -> rowptr + colsrc ----------------

__global__ __launch_bounds__(256) void k_bsort(const unsigned int* __restrict__ ebuf,
                                               const int* __restrict__ tot,
                                               int* __restrict__ rowptr, unsigned short* __restrict__ colsrc) {
    __shared__ int eb[256];
    __shared__ int sbase;
    __shared__ int cnt2[256];
    __shared__ int sc[256];
    __shared__ int cur2[256];
    int b = blockIdx.x, t = threadIdx.x;
    int v = (t < NBK) ? tot[t] : 0;
    eb[t] = v;
    __syncthreads();
    for (int off = 1; off < 256; off <<= 1) {
        int y = (t >= off) ? eb[t - off] : 0;
        __syncthreads();
        eb[t] += y;
        __syncthreads();
    }
    if (t == b) sbase = eb[t] - v;
    __syncthreads();
    int base = sbase, n = tot[b];
    cnt2[t] = 0;
    __syncthreads();
    for (int i = t; i < n; i += 256) atomicAdd(&cnt2[ebuf[base + i] & 255], 1);
    __syncthreads();
    int cv = cnt2[t];
    sc[t] = cv;
    __syncthreads();
    for (int off = 1; off < 256; off <<= 1) {
        int y = (t >= off) ? sc[t - off] : 0;
        __syncthreads();
        sc[t] += y;
        __syncthreads();
    }
    int excl = sc[t] - cv;
    int d = b * 256 + t;
    if (d < NN) rowptr[d] = base + excl;
    if (b == 0 && t == 0) rowptr[NN] = ET;
    cur2[t] = excl;
    __syncthreads();
    for (int i = t; i < n; i += 256) {
        unsigned u = ebuf[base + i];
        int pos = atomicAdd(&cur2[u & 255], 1);
        colsrc[base + pos] = (unsigned short)(u >> 16);
    }
}

// ---------------- GATv2 attention: channel-split + packed fp16 + no-max softmax, fp16 OUTPUT ----------------

template <int CP> struct HVec { hv2 h2[CP / 2]; };

template <int CP>
__device__ __forceinline__ HVec<CP> load_hv(const __half* __restrict__ p) {
    HVec<CP> r;
    if constexpr (CP == 16) {
        float4* rp = (float4*)&r;
        rp[0] = ((const float4*)p)[0];
        rp[1] = ((const float4*)p)[1];
    } else if constexpr (CP == 8) {
        float4 t = *(const float4*)p; r = *(HVec<CP>*)&t;
    } else if constexpr (CP == 4) {
        float2 t = *(const float2*)p; r = *(HVec<CP>*)&t;
    } else {
        r.h2[0] = *(const hv2*)p;
    }
    return r;
}

template <int C, int EP, bool CONCAT>
__global__ __launch_bounds__(256) void k_attn(const __half* __restrict__ xl, const float* __restrict__ xr,
                                              const int* __restrict__ rowptr,
                                              const unsigned short* __restrict__ colsrc,
                                              const float* __restrict__ att, const float* __restrict__ bias,
                                              __half* __restrict__ out) {
    constexpr int CP = C / EP;
    constexpr int LEP = (EP == 4) ? 2 : ((EP == 2) ? 1 : 0);
    int t = blockIdx.x * 256 + threadIdx.x;
    int part = t & (EP - 1);
    int nh = t >> LEP;
    if (nh >= NN * H) return;
    int node = nh >> 2, h = nh & 3;           // H == 4
    int cbase = h * C + part * CP;
    hv2 xrr2[CP / 2], attv2[CP / 2];
    float acc[CP];
    {
        const float* p = xr + (size_t)node * (H * C) + cbase;
        const float* q = att + cbase;
#pragma unroll
        for (int j = 0; j < CP / 2; ++j) {
            xrr2[j] = (hv2){(_Float16)p[2 * j], (_Float16)p[2 * j + 1]};
            attv2[j] = (hv2){(_Float16)q[2 * j], (_Float16)q[2 * j + 1]};
        }
#pragma unroll
        for (int c = 0; c < CP; ++c) acc[c] = 0.f;
    }
    float denom = 0.f;
    int beg = rowptr[node], end = rowptr[node + 1];

    auto process = [&](const HVec<CP>& xv) {
        float part_s = 0.f;
#pragma unroll
        for (int j = 0; j < CP / 2; ++j) {
            hv2 z = xv.h2[j] + xrr2[j];
            hv2 l = __builtin_elementwise_max(z, z * (_Float16)0.2f);   // leaky_relu
            part_s = __builtin_amdgcn_fdot2(l, attv2[j], part_s, false);
        }
        float score = part_s;
#pragma unroll
        for (int mask = 1; mask < EP; mask <<= 1) score += __shfl_xor(score, mask, 64);
        float w = __expf(score);
        denom += w;
        const _Float16* xh = (const _Float16*)&xv;
#pragma unroll
        for (int c = 0; c < CP; ++c) acc[c] = fmaf(w, (float)xh[c], acc[c]);
    };

    int idx = beg;
    for (; idx + 4 <= end; idx += 4) {
        int s0 = colsrc[idx], s1 = colsrc[idx + 1], s2 = colsrc[idx + 2], s3 = colsrc[idx + 3];
        HVec<CP> xv0 = load_hv<CP>(xl + (size_t)s0 * (H * C) + cbase);
        HVec<CP> xv1 = load_hv<CP>(xl + (size_t)s1 * (H * C) + cbase);
        HVec<CP> xv2 = load_hv<CP>(xl + (size_t)s2 * (H * C) + cbase);
        HVec<CP> xv3 = load_hv<CP>(xl + (size_t)s3 * (H * C) + cbase);
        process(xv0);
        process(xv1);
        process(xv2);
        process(xv3);
    }
    for (; idx < end; ++idx) {
        int s = colsrc[idx];
        HVec<CP> xv = load_hv<CP>(xl + (size_t)s * (H * C) + cbase);
        process(xv);
    }

    float inv = 1.f / denom;
    _Float16* op = (_Float16*)out + (size_t)node * (H * C) + cbase;
    _Float16 hv[CP];
#pragma unroll
    for (int c = 0; c < CP; ++c) {
        float v = acc[c] * inv;
        if (CONCAT) v += bias[cbase + c];
        hv[c] = (_Float16)v;
    }
    if constexpr (CP >= 8) {
#pragma unroll
        for (int j = 0; j < CP / 8; ++j) *(half8*)(op + 8 * j) = *(half8*)(hv + 8 * j);
    } else if constexpr (CP == 4) {
        *(half4*)op = *(half4*)hv;
    } else {
        *(hv2*)op = *(hv2*)hv;
    }
}

// ---------------- GraphNorm reduce (fp16 input): one block per (graph, segment) ----------------

template <int LOGC, int SPLIT>
__global__ __launch_bounds__(256) void k_gnred2(const __half* __restrict__ h, const int* __restrict__ bpos,
                                                float* __restrict__ sum, float* __restrict__ sumsq) {
    constexpr int C = 1 << LOGC;
    constexpr int RG = 256 >> LOGC;      // row-groups per block
    int g = blockIdx.x / SPLIT, s = blockIdx.x % SPLIT;
    int c = threadIdx.x & (C - 1);
    int rg = threadIdx.x >> LOGC;
    int b0 = bpos[g], b1 = bpos[g + 1];
    int n = b1 - b0;
    int seg = (n + SPLIT - 1) / SPLIT;
    int r0 = b0 + s * seg;
    int r1 = min(r0 + seg, b1);
    float sv = 0.f, ssv = 0.f;
    for (int r = r0 + rg; r < r1; r += RG) {
        float x = __half2float(h[(size_t)r * C + c]);
        sv += x; ssv += x * x;
    }
    __shared__ float ls[256], lss[256];
    ls[threadIdx.x] = sv; lss[threadIdx.x] = ssv;
    __syncthreads();
    for (int off = 128; off >= C; off >>= 1) {
        if (threadIdx.x < off) {
            ls[threadIdx.x] += ls[threadIdx.x + off];
            lss[threadIdx.x] += lss[threadIdx.x + off];
        }
        __syncthreads();
    }
    if (threadIdx.x < C) {
        atomicAdd(&sum[g * C + threadIdx.x], ls[threadIdx.x]);
        atomicAdd(&sumsq[g * C + threadIdx.x], lss[threadIdx.x]);
    }
}

// var(out) = E[x^2] - (2s - s^2) mu^2; fp16 in -> fp16 out (+ReLU)
__global__ __launch_bounds__(256) void k_gnnorm(const __half* __restrict__ hin, const int* __restrict__ batch,
                                                const float* __restrict__ sum, const float* __restrict__ sumsq,
                                                const int* __restrict__ bpos, const float* __restrict__ w,
                                                const float* __restrict__ b, const float* __restrict__ ms,
                                                int logC, __half* __restrict__ hout) {
    int C = 1 << logC;
    int i = blockIdx.x * 256 + threadIdx.x;
    if (i >= NN * C) return;
    int nd = i >> logC, c = i & (C - 1);
    int g = batch[nd];
    float cg = fmaxf((float)(bpos[g + 1] - bpos[g]), 1.f);
    float mu = sum[g * C + c] / cg;
    float ex2 = sumsq[g * C + c] / cg;
    float s_ = ms[c];
    float var = ex2 - (2.f * s_ - s_ * s_) * mu * mu;
    float y = (__half2float(hin[i]) - mu * s_) * rsqrtf(var + 1e-5f) * w[c] + b[c];
    hout[i] = __float2half(fmaxf(y, 0.f));
}

// ---------------- fused layer-3 tail ----------------
// k_headgn: headmean+bias (from fp16 32-ch attn out) fused with GN sum/sumsq reduction; writes Af.

template <int SPLIT>
__global__ __launch_bounds__(256) void k_headgn(const __half* __restrict__ tmp, const float* __restrict__ b3,
                                                const int* __restrict__ bpos, float* __restrict__ Af,
                                                float* __restrict__ sum, float* __restrict__ sumsq) {
    constexpr int C = 8, RG = 32;
    int g = blockIdx.x / SPLIT, s = blockIdx.x % SPLIT;
    int c = threadIdx.x & 7;
    int rg = threadIdx.x >> 3;
    int b0 = bpos[g], b1 = bpos[g + 1];
    int n = b1 - b0;
    int seg = (n + SPLIT - 1) / SPLIT;
    int r0 = b0 + s * seg;
    int r1 = min(r0 + seg, b1);
    float bias = b3[c];
    float sv = 0.f, ssv = 0.f;
    for (int r = r0 + rg; r < r1; r += RG) {
        const __half* p = tmp + (size_t)r * 32 + c;
        float v = 0.25f * (__half2float(p[0]) + __half2float(p[8]) +
                           __half2float(p[16]) + __half2float(p[24])) + bias;
        Af[(size_t)r * C + c] = v;
        sv += v; ssv += v * v;
    }
    __shared__ float ls[256], lss[256];
    ls[threadIdx.x] = sv; lss[threadIdx.x] = ssv;
    __syncthreads();
    for (int off = 128; off >= C; off >>= 1) {
        if (threadIdx.x < off) {
            ls[threadIdx.x] += ls[threadIdx.x + off];
            lss[threadIdx.x] += lss[threadIdx.x + off];
        }
        __syncthreads();
    }
    if (threadIdx.x < C) {
        atomicAdd(&sum[g * C + threadIdx.x], ls[threadIdx.x]);
        atomicAdd(&sumsq[g * C + threadIdx.x], lss[threadIdx.x]);
    }
}

template <int SPLIT>
__global__ __launch_bounds__(256) void k_gnpool(const float* __restrict__ Af, const int* __restrict__ bpos,
                                                const float* __restrict__ sum, const float* __restrict__ sumsq,
                                                const float* __restrict__ w,
                                                const float* __restrict__ b, const float* __restrict__ ms,
                                                float* __restrict__ pool) {
    constexpr int C = 8, RG = 32;
    int g = blockIdx.x / SPLIT, s = blockIdx.x % SPLIT;
    int c = threadIdx.x & 7;
    int rg = threadIdx.x >> 3;
    int b0 = bpos[g], b1 = bpos[g + 1];
    int n = b1 - b0;
    int seg = (n + SPLIT - 1) / SPLIT;
    int r0 = b0 + s * seg;
    int r1 = min(r0 + seg, b1);
    float cg = fmaxf((float)n, 1.f);
    float mu = sum[g * C + c] / cg;
    float ex2 = sumsq[g * C + c] / cg;
    float s_ = ms[c];
    float var = ex2 - (2.f * s_ - s_ * s_) * mu * mu;
    float rs = rsqrtf(var + 1e-5f) * w[c];
    float bb = b[c], mus = mu * s_;
    float pv = 0.f;
    for (int r = r0 + rg; r < r1; r += RG) {
        float y = fmaxf((Af[(size_t)r * C + c] - mus) * rs + bb, 0.f);
        pv += y;
    }
    __shared__ float ls[256];
    ls[threadIdx.x] = pv;
    __syncthreads();
    for (int off = 128; off >= C; off >>= 1) {
        if (threadIdx.x < off) ls[threadIdx.x] += ls[threadIdx.x + off];
        __syncthreads();
    }
    if (threadIdx.x < C) atomicAdd(&pool[g * C + threadIdx.x], ls[threadIdx.x]);
}

// ---------------- pool mean + linear head ----------------

__global__ __launch_bounds__(512) void k_final(const float* __restrict__ pool, const int* __restrict__ bpos,
                                               const float* __restrict__ lw, const float* __restrict__ lb,
                                               float* __restrict__ outp) {
    __shared__ float feat[512];
    int t = threadIdx.x;
    int g = t >> 3;
    float f = pool[t] / fmaxf((float)(bpos[g + 1] - bpos[g]), 1.f);
    feat[t] = f;
    outp[256 + t] = f;          // features: d_out[256 .. 768)
    __syncthreads();
    if (t < 256) {
        int g2 = t >> 2, o = t & 3;
        float a = lb[o];
#pragma unroll
        for (int cc = 0; cc < 8; ++cc) a += feat[g2 * 8 + cc] * lw[cc * 4 + o];
        outp[t] = a;            // logits: d_out[0 .. 256)
    }
}

// ---------------- host ----------------

extern "C" void kernel_launch(void* const* d_in, const int* in_sizes, int n_in,
                              void* d_out, int out_size, void* d_ws, size_t ws_size,
                              hipStream_t stream) {
    const float* x    = (const float*)d_in[0];
    const int*   ei   = (const int*)d_in[1];
    const int*   batch= (const int*)d_in[2];
    const float *w_l1 = (const float*)d_in[3],  *w_r1 = (const float*)d_in[4];
    const float *att1 = (const float*)d_in[5],  *b1   = (const float*)d_in[6];
    const float *gn1w = (const float*)d_in[7],  *gn1b = (const float*)d_in[8],  *gn1s = (const float*)d_in[9];
    const float *w_l2 = (const float*)d_in[10], *w_r2 = (const float*)d_in[11];
    const float *att2 = (const float*)d_in[12], *b2   = (const float*)d_in[13];
    const float *gn2w = (const float*)d_in[14], *gn2b = (const float*)d_in[15], *gn2s = (const float*)d_in[16];
    const float *w_l3 = (const float*)d_in[17], *w_r3 = (const float*)d_in[18];
    const float *att3 = (const float*)d_in[19], *b3   = (const float*)d_in[20];
    const float *gn3w = (const float*)d_in[21], *gn3b = (const float*)d_in[22], *gn3s = (const float*)d_in[23];
    const float *lw   = (const float*)d_in[24], *lb   = (const float*)d_in[25];

    char* ws = (char*)d_ws;
    size_t off = 0;
    auto alloc = [&](size_t bytes) -> void* {
        void* p = ws + off;
        off += (bytes + 255) & ~(size_t)255;
        return p;
    };
    __half* Ah  = (__half*)alloc((size_t)NN * 128 * 2);  // x_l fp16 (GEMM out, attn gather operand)
    __half* Xh  = (__half*)alloc((size_t)NN * 128 * 2);  // fp16 layer activations (gnnorm out)
    __half* Bh  = (__half*)alloc((size_t)NN * 128 * 2);  // attn out fp16 (l1, l3)
    __half* Chh = (__half*)alloc((size_t)NN * 64 * 2);   // attn out fp16 (l2)
    float*  B   = (float*)alloc((size_t)NN * 128 * 4);   // x_r fp32 (l1, l3)
    float*  Cb  = (float*)alloc((size_t)NN * 64 * 4);    // x_r fp32 (l2)
    float*  Af  = (float*)alloc((size_t)NN * 8 * 4);     // layer-3 head-mean features
    _Float16* Wf1 = (_Float16*)alloc((size_t)256 * 128 * 2);  // frag-ordered weights l1
    _Float16* Wf2 = (_Float16*)alloc((size_t)128 * 128 * 2);  // l2
    _Float16* Wf3 = (_Float16*)alloc((size_t)64 * 64 * 2);    // l3
    int* rowptr = (int*)alloc((size_t)(NN + 1) * 4);
    unsigned short* colsrc = (unsigned short*)alloc((size_t)ET * 2);
    unsigned int* ebuf = (unsigned int*)alloc((size_t)ET * 4);
    int* bcnt   = (int*)alloc((size_t)NBK * SB * 4);
    int* boff   = (int*)alloc((size_t)NBK * SB * 4);
    int* tot    = (int*)alloc((size_t)NBK * 4);
    int* bpos   = (int*)alloc((size_t)(NG + 1) * 4);
    char* zbase = ws + off;                              // everything below gets one memset
    float* sum1 = (float*)alloc((size_t)NG * 128 * 4);
    float* sq1  = (float*)alloc((size_t)NG * 128 * 4);
    float* sum2 = (float*)alloc((size_t)NG * 64 * 4);
    float* sq2  = (float*)alloc((size_t)NG * 64 * 4);
    float* sum3 = (float*)alloc((size_t)NG * 8 * 4);
    float* sq3  = (float*)alloc((size_t)NG * 8 * 4);
    float* pool = (float*)alloc((size_t)NG * 8 * 4);
    size_t zbytes = (size_t)((ws + off) - zbase);
    (void)hipMemsetAsync(zbase, 0, zbytes, stream);

    k_prep<<<26 + NBK + SB, 256, 0, stream>>>(w_l1, w_r1, w_l2, w_r2, w_l3, w_r3, Wf1, Wf2, Wf3,
                                              batch, bpos, ei, bcnt);
    k_gemm1_scan<<<GD + NBK, 256, 0, stream>>>(x, Wf1, Ah, B, bcnt, boff, tot);
    k_bscatter<<<SB, 256, 0, stream>>>(ei, tot, boff, ebuf);
    k_bsort<<<NBK, 256, 0, stream>>>(ebuf, tot, rowptr, colsrc);

    int gA2ep = (NN * H * 2 + 255) / 256;         // EP=2 grids
    int gA1ep = (NN * H + 255) / 256;             // EP=1 grid

    // ---- layer 1: 128 -> 4x32 concat -> 128
    k_attn<32, 2, true><<<gA2ep, 256, 0, stream>>>(Ah, B, rowptr, colsrc, att1, b1, Bh);
    k_gnred2<7, 8><<<NG * 8, 256, 0, stream>>>(Bh, bpos, sum1, sq1);
    k_gnnorm<<<(NN * 128 + 255) / 256, 256, 0, stream>>>(Bh, batch, sum1, sq1, bpos, gn1w, gn1b, gn1s, 7, Xh);

    // ---- layer 2: 128 -> 4x16 concat -> 64
    k_dualgemm<128, 64, _Float16><<<GD, 256, 0, stream>>>((const _Float16*)Xh, Wf2, Ah, Cb);
    k_attn<16, 2, true><<<gA2ep, 256, 0, stream>>>(Ah, Cb, rowptr, colsrc, att2, b2, Chh);
    k_gnred2<6, 8><<<NG * 8, 256, 0, stream>>>(Chh, bpos, sum2, sq2);
    k_gnnorm<<<(NN * 64 + 255) / 256, 256, 0, stream>>>(Chh, batch, sum2, sq2, bpos, gn2w, gn2b, gn2s, 6, Xh);

    // ---- layer 3: 64 -> 4x8 mean -> 8, fused tail
    k_dualgemm<64, 32, _Float16><<<GD, 256, 0, stream>>>((const _Float16*)Xh, Wf3, Ah, B);
    k_attn<8, 1, false><<<gA1ep, 256, 0, stream>>>(Ah, B, rowptr, colsrc, att3, nullptr, Bh);
    k_headgn<8><<<NG * 8, 256, 0, stream>>>(Bh, b3, bpos, Af, sum3, sq3);
    k_gnpool<8><<<NG * 8, 256, 0, stream>>>(Af, bpos, sum3, sq3, gn3w, gn3b, gn3s, pool);
    k_final<<<1, 512, 0, stream>>>(pool, bpos, lw, lb, (float*)d_out);
}

// Round 18
// 302.069 us; speedup vs baseline: 1.6788x; 1.0534x over previous
//
#include <hip/hip_runtime.h>
#include <hip/hip_fp16.h>
#include <math.h>

#define NN 50000
#define NE 800000
#define ET (NE + NN)
#define NG 64
#define H 4
#define NBK 196                   // dst buckets (dst >> 8)
#define CH 2048                   // edges per chunk
#define SB ((ET + CH - 1) / CH)   // 416 edge chunks
#define GD ((NN + 63) / 64)       // dualgemm grid (782)

typedef _Float16 half8 __attribute__((ext_vector_type(8)));
typedef _Float16 half4 __attribute__((ext_vector_type(4)));
typedef _Float16 hv2 __attribute__((ext_vector_type(2)));
typedef float floatx4 __attribute__((ext_vector_type(4)));

// ---------------- weight prep device fn ----------------

template <int K, int M2>
__device__ __forceinline__ void wprep_fn(int chunk, const float* __restrict__ Wl, const float* __restrict__ Wr,
                                         _Float16* __restrict__ Wfrag) {
    constexpr int MTOT = 2 * M2, NT = MTOT / 16;
    if (chunk >= MTOT * K / 8) return;
    int lane = chunk & 63, tt = chunk >> 6;
    int t = tt % NT, kt = tt / NT;
    int n = t * 16 + (lane & 15);
    int kb = kt * 32 + (lane >> 4) * 8;
    const float* src = (n < M2) ? (Wl + n) : (Wr + (n - M2));
    half8 h;
#pragma unroll
    for (int j = 0; j < 8; ++j) h[j] = (_Float16)src[(size_t)(kb + j) * M2];
    *(half8*)(Wfrag + (size_t)chunk * 8) = h;
}

// ---------------- fused prep: wprep (26) + bounds (196) + bhist (416) ----------------

__global__ __launch_bounds__(256) void k_prep(const float* __restrict__ Wl1, const float* __restrict__ Wr1,
                                              const float* __restrict__ Wl2, const float* __restrict__ Wr2,
                                              const float* __restrict__ Wl3, const float* __restrict__ Wr3,
                                              _Float16* __restrict__ Wf1, _Float16* __restrict__ Wf2,
                                              _Float16* __restrict__ Wf3,
                                              const int* __restrict__ batch, int* __restrict__ bpos,
                                              const int* __restrict__ ei, int* __restrict__ bcnt) {
    int b = blockIdx.x, t = threadIdx.x;
    if (b < 16) { wprep_fn<128, 128>(b * 256 + t, Wl1, Wr1, Wf1); return; }
    if (b < 24) { wprep_fn<128, 64>((b - 16) * 256 + t, Wl2, Wr2, Wf2); return; }
    if (b < 26) { wprep_fn<64, 32>((b - 24) * 256 + t, Wl3, Wr3, Wf3); return; }
    if (b < 26 + NBK) {
        int i = (b - 26) * 256 + t;
        if (i >= NN) return;
        int cur = batch[i];
        int prev = (i == 0) ? -1 : batch[i - 1];
        for (int g = prev + 1; g <= cur; ++g) bpos[g] = i;
        if (i == NN - 1)
            for (int g = cur + 1; g <= NG; ++g) bpos[g] = NN;
        return;
    }
    // bhist
    __shared__ int hist[NBK];
    int b0 = b - 26 - NBK;
    for (int i = t; i < NBK; i += 256) hist[i] = 0;
    __syncthreads();
#pragma unroll
    for (int pass = 0; pass < CH / 256; ++pass) {
        int e = b0 * CH + pass * 256 + t;
        if (e < ET) {
            int d = (e < NE) ? ei[NE + e] : (e - NE);
            atomicAdd(&hist[d >> 8], 1);
        }
    }
    __syncthreads();
    if (t < NBK) bcnt[t * SB + b0] = hist[t];
}

// ---------------- dualgemm body; A fp16/fp32; optional fused GraphNorm on A (y = x*a + bsh, ReLU) ----------------

template <typename AT, bool NORM>
__device__ __forceinline__ half8 load_a8(const AT* __restrict__ ap, const float* __restrict__ pa,
                                         const float* __restrict__ pb) {
    if constexpr (NORM) {
        half8 raw = *(const half8*)ap;
        half8 h;
#pragma unroll
        for (int j = 0; j < 8; ++j) {
            float y = fmaf((float)raw[j], pa[j], pb[j]);
            h[j] = (_Float16)fmaxf(y, 0.f);
        }
        return h;
    } else if constexpr (__is_same(AT, _Float16)) {
        return *(const half8*)ap;
    } else {
        const float4* p = (const float4*)ap;
        float4 a = p[0], b = p[1];
        half8 h;
        h[0] = (_Float16)a.x; h[1] = (_Float16)a.y; h[2] = (_Float16)a.z; h[3] = (_Float16)a.w;
        h[4] = (_Float16)b.x; h[5] = (_Float16)b.y; h[6] = (_Float16)b.z; h[7] = (_Float16)b.w;
        return h;
    }
}

template <int K, int M2, typename AT, bool NORM>
__device__ __forceinline__ void dualgemm_body(int blk, int tid, const AT* __restrict__ Ain,
                                              const _Float16* __restrict__ Wfrag,
                                              __half* __restrict__ Ol, float* __restrict__ Or,
                                              const float* __restrict__ ga, const float* __restrict__ gb,
                                              const int* __restrict__ batch) {
    constexpr int MTOT = 2 * M2;
    constexpr int NT = MTOT / 16;
    constexpr int KT = K / 32;
    int wid = tid >> 6, lane = tid & 63;
    int q = lane >> 4, l15 = lane & 15;
    int r0 = blk * 64 + wid * 16;
    int arow = min(r0 + l15, NN - 1);
    const AT* ap = Ain + (size_t)arow * K + q * 8;
    const float *pa = nullptr, *pb = nullptr;
    if constexpr (NORM) {
        int g = batch[arow];
        pa = ga + g * K + q * 8;
        pb = gb + g * K + q * 8;
    }

    floatx4 acc[NT];
#pragma unroll
    for (int t = 0; t < NT; ++t) acc[t] = (floatx4){0.f, 0.f, 0.f, 0.f};

#pragma unroll
    for (int kt = 0; kt < KT; ++kt) {
        half8 a8 = load_a8<AT, NORM>(ap + kt * 32, pa + (NORM ? kt * 32 : 0), pb + (NORM ? kt * 32 : 0));
        const _Float16* wp = Wfrag + ((size_t)(kt * NT) * 64 + lane) * 8;
#pragma unroll
        for (int t = 0; t < NT; ++t) {
            half8 b8 = *(const half8*)(wp + (size_t)t * 64 * 8);
            acc[t] = __builtin_amdgcn_mfma_f32_16x16x32_f16(a8, b8, acc[t], 0, 0, 0);
        }
    }

#pragma unroll
    for (int t = 0; t < NT; ++t) {
        int cn = t * 16 + l15;
#pragma unroll
        for (int reg = 0; reg < 4; ++reg) {
            int r = r0 + q * 4 + reg;
            if (r < NN) {
                if (cn < M2) Ol[(size_t)r * M2 + cn] = __float2half(acc[t][reg]);
                else         Or[(size_t)r * M2 + (cn - M2)] = acc[t][reg];
            }
        }
    }
}

template <int K, int M2>
__global__ __launch_bounds__(256) void k_dualgemm_n(const __half* __restrict__ Ain,
                                                    const _Float16* __restrict__ Wfrag,
                                                    __half* __restrict__ Ol, float* __restrict__ Or,
                                                    const float* __restrict__ ga, const float* __restrict__ gb,
                                                    const int* __restrict__ batch) {
    dualgemm_body<K, M2, _Float16, true>(blockIdx.x, threadIdx.x, (const _Float16*)Ain, Wfrag, Ol, Or,
                                         ga, gb, batch);
}

// ---------------- bscanA device fn: pair-scan of SB(416) chunk-counts per bucket ----------------

__device__ __forceinline__ void bscanA_fn(int b, int t, const int* __restrict__ bcnt,
                                          int* __restrict__ boff, int* __restrict__ tot) {
    __shared__ int lds[256];
    int i0 = 2 * t, i1 = 2 * t + 1;
    int v0 = (i0 < SB) ? bcnt[b * SB + i0] : 0;
    int v1 = (i1 < SB) ? bcnt[b * SB + i1] : 0;
    int pair = v0 + v1;
    lds[t] = pair;
    __syncthreads();
    for (int off = 1; off < 256; off <<= 1) {
        int y = (t >= off) ? lds[t - off] : 0;
        __syncthreads();
        lds[t] += y;
        __syncthreads();
    }
    int excl = lds[t] - pair;
    if (i0 < SB) boff[b * SB + i0] = excl;
    if (i1 < SB) boff[b * SB + i1] = excl + v0;
    if (t == 255) tot[b] = lds[255];
}

// ---- fused: dualgemm l1 (782 blocks, fp32 input) + bscanA (196 blocks)

__global__ __launch_bounds__(256) void k_gemm1_scan(const float* __restrict__ x, const _Float16* __restrict__ Wf1,
                                                    __half* __restrict__ Ol, float* __restrict__ Or,
                                                    const int* __restrict__ bcnt, int* __restrict__ boff,
                                                    int* __restrict__ tot) {
    if (blockIdx.x < GD)
        dualgemm_body<128, 128, float, false>(blockIdx.x, threadIdx.x, x, Wf1, Ol, Or, nullptr, nullptr, nullptr);
    else
        bscanA_fn(blockIdx.x - GD, threadIdx.x, bcnt, boff, tot);
}

// ---------------- CSR: scatter into bucket-major ebuf ----------------

__device__ __forceinline__ void edge_sd(int e, const int* __restrict__ ei, int& s, int& d) {
    if (e < NE) { s = ei[e]; d = ei[NE + e]; } else { s = e - NE; d = s; }
}

__global__ __launch_bounds__(256) void k_bscatter(const int* __restrict__ ei, const int* __restrict__ tot,
                                                  const int* __restrict__ boff, unsigned int* __restrict__ ebuf) {
    __shared__ int eb[256];
    __shared__ int cur[NBK];
    int b0 = blockIdx.x, t = threadIdx.x;
    int v = (t < NBK) ? tot[t] : 0;
    eb[t] = v;
    __syncthreads();
    for (int off = 1; off < 256; off <<= 1) {
        int y = (t >= off) ? eb[t - off] : 0;
        __syncthreads();
        eb[t] += y;
        __syncthreads();
    }
    if (t < NBK) cur[t] = (eb[t] - v) + boff[t * SB + b0];
    __syncthreads();
#pragma unroll
    for (int pass = 0; pass < CH / 256; ++pass) {
        int e = b0 * CH + pass * 256 + t;
        if (e < ET) {
            int s, d;
            edge_sd(e, ei, s, d);
            int pos = atomicAdd(&cur[d >> 8], 1);
            ebuf[pos] = ((unsigned)s << 16) | (unsigned)(d & 255);
        }
    }
}

// ---------------- CSR: per-bucket exact-dst counting sort -> rowptr + colsrc ----------------

__global__ __launch_bounds__(256) void k_bsort(const unsigned int* __restrict__ ebuf,
                                               const int* __restrict__ tot,
                                               int* __restrict__ rowptr, unsigned short* __restrict__ colsrc) {
    __shared__ int eb[256];
    __shared__ int sbase;
    __shared__ int cnt2[256];
    __shared__ int sc[256];
    __shared__ int cur2[256];
    int b = blockIdx.x, t = threadIdx.x;
    int v = (t < NBK) ? tot[t] : 0;
    eb[t] = v;
    __syncthreads();
    for (int off = 1; off < 256; off <<= 1) {
        int y = (t >= off) ? eb[t - off] : 0;
        __syncthreads();
        eb[t] += y;
        __syncthreads();
    }
    if (t == b) sbase = eb[t] - v;
    __syncthreads();
    int base = sbase, n = tot[b];
    cnt2[t] = 0;
    __syncthreads();
    for (int i = t; i < n; i += 256) atomicAdd(&cnt2[ebuf[base + i] & 255], 1);
    __syncthreads();
    int cv = cnt2[t];
    sc[t] = cv;
    __syncthreads();
    for (int off = 1; off < 256; off <<= 1) {
        int y = (t >= off) ? sc[t - off] : 0;
        __syncthreads();
        sc[t] += y;
        __syncthreads();
    }
    int excl = sc[t] - cv;
    int d = b * 256 + t;
    if (d < NN) rowptr[d] = base + excl;
    if (b == 0 && t == 0) rowptr[NN] = ET;
    cur2[t] = excl;
    __syncthreads();
    for (int i = t; i < n; i += 256) {
        unsigned u = ebuf[base + i];
        int pos = atomicAdd(&cur2[u & 255], 1);
        colsrc[base + pos] = (unsigned short)(u >> 16);
    }
}

// ---------------- GATv2 attention: channel-split + packed fp16 + no-max softmax, fp16 output ----------------

template <int CP> struct HVec { hv2 h2[CP / 2]; };

template <int CP>
__device__ __forceinline__ HVec<CP> load_hv(const __half* __restrict__ p) {
    HVec<CP> r;
    if constexpr (CP == 16) {
        float4* rp = (float4*)&r;
        rp[0] = ((const float4*)p)[0];
        rp[1] = ((const float4*)p)[1];
    } else if constexpr (CP == 8) {
        float4 t = *(const float4*)p; r = *(HVec<CP>*)&t;
    } else if constexpr (CP == 4) {
        float2 t = *(const float2*)p; r = *(HVec<CP>*)&t;
    } else {
        r.h2[0] = *(const hv2*)p;
    }
    return r;
}

template <int C, int EP, bool CONCAT>
__global__ __launch_bounds__(256) void k_attn(const __half* __restrict__ xl, const float* __restrict__ xr,
                                              const int* __restrict__ rowptr,
                                              const unsigned short* __restrict__ colsrc,
                                              const float* __restrict__ att, const float* __restrict__ bias,
                                              __half* __restrict__ out) {
    constexpr int CP = C / EP;
    constexpr int LEP = (EP == 4) ? 2 : ((EP == 2) ? 1 : 0);
    int t = blockIdx.x * 256 + threadIdx.x;
    int part = t & (EP - 1);
    int nh = t >> LEP;
    if (nh >= NN * H) return;
    int node = nh >> 2, h = nh & 3;           // H == 4
    int cbase = h * C + part * CP;
    hv2 xrr2[CP / 2], attv2[CP / 2];
    float acc[CP];
    {
        const float* p = xr + (size_t)node * (H * C) + cbase;
        const float* q = att + cbase;
#pragma unroll
        for (int j = 0; j < CP / 2; ++j) {
            xrr2[j] = (hv2){(_Float16)p[2 * j], (_Float16)p[2 * j + 1]};
            attv2[j] = (hv2){(_Float16)q[2 * j], (_Float16)q[2 * j + 1]};
        }
#pragma unroll
        for (int c = 0; c < CP; ++c) acc[c] = 0.f;
    }
    float denom = 0.f;
    int beg = rowptr[node], end = rowptr[node + 1];

    auto process = [&](const HVec<CP>& xv) {
        float part_s = 0.f;
#pragma unroll
        for (int j = 0; j < CP / 2; ++j) {
            hv2 z = xv.h2[j] + xrr2[j];
            hv2 l = __builtin_elementwise_max(z, z * (_Float16)0.2f);   // leaky_relu
            part_s = __builtin_amdgcn_fdot2(l, attv2[j], part_s, false);
        }
        float score = part_s;
#pragma unroll
        for (int mask = 1; mask < EP; mask <<= 1) score += __shfl_xor(score, mask, 64);
        float w = __expf(score);
        denom += w;
        const _Float16* xh = (const _Float16*)&xv;
#pragma unroll
        for (int c = 0; c < CP; ++c) acc[c] = fmaf(w, (float)xh[c], acc[c]);
    };

    int idx = beg;
    for (; idx + 4 <= end; idx += 4) {
        int s0 = colsrc[idx], s1 = colsrc[idx + 1], s2 = colsrc[idx + 2], s3 = colsrc[idx + 3];
        HVec<CP> xv0 = load_hv<CP>(xl + (size_t)s0 * (H * C) + cbase);
        HVec<CP> xv1 = load_hv<CP>(xl + (size_t)s1 * (H * C) + cbase);
        HVec<CP> xv2 = load_hv<CP>(xl + (size_t)s2 * (H * C) + cbase);
        HVec<CP> xv3 = load_hv<CP>(xl + (size_t)s3 * (H * C) + cbase);
        process(xv0);
        process(xv1);
        process(xv2);
        process(xv3);
    }
    for (; idx < end; ++idx) {
        int s = colsrc[idx];
        HVec<CP> xv = load_hv<CP>(xl + (size_t)s * (H * C) + cbase);
        process(xv);
    }

    float inv = 1.f / denom;
    _Float16* op = (_Float16*)out + (size_t)node * (H * C) + cbase;
    _Float16 hv[CP];
#pragma unroll
    for (int c = 0; c < CP; ++c) {
        float v = acc[c] * inv;
        if (CONCAT) v += bias[cbase + c];
        hv[c] = (_Float16)v;
    }
    if constexpr (CP >= 8) {
#pragma unroll
        for (int j = 0; j < CP / 8; ++j) *(half8*)(op + 8 * j) = *(half8*)(hv + 8 * j);
    } else if constexpr (CP == 4) {
        *(half4*)op = *(half4*)hv;
    } else {
        *(hv2*)op = *(hv2*)hv;
    }
}

// ---------------- GraphNorm reduce (fp16 input): one block per (graph, segment) ----------------

template <int LOGC, int SPLIT>
__global__ __launch_bounds__(256) void k_gnred2(const __half* __restrict__ h, const int* __restrict__ bpos,
                                                float* __restrict__ sum, float* __restrict__ sumsq) {
    constexpr int C = 1 << LOGC;
    constexpr int RG = 256 >> LOGC;      // row-groups per block
    int g = blockIdx.x / SPLIT, s = blockIdx.x % SPLIT;
    int c = threadIdx.x & (C - 1);
    int rg = threadIdx.x >> LOGC;
    int b0 = bpos[g], b1 = bpos[g + 1];
    int n = b1 - b0;
    int seg = (n + SPLIT - 1) / SPLIT;
    int r0 = b0 + s * seg;
    int r1 = min(r0 + seg, b1);
    float sv = 0.f, ssv = 0.f;
    for (int r = r0 + rg; r < r1; r += RG) {
        float x = __half2float(h[(size_t)r * C + c]);
        sv += x; ssv += x * x;
    }
    __shared__ float ls[256], lss[256];
    ls[threadIdx.x] = sv; lss[threadIdx.x] = ssv;
    __syncthreads();
    for (int off = 128; off >= C; off >>= 1) {
        if (threadIdx.x < off) {
            ls[threadIdx.x] += ls[threadIdx.x + off];
            lss[threadIdx.x] += lss[threadIdx.x + off];
        }
        __syncthreads();
    }
    if (threadIdx.x < C) {
        atomicAdd(&sum[g * C + threadIdx.x], ls[threadIdx.x]);
        atomicAdd(&sumsq[g * C + threadIdx.x], lss[threadIdx.x]);
    }
}

// ---------------- GN affine-param precompute: a = rsqrt(var+eps)*w, bsh = b - mu*ms*a ----------------

__global__ __launch_bounds__(256) void k_gnparam(const float* __restrict__ sum, const float* __restrict__ sumsq,
                                                 const int* __restrict__ bpos, const float* __restrict__ w,
                                                 const float* __restrict__ b, const float* __restrict__ ms,
                                                 int logC, float* __restrict__ ga, float* __restrict__ gb) {
    int C = 1 << logC;
    int i = blockIdx.x * 256 + threadIdx.x;
    if (i >= NG * C) return;
    int g = i >> logC, c = i & (C - 1);
    float cg = fmaxf((float)(bpos[g + 1] - bpos[g]), 1.f);
    float mu = sum[i] / cg;
    float ex2 = sumsq[i] / cg;
    float s_ = ms[c];
    float var = ex2 - (2.f * s_ - s_ * s_) * mu * mu;
    float a = rsqrtf(var + 1e-5f) * w[c];
    ga[i] = a;
    gb[i] = b[c] - mu * s_ * a;
}

// ---------------- fused layer-3 tail ----------------

template <int SPLIT>
__global__ __launch_bounds__(256) void k_headgn(const __half* __restrict__ tmp, const float* __restrict__ b3,
                                                const int* __restrict__ bpos, float* __restrict__ Af,
                                                float* __restrict__ sum, float* __restrict__ sumsq) {
    constexpr int C = 8, RG = 32;
    int g = blockIdx.x / SPLIT, s = blockIdx.x % SPLIT;
    int c = threadIdx.x & 7;
    int rg = threadIdx.x >> 3;
    int b0 = bpos[g], b1 = bpos[g + 1];
    int n = b1 - b0;
    int seg = (n + SPLIT - 1) / SPLIT;
    int r0 = b0 + s * seg;
    int r1 = min(r0 + seg, b1);
    float bias = b3[c];
    float sv = 0.f, ssv = 0.f;
    for (int r = r0 + rg; r < r1; r += RG) {
        const __half* p = tmp + (size_t)r * 32 + c;
        float v = 0.25f * (__half2float(p[0]) + __half2float(p[8]) +
                           __half2float(p[16]) + __half2float(p[24])) + bias;
        Af[(size_t)r * C + c] = v;
        sv += v; ssv += v * v;
    }
    __shared__ float ls[256], lss[256];
    ls[threadIdx.x] = sv; lss[threadIdx.x] = ssv;
    __syncthreads();
    for (int off = 128; off >= C; off >>= 1) {
        if (threadIdx.x < off) {
            ls[threadIdx.x] += ls[threadIdx.x + off];
            lss[threadIdx.x] += lss[threadIdx.x + off];
        }
        __syncthreads();
    }
    if (threadIdx.x < C) {
        atomicAdd(&sum[g * C + threadIdx.x], ls[threadIdx.x]);
        atomicAdd(&sumsq[g * C + threadIdx.x], lss[threadIdx.x]);
    }
}

template <int SPLIT>
__global__ __launch_bounds__(256) void k_gnpool(const float* __restrict__ Af, const int* __restrict__ bpos,
                                                const float* __restrict__ sum, const float* __restrict__ sumsq,
                                                const float* __restrict__ w,
                                                const float* __restrict__ b, const float* __restrict__ ms,
                                                float* __restrict__ pool) {
    constexpr int C = 8, RG = 32;
    int g = blockIdx.x / SPLIT, s = blockIdx.x % SPLIT;
    int c = threadIdx.x & 7;
    int rg = threadIdx.x >> 3;
    int b0 = bpos[g], b1 = bpos[g + 1];
    int n = b1 - b0;
    int seg = (n + SPLIT - 1) / SPLIT;
    int r0 = b0 + s * seg;
    int r1 = min(r0 + seg, b1);
    float cg = fmaxf((float)n, 1.f);
    float mu = sum[g * C + c] / cg;
    float ex2 = sumsq[g * C + c] / cg;
    float s_ = ms[c];
    float var = ex2 - (2.f * s_ - s_ * s_) * mu * mu;
    float rs = rsqrtf(var + 1e-5f) * w[c];
    float bb = b[c], mus = mu * s_;
    float pv = 0.f;
    for (int r = r0 + rg; r < r1; r += RG) {
        float y = fmaxf((Af[(size_t)r * C + c] - mus) * rs + bb, 0.f);
        pv += y;
    }
    __shared__ float ls[256];
    ls[threadIdx.x] = pv;
    __syncthreads();
    for (int off = 128; off >= C; off >>= 1) {
        if (threadIdx.x < off) ls[threadIdx.x] += ls[threadIdx.x + off];
        __syncthreads();
    }
    if (threadIdx.x < C) atomicAdd(&pool[g * C + threadIdx.x], ls[threadIdx.x]);
}

// ---------------- pool mean + linear head ----------------

__global__ __launch_bounds__(512) void k_final(const float* __restrict__ pool, const int* __restrict__ bpos,
                                               const float* __restrict__ lw, const float* __restrict__ lb,
                                               float* __restrict__ outp) {
    __shared__ float feat[512];
    int t = threadIdx.x;
    int g = t >> 3;
    float f = pool[t] / fmaxf((float)(bpos[g + 1] - bpos[g]), 1.f);
    feat[t] = f;
    outp[256 + t] = f;          // features: d_out[256 .. 768)
    __syncthreads();
    if (t < 256) {
        int g2 = t >> 2, o = t & 3;
        float a = lb[o];
#pragma unroll
        for (int cc = 0; cc < 8; ++cc) a += feat[g2 * 8 + cc] * lw[cc * 4 + o];
        outp[t] = a;            // logits: d_out[0 .. 256)
    }
}

// ---------------- host ----------------

extern "C" void kernel_launch(void* const* d_in, const int* in_sizes, int n_in,
                              void* d_out, int out_size, void* d_ws, size_t ws_size,
                              hipStream_t stream) {
    const float* x    = (const float*)d_in[0];
    const int*   ei   = (const int*)d_in[1];
    const int*   batch= (const int*)d_in[2];
    const float *w_l1 = (const float*)d_in[3],  *w_r1 = (const float*)d_in[4];
    const float *att1 = (const float*)d_in[5],  *b1   = (const float*)d_in[6];
    const float *gn1w = (const float*)d_in[7],  *gn1b = (const float*)d_in[8],  *gn1s = (const float*)d_in[9];
    const float *w_l2 = (const float*)d_in[10], *w_r2 = (const float*)d_in[11];
    const float *att2 = (const float*)d_in[12], *b2   = (const float*)d_in[13];
    const float *gn2w = (const float*)d_in[14], *gn2b = (const float*)d_in[15], *gn2s = (const float*)d_in[16];
    const float *w_l3 = (const float*)d_in[17], *w_r3 = (const float*)d_in[18];
    const float *att3 = (const float*)d_in[19], *b3   = (const float*)d_in[20];
    const float *gn3w = (const float*)d_in[21], *gn3b = (const float*)d_in[22], *gn3s = (const float*)d_in[23];
    const float *lw   = (const float*)d_in[24], *lb   = (const float*)d_in[25];

    char* ws = (char*)d_ws;
    size_t off = 0;
    auto alloc = [&](size_t bytes) -> void* {
        void* p = ws + off;
        off += (bytes + 255) & ~(size_t)255;
        return p;
    };
    __half* Ah  = (__half*)alloc((size_t)NN * 128 * 2);  // x_l fp16 (GEMM out, attn gather operand)
    __half* Bh  = (__half*)alloc((size_t)NN * 128 * 2);  // attn out fp16 (l1, l3)
    __half* Chh = (__half*)alloc((size_t)NN * 64 * 2);   // attn out fp16 (l2)
    float*  B   = (float*)alloc((size_t)NN * 128 * 4);   // x_r fp32 (l1, l3)
    float*  Cb  = (float*)alloc((size_t)NN * 64 * 4);    // x_r fp32 (l2)
    float*  Af  = (float*)alloc((size_t)NN * 8 * 4);     // layer-3 head-mean features
    _Float16* Wf1 = (_Float16*)alloc((size_t)256 * 128 * 2);  // frag-ordered weights l1
    _Float16* Wf2 = (_Float16*)alloc((size_t)128 * 128 * 2);  // l2
    _Float16* Wf3 = (_Float16*)alloc((size_t)64 * 64 * 2);    // l3
    float* ga1 = (float*)alloc((size_t)NG * 128 * 4);    // GN affine params l1
    float* gb1 = (float*)alloc((size_t)NG * 128 * 4);
    float* ga2 = (float*)alloc((size_t)NG * 64 * 4);     // l2
    float* gb2 = (float*)alloc((size_t)NG * 64 * 4);
    int* rowptr = (int*)alloc((size_t)(NN + 1) * 4);
    unsigned short* colsrc = (unsigned short*)alloc((size_t)ET * 2);
    unsigned int* ebuf = (unsigned int*)alloc((size_t)ET * 4);
    int* bcnt   = (int*)alloc((size_t)NBK * SB * 4);
    int* boff   = (int*)alloc((size_t)NBK * SB * 4);
    int* tot    = (int*)alloc((size_t)NBK * 4);
    int* bpos   = (int*)alloc((size_t)(NG + 1) * 4);
    char* zbase = ws + off;                              // everything below gets one memset
    float* sum1 = (float*)alloc((size_t)NG * 128 * 4);
    float* sq1  = (float*)alloc((size_t)NG * 128 * 4);
    float* sum2 = (float*)alloc((size_t)NG * 64 * 4);
    float* sq2  = (float*)alloc((size_t)NG * 64 * 4);
    float* sum3 = (float*)alloc((size_t)NG * 8 * 4);
    float* sq3  = (float*)alloc((size_t)NG * 8 * 4);
    float* pool = (float*)alloc((size_t)NG * 8 * 4);
    size_t zbytes = (size_t)((ws + off) - zbase);
    (void)hipMemsetAsync(zbase, 0, zbytes, stream);

    k_prep<<<26 + NBK + SB, 256, 0, stream>>>(w_l1, w_r1, w_l2, w_r2, w_l3, w_r3, Wf1, Wf2, Wf3,
                                              batch, bpos, ei, bcnt);
    k_gemm1_scan<<<GD + NBK, 256, 0, stream>>>(x, Wf1, Ah, B, bcnt, boff, tot);
    k_bscatter<<<SB, 256, 0, stream>>>(ei, tot, boff, ebuf);
    k_bsort<<<NBK, 256, 0, stream>>>(ebuf, tot, rowptr, colsrc);

    int gA2ep = (NN * H * 2 + 255) / 256;         // EP=2 grids
    int gA1ep = (NN * H + 255) / 256;             // EP=1 grid

    // ---- layer 1: 128 -> 4x32 concat -> 128 (GN folded into l2 GEMM A-load)
    k_attn<32, 2, true><<<gA2ep, 256, 0, stream>>>(Ah, B, rowptr, colsrc, att1, b1, Bh);
    k_gnred2<7, 8><<<NG * 8, 256, 0, stream>>>(Bh, bpos, sum1, sq1);
    k_gnparam<<<(NG * 128 + 255) / 256, 256, 0, stream>>>(sum1, sq1, bpos, gn1w, gn1b, gn1s, 7, ga1, gb1);

    // ---- layer 2: 128 -> 4x16 concat -> 64 (GN folded into l3 GEMM A-load)
    k_dualgemm_n<128, 64><<<GD, 256, 0, stream>>>(Bh, Wf2, Ah, Cb, ga1, gb1, batch);
    k_attn<16, 2, true><<<gA2ep, 256, 0, stream>>>(Ah, Cb, rowptr, colsrc, att2, b2, Chh);
    k_gnred2<6, 8><<<NG * 8, 256, 0, stream>>>(Chh, bpos, sum2, sq2);
    k_gnparam<<<(NG * 64 + 255) / 256, 256, 0, stream>>>(sum2, sq2, bpos, gn2w, gn2b, gn2s, 6, ga2, gb2);

    // ---- layer 3: 64 -> 4x8 mean -> 8, fused tail
    k_dualgemm_n<64, 32><<<GD, 256, 0, stream>>>(Chh, Wf3, Ah, B, ga2, gb2, batch);
    k_attn<8, 1, false><<<gA1ep, 256, 0, stream>>>(Ah, B, rowptr, colsrc, att3, nullptr, Bh);
    k_headgn<8><<<NG * 8, 256, 0, stream>>>(Bh, b3, bpos, Af, sum3, sq3);
    k_gnpool<8><<<NG * 8, 256, 0, stream>>>(Af, bpos, sum3, sq3, gn3w, gn3b, gn3s, pool);
    k_final<<<1, 512, 0, stream>>>(pool, bpos, lw, lb, (float*)d_out);
}